// Round 2
// baseline (1998.718 us; speedup 1.0000x reference)
//
#include <hip/hip_runtime.h>
#include <hip/hip_bf16.h>
#include <math.h>

#define NNODES   50000
#define INDIM    78
#define NHEADS   10
#define CDIM     78
#define HCDIM    780
#define NEDGES   400000
#define NBATCH   256
#define ETOT     (NEDGES + NNODES)   // 450000, with self-loops
#define NEG_SLOPE 0.2f

// bf16 <-> f32 helpers (bit-level; bf16->f32 exact, f32->bf16 via hip RN)
__device__ __forceinline__ float bf2f(unsigned short u) {
    union { unsigned int i; float f; } v; v.i = ((unsigned int)u) << 16; return v.f;
}
__device__ __forceinline__ unsigned short f2bf(float f) {
    __hip_bfloat16 h = __float2bfloat16(f);
    return *reinterpret_cast<unsigned short*>(&h);
}

// ---------------------------------------------------------------------------
// zero-init (no hipMemsetAsync: keep graph capture trivially safe)
// ---------------------------------------------------------------------------
__global__ void zero_f_kernel(float* __restrict__ p, int n) {
    int i = blockIdx.x * blockDim.x + threadIdx.x;
    if (i < n) p[i] = 0.f;
}
__global__ void zero_i_kernel(int* __restrict__ p, int n) {
    int i = blockIdx.x * blockDim.x + threadIdx.x;
    if (i < n) p[i] = 0;
}

// ---------------------------------------------------------------------------
// CSR build
// ---------------------------------------------------------------------------
__global__ void count_kernel(const int* __restrict__ ei, int* __restrict__ deg) {
    int e = blockIdx.x * blockDim.x + threadIdx.x;
    if (e >= ETOT) return;
    int d = (e < NEDGES) ? ei[NEDGES + e] : (e - NEDGES);   // dst row
    atomicAdd(&deg[d], 1);
}

// single-block exclusive scan over deg[0..n) -> row_ptr, cursor
__global__ void scan_kernel(const int* __restrict__ deg, int n,
                            int* __restrict__ row_ptr, int* __restrict__ cursor) {
    __shared__ int bufA[1024];
    __shared__ int bufB[1024];
    __shared__ int carry_s;
    int t = threadIdx.x;
    if (t == 0) carry_s = 0;
    __syncthreads();
    for (int base = 0; base < n; base += 1024) {
        int i = base + t;
        int v = (i < n) ? deg[i] : 0;
        bufA[t] = v;
        __syncthreads();
        int* src = bufA; int* dst = bufB;
        for (int off = 1; off < 1024; off <<= 1) {
            int val = src[t] + ((t >= off) ? src[t - off] : 0);
            dst[t] = val;
            __syncthreads();
            int* tp = src; src = dst; dst = tp;
        }
        int incl = src[t];
        int carry = carry_s;
        int excl = incl - v + carry;
        if (i < n) { row_ptr[i] = excl; cursor[i] = excl; }
        __syncthreads();
        if (t == 1023) carry_s = carry + src[1023];
        __syncthreads();
    }
    if (t == 0) row_ptr[n] = carry_s;
}

__global__ void fill_kernel(const int* __restrict__ ei,
                            int* __restrict__ cursor, int* __restrict__ col) {
    int e = blockIdx.x * blockDim.x + threadIdx.x;
    if (e >= ETOT) return;
    int s, d;
    if (e < NEDGES) { s = ei[e]; d = ei[NEDGES + e]; }
    else            { s = d = e - NEDGES; }
    int pos = atomicAdd(&cursor[d], 1);
    col[pos] = s;
}

__global__ void dinv_kernel(const int* __restrict__ deg, float* __restrict__ dinv, int n) {
    int i = blockIdx.x * blockDim.x + threadIdx.x;
    if (i < n) dinv[i] = rsqrtf((float)deg[i]);   // deg >= 1 (self-loop)
}

// ---------------------------------------------------------------------------
// batch row ranges (batch is sorted): start[b] = lower_bound(batch, b)
// ---------------------------------------------------------------------------
__global__ void bstart_kernel(const int* __restrict__ batch, int n, int* __restrict__ start) {
    int b = threadIdx.x;
    if (b > NBATCH) return;
    int lo = 0, hi = n;
    while (lo < hi) { int mid = (lo + hi) >> 1; if (batch[mid] < b) lo = mid + 1; else hi = mid; }
    start[b] = lo;
}

// ---------------------------------------------------------------------------
// GEMM1: C_bf16[M,N] = A_f32[M,K] @ B_f32[K,N]
// 64x64 tile, BK=16, 256 threads, 4x4 per thread
// ---------------------------------------------------------------------------
__global__ __launch_bounds__(256) void gemm1_kernel(
        const float* __restrict__ A, const float* __restrict__ B,
        unsigned short* __restrict__ C, int M, int K, int N) {
    __shared__ float As[16][65];
    __shared__ float Bs[16][64];
    int tid = threadIdx.x;
    int bm = blockIdx.y * 64, bn = blockIdx.x * 64;
    int am = tid >> 2;
    int ak = (tid & 3) * 4;
    int bk = tid >> 4;
    int bnl = (tid & 15) * 4;
    int ty = tid >> 4, tx = tid & 15;
    float acc[4][4] = {};
    for (int k0 = 0; k0 < K; k0 += 16) {
        float a0 = 0.f, a1 = 0.f, a2 = 0.f, a3 = 0.f;
        int arow = bm + am;
        int kk = k0 + ak;
        if (arow < M) {
            const float* ap = A + (size_t)arow * K + kk;
            if (kk + 0 < K) a0 = ap[0];
            if (kk + 1 < K) a1 = ap[1];
            if (kk + 2 < K) a2 = ap[2];
            if (kk + 3 < K) a3 = ap[3];
        }
        float b0 = 0.f, b1 = 0.f, b2 = 0.f, b3 = 0.f;
        int brow = k0 + bk;
        if (brow < K) {
            int cc = bn + bnl;
            const float* bp = B + (size_t)brow * N + cc;
            if (cc + 3 < N) { float4 v = *(const float4*)bp; b0=v.x; b1=v.y; b2=v.z; b3=v.w; }
            else {
                if (cc + 0 < N) b0 = bp[0];
                if (cc + 1 < N) b1 = bp[1];
                if (cc + 2 < N) b2 = bp[2];
            }
        }
        __syncthreads();
        As[ak + 0][am] = a0; As[ak + 1][am] = a1;
        As[ak + 2][am] = a2; As[ak + 3][am] = a3;
        Bs[bk][bnl + 0] = b0; Bs[bk][bnl + 1] = b1;
        Bs[bk][bnl + 2] = b2; Bs[bk][bnl + 3] = b3;
        __syncthreads();
        #pragma unroll
        for (int k2 = 0; k2 < 16; k2++) {
            float ar[4], br[4];
            #pragma unroll
            for (int i = 0; i < 4; i++) { ar[i] = As[k2][ty * 4 + i]; br[i] = Bs[k2][tx * 4 + i]; }
            #pragma unroll
            for (int i = 0; i < 4; i++)
                #pragma unroll
                for (int j = 0; j < 4; j++)
                    acc[i][j] = fmaf(ar[i], br[j], acc[i][j]);
        }
    }
    #pragma unroll
    for (int i = 0; i < 4; i++) {
        int row = bm + ty * 4 + i;
        if (row >= M) continue;
        #pragma unroll
        for (int j = 0; j < 4; j++) {
            int cc = bn + tx * 4 + j;
            if (cc >= N) continue;
            C[(size_t)row * N + cc] = f2bf(acc[i][j]);
        }
    }
}

// ---------------------------------------------------------------------------
// GATv2 aggregation: one wave per (node, head); online softmax over in-edges.
// xl, xr bf16; h_out (bf16) aliases xr (each wave writes only its own slice).
// ---------------------------------------------------------------------------
__global__ __launch_bounds__(256) void gat_kernel(
        const unsigned short* __restrict__ xl, const unsigned short* xr,
        const int* __restrict__ row_ptr, const int* __restrict__ col,
        const float* __restrict__ att, const float* __restrict__ bias1,
        unsigned short* h_out) {
    int wave = blockIdx.x * (blockDim.x >> 6) + (threadIdx.x >> 6);
    int lane = threadIdx.x & 63;
    int node = wave / NHEADS;
    int head = wave - node * NHEADS;
    if (node >= NNODES) return;
    const int c1 = lane;
    const bool has2 = lane < (CDIM - 64);   // lanes 0..13 hold c = 64+lane
    const int c2 = 64 + lane;
    size_t hb = (size_t)head * CDIM;
    float at1 = att[hb + c1];
    float at2 = has2 ? att[hb + c2] : 0.f;
    size_t xr_off = (size_t)node * HCDIM + hb;
    float xr1 = bf2f(xr[xr_off + c1]);
    float xr2 = has2 ? bf2f(xr[xr_off + c2]) : 0.f;
    float m = -INFINITY, l = 0.f, acc1 = 0.f, acc2 = 0.f;
    int e0 = row_ptr[node], e1 = row_ptr[node + 1];
    for (int e = e0; e < e1; e++) {
        int j = col[e];
        size_t xo = (size_t)j * HCDIM + hb;
        float v1 = bf2f(xl[xo + c1]);
        float v2 = has2 ? bf2f(xl[xo + c2]) : 0.f;
        float t1 = v1 + xr1, t2 = v2 + xr2;
        t1 = t1 > 0.f ? t1 : NEG_SLOPE * t1;
        t2 = t2 > 0.f ? t2 : NEG_SLOPE * t2;
        float part = t1 * at1 + (has2 ? t2 * at2 : 0.f);
        #pragma unroll
        for (int off = 32; off; off >>= 1) part += __shfl_xor(part, off, 64);
        float s = part;
        float mnew = fmaxf(m, s);
        float scale = __expf(m - mnew);   // first iter: exp(-inf) = 0
        float p = __expf(s - mnew);
        l = l * scale + p;
        acc1 = acc1 * scale + p * v1;
        acc2 = acc2 * scale + p * v2;
        m = mnew;
    }
    float inv = 1.f / l;
    float r1 = acc1 * inv + bias1[hb + c1];
    r1 = r1 > 0.f ? r1 : (__expf(r1) - 1.f);   // ELU
    h_out[xr_off + c1] = f2bf(r1);
    if (has2) {
        float r2 = acc2 * inv + bias1[hb + c2];
        r2 = r2 > 0.f ? r2 : (__expf(r2) - 1.f);
        h_out[xr_off + c2] = f2bf(r2);
    }
}

// ---------------------------------------------------------------------------
// GCN aggregation: agg[i] = dinv[i] * sum_j dinv[j] * h[j]   (bf16 in/out)
// one block (256 thr) per node; threads stride the 780 columns
// ---------------------------------------------------------------------------
__global__ __launch_bounds__(256) void gcn_agg_kernel(
        const unsigned short* __restrict__ h, const int* __restrict__ row_ptr,
        const int* __restrict__ col, const float* __restrict__ dinv,
        unsigned short* __restrict__ agg) {
    int i = blockIdx.x;
    int t = threadIdx.x;
    bool has3 = t < (HCDIM - 768);   // t < 12
    float a0 = 0.f, a1 = 0.f, a2 = 0.f, a3 = 0.f;
    int e0 = row_ptr[i], e1 = row_ptr[i + 1];
    for (int e = e0; e < e1; e++) {
        int j = col[e];
        float s = dinv[j];
        const unsigned short* hr = h + (size_t)j * HCDIM;
        a0 += s * bf2f(hr[t]);
        a1 += s * bf2f(hr[t + 256]);
        a2 += s * bf2f(hr[t + 512]);
        if (has3) a3 += s * bf2f(hr[t + 768]);
    }
    float di = dinv[i];
    unsigned short* ar = agg + (size_t)i * HCDIM;
    ar[t] = f2bf(a0 * di); ar[t + 256] = f2bf(a1 * di); ar[t + 512] = f2bf(a2 * di);
    if (has3) ar[t + 768] = f2bf(a3 * di);
}

// ---------------------------------------------------------------------------
// GEMM2 fused: h2 = relu(agg_bf16 @ W_gcn_f32 + bias); segment max/mean pool
// into out via atomics (sum finalized by finalize_kernel).
// ---------------------------------------------------------------------------
__global__ __launch_bounds__(256) void gemm2_pool_kernel(
        const unsigned short* __restrict__ A, const float* __restrict__ B,
        const float* __restrict__ bias, const int* __restrict__ batch,
        float* __restrict__ out, int M, int K, int N) {
    __shared__ float As[16][65];
    __shared__ float Bs[16][64];
    __shared__ float Cs[64][65];
    __shared__ int   bsh[64];
    int tid = threadIdx.x;
    int bm = blockIdx.y * 64, bn = blockIdx.x * 64;
    if (tid < 64) {
        int row = bm + tid;
        bsh[tid] = (row < M) ? batch[row] : -1;
    }
    int am = tid >> 2;
    int ak = (tid & 3) * 4;
    int bk = tid >> 4;
    int bnl = (tid & 15) * 4;
    int ty = tid >> 4, tx = tid & 15;
    float acc[4][4] = {};
    for (int k0 = 0; k0 < K; k0 += 16) {
        float a0 = 0.f, a1 = 0.f, a2 = 0.f, a3 = 0.f;
        int arow = bm + am;
        int kk = k0 + ak;
        if (arow < M) {
            const unsigned short* ap = A + (size_t)arow * K + kk;
            if (kk + 3 < K) {
                ushort4 u = *(const ushort4*)ap;
                a0 = bf2f(u.x); a1 = bf2f(u.y); a2 = bf2f(u.z); a3 = bf2f(u.w);
            } else {
                if (kk + 0 < K) a0 = bf2f(ap[0]);
                if (kk + 1 < K) a1 = bf2f(ap[1]);
                if (kk + 2 < K) a2 = bf2f(ap[2]);
            }
        }
        float b0 = 0.f, b1 = 0.f, b2 = 0.f, b3 = 0.f;
        int brow = k0 + bk;
        if (brow < K) {
            int cc = bn + bnl;
            const float* bp = B + (size_t)brow * N + cc;
            if (cc + 3 < N) { float4 v = *(const float4*)bp; b0=v.x; b1=v.y; b2=v.z; b3=v.w; }
            else {
                if (cc + 0 < N) b0 = bp[0];
                if (cc + 1 < N) b1 = bp[1];
                if (cc + 2 < N) b2 = bp[2];
            }
        }
        __syncthreads();
        As[ak + 0][am] = a0; As[ak + 1][am] = a1;
        As[ak + 2][am] = a2; As[ak + 3][am] = a3;
        Bs[bk][bnl + 0] = b0; Bs[bk][bnl + 1] = b1;
        Bs[bk][bnl + 2] = b2; Bs[bk][bnl + 3] = b3;
        __syncthreads();
        #pragma unroll
        for (int k2 = 0; k2 < 16; k2++) {
            float ar[4], br[4];
            #pragma unroll
            for (int i = 0; i < 4; i++) { ar[i] = As[k2][ty * 4 + i]; br[i] = Bs[k2][tx * 4 + i]; }
            #pragma unroll
            for (int i = 0; i < 4; i++)
                #pragma unroll
                for (int j = 0; j < 4; j++)
                    acc[i][j] = fmaf(ar[i], br[j], acc[i][j]);
        }
    }
    // epilogue: bias + relu into LDS C tile
    #pragma unroll
    for (int i = 0; i < 4; i++) {
        #pragma unroll
        for (int j = 0; j < 4; j++) {
            int cc = bn + tx * 4 + j;
            float v = 0.f;
            if (cc < N) { v = acc[i][j] + bias[cc]; v = v > 0.f ? v : 0.f; }
            Cs[ty * 4 + i][tx * 4 + j] = v;
        }
    }
    __syncthreads();
    // segmented max/sum over the 64 rows (sorted batch ids), 4 threads/col
    int colw = tid & 63;
    int r0 = (tid >> 6) * 16;
    int gc = bn + colw;
    bool gcvalid = gc < N;
    int cur = -1; float mx = 0.f, sm = 0.f;
    for (int r = r0; r < r0 + 16; r++) {
        int b = bsh[r];
        if (b < 0) break;                  // invalid rows only at tile end
        float v = Cs[r][colw];
        if (b != cur) {
            if (cur >= 0 && gcvalid) {
                atomicMax((int*)(out + (size_t)cur * (2 * HCDIM) + gc), __float_as_int(mx));
                atomicAdd(out + (size_t)cur * (2 * HCDIM) + HCDIM + gc, sm);
            }
            cur = b; mx = v; sm = v;
        } else { mx = fmaxf(mx, v); sm += v; }
    }
    if (cur >= 0 && gcvalid) {
        atomicMax((int*)(out + (size_t)cur * (2 * HCDIM) + gc), __float_as_int(mx));
        atomicAdd(out + (size_t)cur * (2 * HCDIM) + HCDIM + gc, sm);
    }
}

// divide the mean slots by counts
__global__ void finalize_kernel(float* __restrict__ out, const int* __restrict__ bst) {
    int i = blockIdx.x * blockDim.x + threadIdx.x;
    if (i >= NBATCH * HCDIM) return;
    int b = i / HCDIM, c = i - b * HCDIM;
    int cnt = bst[b + 1] - bst[b];
    out[(size_t)b * (2 * HCDIM) + HCDIM + c] /= (float)(cnt > 0 ? cnt : 1);
}

// ---------------------------------------------------------------------------
extern "C" void kernel_launch(void* const* d_in, const int* in_sizes, int n_in,
                              void* d_out, int out_size, void* d_ws, size_t ws_size,
                              hipStream_t stream) {
    const float* x       = (const float*)d_in[0];
    const int*   ei      = (const int*)d_in[1];   // [2, E]
    const int*   batch   = (const int*)d_in[2];   // [N], sorted
    const float* W_l     = (const float*)d_in[3];
    const float* W_r     = (const float*)d_in[4];
    const float* att     = (const float*)d_in[5];
    const float* bias1   = (const float*)d_in[6];
    const float* W_gcn   = (const float*)d_in[7];
    const float* bias_gcn= (const float*)d_in[8];
    float* out = (float*)d_out;

    char* w = (char*)d_ws;
    const size_t BIGH = (size_t)NNODES * HCDIM * sizeof(unsigned short);  // 78,000,000
    unsigned short* xl  = (unsigned short*)(w);          // later reused as agg
    unsigned short* xr  = (unsigned short*)(w + BIGH);   // becomes h after GAT
    unsigned short* agg = xl;                            // xl dead after gat_kernel
    char* sm = w + 2 * BIGH;
    int*   deg  = (int*)(sm);                    sm += 50048 * 4;
    int*   rowp = (int*)(sm);                    sm += 50048 * 4;
    int*   curs = (int*)(sm);                    sm += 50048 * 4;
    int*   col  = (int*)(sm);                    sm += 450048 * 4;
    float* dinv = (float*)(sm);                  sm += 50048 * 4;
    int*   bst  = (int*)(sm);                    sm += 512 * 4;
    size_t needed = (size_t)(sm - (char*)d_ws);
    if (ws_size < needed) return;   // fail soft (wrong result) instead of OOB fault

    // --- zero-init (out for atomics; deg for CSR count) ---
    zero_f_kernel<<<(NBATCH * 2 * HCDIM + 255) / 256, 256, 0, stream>>>(out, NBATCH * 2 * HCDIM);
    zero_i_kernel<<<(NNODES + 255) / 256, 256, 0, stream>>>(deg, NNODES);

    // --- CSR build ---
    {
        int blocks = (ETOT + 255) / 256;
        count_kernel<<<blocks, 256, 0, stream>>>(ei, deg);
        scan_kernel<<<1, 1024, 0, stream>>>(deg, NNODES, rowp, curs);
        fill_kernel<<<blocks, 256, 0, stream>>>(ei, curs, col);
        dinv_kernel<<<(NNODES + 255) / 256, 256, 0, stream>>>(deg, dinv, NNODES);
        bstart_kernel<<<1, 512, 0, stream>>>(batch, NNODES, bst);
    }

    // --- xl = x @ W_l ; xr = x @ W_r (bf16 out) ---
    {
        dim3 grid((HCDIM + 63) / 64, (NNODES + 63) / 64);
        gemm1_kernel<<<grid, 256, 0, stream>>>(x, W_l, xl, NNODES, INDIM, HCDIM);
        gemm1_kernel<<<grid, 256, 0, stream>>>(x, W_r, xr, NNODES, INDIM, HCDIM);
    }

    // --- GATv2 + ELU (writes h over xr) ---
    {
        int pairs = NNODES * NHEADS;            // 500000 waves
        int blocks = (pairs + 3) / 4;           // 4 waves / block
        gat_kernel<<<blocks, 256, 0, stream>>>(xl, xr, rowp, col, att, bias1, xr);
    }

    // --- GCN aggregate (bf16 h -> bf16 agg, overwrites xl space) ---
    gcn_agg_kernel<<<NNODES, 256, 0, stream>>>(xr, rowp, col, dinv, agg);

    // --- GEMM2 + bias + relu + fused segment max/mean pooling ---
    {
        dim3 grid((HCDIM + 63) / 64, (NNODES + 63) / 64);
        gemm2_pool_kernel<<<grid, 256, 0, stream>>>(agg, W_gcn, bias_gcn, batch,
                                                    out, NNODES, HCDIM, HCDIM);
    }

    // --- finalize means ---
    finalize_kernel<<<(NBATCH * HCDIM + 255) / 256, 256, 0, stream>>>(out, bst);
}

// Round 3
// 1479.582 us; speedup vs baseline: 1.3509x; 1.3509x over previous
//
#include <hip/hip_runtime.h>
#include <hip/hip_bf16.h>
#include <math.h>

#define NNODES   50000
#define INDIM    78
#define NHEADS   10
#define CDIM     78
#define HCDIM    780
#define NEDGES   400000
#define NBATCH   256
#define ETOT     (NEDGES + NNODES)   // 450000, with self-loops
#define NEG_SLOPE 0.2f

// GEMM2 MFMA tiling
#define BM 128
#define BN 128
#define BK 32
#define KPAD 800          // 25 * 32
#define NPAD 896          // 7 * 128
#define LDA 40            // LDS row stride (elems) for As/Bs: 80 B, 16B-aligned
#define LDC 132           // LDS row stride for bf16 C tile

typedef __attribute__((ext_vector_type(8))) short bf16x8_t;
typedef __attribute__((ext_vector_type(4))) float f32x4_t;

// bf16 <-> f32 helpers
__device__ __forceinline__ float bf2f(unsigned short u) {
    union { unsigned int i; float f; } v; v.i = ((unsigned int)u) << 16; return v.f;
}
__device__ __forceinline__ unsigned short f2bf(float f) {
    __hip_bfloat16 h = __float2bfloat16(f);
    return *reinterpret_cast<unsigned short*>(&h);
}

// ---------------------------------------------------------------------------
// zero-init
// ---------------------------------------------------------------------------
__global__ void zero_f_kernel(float* __restrict__ p, int n) {
    int i = blockIdx.x * blockDim.x + threadIdx.x;
    if (i < n) p[i] = 0.f;
}
__global__ void zero_i_kernel(int* __restrict__ p, int n) {
    int i = blockIdx.x * blockDim.x + threadIdx.x;
    if (i < n) p[i] = 0;
}

// ---------------------------------------------------------------------------
// CSR build
// ---------------------------------------------------------------------------
__global__ void count_kernel(const int* __restrict__ ei, int* __restrict__ deg) {
    int e = blockIdx.x * blockDim.x + threadIdx.x;
    if (e >= ETOT) return;
    int d = (e < NEDGES) ? ei[NEDGES + e] : (e - NEDGES);
    atomicAdd(&deg[d], 1);
}

__global__ void scan_kernel(const int* __restrict__ deg, int n,
                            int* __restrict__ row_ptr, int* __restrict__ cursor) {
    __shared__ int bufA[1024];
    __shared__ int bufB[1024];
    __shared__ int carry_s;
    int t = threadIdx.x;
    if (t == 0) carry_s = 0;
    __syncthreads();
    for (int base = 0; base < n; base += 1024) {
        int i = base + t;
        int v = (i < n) ? deg[i] : 0;
        bufA[t] = v;
        __syncthreads();
        int* src = bufA; int* dst = bufB;
        for (int off = 1; off < 1024; off <<= 1) {
            int val = src[t] + ((t >= off) ? src[t - off] : 0);
            dst[t] = val;
            __syncthreads();
            int* tp = src; src = dst; dst = tp;
        }
        int incl = src[t];
        int carry = carry_s;
        int excl = incl - v + carry;
        if (i < n) { row_ptr[i] = excl; cursor[i] = excl; }
        __syncthreads();
        if (t == 1023) carry_s = carry + src[1023];
        __syncthreads();
    }
    if (t == 0) row_ptr[n] = carry_s;
}

__global__ void fill_kernel(const int* __restrict__ ei,
                            int* __restrict__ cursor, int* __restrict__ col) {
    int e = blockIdx.x * blockDim.x + threadIdx.x;
    if (e >= ETOT) return;
    int s, d;
    if (e < NEDGES) { s = ei[e]; d = ei[NEDGES + e]; }
    else            { s = d = e - NEDGES; }
    int pos = atomicAdd(&cursor[d], 1);
    col[pos] = s;
}

__global__ void dinv_kernel(const int* __restrict__ deg, float* __restrict__ dinv, int n) {
    int i = blockIdx.x * blockDim.x + threadIdx.x;
    if (i < n) dinv[i] = rsqrtf((float)deg[i]);
}

__global__ void bstart_kernel(const int* __restrict__ batch, int n, int* __restrict__ start) {
    int b = threadIdx.x;
    if (b > NBATCH) return;
    int lo = 0, hi = n;
    while (lo < hi) { int mid = (lo + hi) >> 1; if (batch[mid] < b) lo = mid + 1; else hi = mid; }
    start[b] = lo;
}

// ---------------------------------------------------------------------------
// GEMM1: C_bf16[M,N] = A_f32[M,K] @ B_f32[K,N]   (64x64 tile, fp32 VALU)
// ---------------------------------------------------------------------------
__global__ __launch_bounds__(256) void gemm1_kernel(
        const float* __restrict__ A, const float* __restrict__ B,
        unsigned short* __restrict__ C, int M, int K, int N) {
    __shared__ float As[16][65];
    __shared__ float Bs[16][64];
    int tid = threadIdx.x;
    int bm = blockIdx.y * 64, bn = blockIdx.x * 64;
    int am = tid >> 2;
    int ak = (tid & 3) * 4;
    int bk = tid >> 4;
    int bnl = (tid & 15) * 4;
    int ty = tid >> 4, tx = tid & 15;
    float acc[4][4] = {};
    for (int k0 = 0; k0 < K; k0 += 16) {
        float a0 = 0.f, a1 = 0.f, a2 = 0.f, a3 = 0.f;
        int arow = bm + am;
        int kk = k0 + ak;
        if (arow < M) {
            const float* ap = A + (size_t)arow * K + kk;
            if (kk + 0 < K) a0 = ap[0];
            if (kk + 1 < K) a1 = ap[1];
            if (kk + 2 < K) a2 = ap[2];
            if (kk + 3 < K) a3 = ap[3];
        }
        float b0 = 0.f, b1 = 0.f, b2 = 0.f, b3 = 0.f;
        int brow = k0 + bk;
        if (brow < K) {
            int cc = bn + bnl;
            const float* bp = B + (size_t)brow * N + cc;
            if (cc + 3 < N) { float4 v = *(const float4*)bp; b0=v.x; b1=v.y; b2=v.z; b3=v.w; }
            else {
                if (cc + 0 < N) b0 = bp[0];
                if (cc + 1 < N) b1 = bp[1];
                if (cc + 2 < N) b2 = bp[2];
            }
        }
        __syncthreads();
        As[ak + 0][am] = a0; As[ak + 1][am] = a1;
        As[ak + 2][am] = a2; As[ak + 3][am] = a3;
        Bs[bk][bnl + 0] = b0; Bs[bk][bnl + 1] = b1;
        Bs[bk][bnl + 2] = b2; Bs[bk][bnl + 3] = b3;
        __syncthreads();
        #pragma unroll
        for (int k2 = 0; k2 < 16; k2++) {
            float ar[4], br[4];
            #pragma unroll
            for (int i = 0; i < 4; i++) { ar[i] = As[k2][ty * 4 + i]; br[i] = Bs[k2][tx * 4 + i]; }
            #pragma unroll
            for (int i = 0; i < 4; i++)
                #pragma unroll
                for (int j = 0; j < 4; j++)
                    acc[i][j] = fmaf(ar[i], br[j], acc[i][j]);
        }
    }
    #pragma unroll
    for (int i = 0; i < 4; i++) {
        int row = bm + ty * 4 + i;
        if (row >= M) continue;
        #pragma unroll
        for (int j = 0; j < 4; j++) {
            int cc = bn + tx * 4 + j;
            if (cc >= N) continue;
            C[(size_t)row * N + cc] = f2bf(acc[i][j]);
        }
    }
}

// ---------------------------------------------------------------------------
// GATv2 aggregation (unchanged from round 2)
// ---------------------------------------------------------------------------
__global__ __launch_bounds__(256) void gat_kernel(
        const unsigned short* __restrict__ xl, const unsigned short* xr,
        const int* __restrict__ row_ptr, const int* __restrict__ col,
        const float* __restrict__ att, const float* __restrict__ bias1,
        unsigned short* h_out) {
    int wave = blockIdx.x * (blockDim.x >> 6) + (threadIdx.x >> 6);
    int lane = threadIdx.x & 63;
    int node = wave / NHEADS;
    int head = wave - node * NHEADS;
    if (node >= NNODES) return;
    const int c1 = lane;
    const bool has2 = lane < (CDIM - 64);
    const int c2 = 64 + lane;
    size_t hb = (size_t)head * CDIM;
    float at1 = att[hb + c1];
    float at2 = has2 ? att[hb + c2] : 0.f;
    size_t xr_off = (size_t)node * HCDIM + hb;
    float xr1 = bf2f(xr[xr_off + c1]);
    float xr2 = has2 ? bf2f(xr[xr_off + c2]) : 0.f;
    float m = -INFINITY, l = 0.f, acc1 = 0.f, acc2 = 0.f;
    int e0 = row_ptr[node], e1 = row_ptr[node + 1];
    for (int e = e0; e < e1; e++) {
        int j = col[e];
        size_t xo = (size_t)j * HCDIM + hb;
        float v1 = bf2f(xl[xo + c1]);
        float v2 = has2 ? bf2f(xl[xo + c2]) : 0.f;
        float t1 = v1 + xr1, t2 = v2 + xr2;
        t1 = t1 > 0.f ? t1 : NEG_SLOPE * t1;
        t2 = t2 > 0.f ? t2 : NEG_SLOPE * t2;
        float part = t1 * at1 + (has2 ? t2 * at2 : 0.f);
        #pragma unroll
        for (int off = 32; off; off >>= 1) part += __shfl_xor(part, off, 64);
        float s = part;
        float mnew = fmaxf(m, s);
        float scale = __expf(m - mnew);
        float p = __expf(s - mnew);
        l = l * scale + p;
        acc1 = acc1 * scale + p * v1;
        acc2 = acc2 * scale + p * v2;
        m = mnew;
    }
    float inv = 1.f / l;
    float r1 = acc1 * inv + bias1[hb + c1];
    r1 = r1 > 0.f ? r1 : (__expf(r1) - 1.f);
    h_out[xr_off + c1] = f2bf(r1);
    if (has2) {
        float r2 = acc2 * inv + bias1[hb + c2];
        r2 = r2 > 0.f ? r2 : (__expf(r2) - 1.f);
        h_out[xr_off + c2] = f2bf(r2);
    }
}

// ---------------------------------------------------------------------------
// GCN aggregation (unchanged)
// ---------------------------------------------------------------------------
__global__ __launch_bounds__(256) void gcn_agg_kernel(
        const unsigned short* __restrict__ h, const int* __restrict__ row_ptr,
        const int* __restrict__ col, const float* __restrict__ dinv,
        unsigned short* __restrict__ agg) {
    int i = blockIdx.x;
    int t = threadIdx.x;
    bool has3 = t < (HCDIM - 768);
    float a0 = 0.f, a1 = 0.f, a2 = 0.f, a3 = 0.f;
    int e0 = row_ptr[i], e1 = row_ptr[i + 1];
    for (int e = e0; e < e1; e++) {
        int j = col[e];
        float s = dinv[j];
        const unsigned short* hr = h + (size_t)j * HCDIM;
        a0 += s * bf2f(hr[t]);
        a1 += s * bf2f(hr[t + 256]);
        a2 += s * bf2f(hr[t + 512]);
        if (has3) a3 += s * bf2f(hr[t + 768]);
    }
    float di = dinv[i];
    unsigned short* ar = agg + (size_t)i * HCDIM;
    ar[t] = f2bf(a0 * di); ar[t + 256] = f2bf(a1 * di); ar[t + 512] = f2bf(a2 * di);
    if (has3) ar[t + 768] = f2bf(a3 * di);
}

// ---------------------------------------------------------------------------
// BT prep: BT[n][k] = bf16(W_gcn[k][n]), zero-padded to [NPAD][KPAD]
// ---------------------------------------------------------------------------
__global__ void btprep_kernel(const float* __restrict__ W, unsigned short* __restrict__ BT) {
    int idx = blockIdx.x * 256 + threadIdx.x;
    if (idx >= NPAD * KPAD) return;
    int n = idx / KPAD, k = idx - n * KPAD;
    float v = (n < HCDIM && k < HCDIM) ? W[(size_t)k * HCDIM + n] : 0.f;
    BT[idx] = f2bf(v);
}

// ---------------------------------------------------------------------------
// GEMM2 MFMA fused: h2 = relu(agg_bf16 @ W_gcn + bias); segment max/mean pool.
// A: [M,780] bf16 row-major (unpadded). BT: [NPAD][KPAD] bf16 (B transposed,
// zero-padded). 128x128 tile, BK=32, 4 waves (2x2) each 64x64 via 16x16x32.
// ---------------------------------------------------------------------------
__global__ __launch_bounds__(256) void gemm2_pool_kernel(
        const unsigned short* __restrict__ A, const unsigned short* __restrict__ BT,
        const float* __restrict__ bias, const int* __restrict__ batch,
        float* __restrict__ out, int M) {
    // union LDS: staging (As+Bs = 20,480 B) vs epilogue C tile (33,792 B)
    __shared__ unsigned short smem[BM * LDC];          // 33,792 B
    unsigned short* As = smem;                          // [BM][LDA]
    unsigned short* Bs = smem + BM * LDA;               // [BN][LDA]
    __shared__ int bsh[BM];

    int t = threadIdx.x;
    int bm = blockIdx.y * BM, bn = blockIdx.x * BN;

    if (t < BM) {
        int row = bm + t;
        bsh[t] = (row < M) ? batch[row] : -1;
    }

    int lane = t & 63, w = t >> 6;
    int wr = (w >> 1) * 64, wc = (w & 1) * 64;
    int m16 = lane & 15, q = lane >> 4;

    // staging mapping: thread -> (row r, 16-elem chunk c0)
    int r = t >> 1;
    int c0 = (t & 1) * 16;

    f32x4_t acc[4][4];
    #pragma unroll
    for (int i = 0; i < 4; i++)
        #pragma unroll
        for (int j = 0; j < 4; j++)
            acc[i][j] = (f32x4_t)(0.f);

    const int gr = bm + r;
    const bool rv = gr < M;
    const unsigned short* aprow = A + (size_t)gr * HCDIM;
    const unsigned short* bprow = BT + (size_t)(bn + r) * KPAD;

    for (int k0 = 0; k0 < KPAD; k0 += BK) {
        // ---- global -> regs ----
        ushort4 av[4], bv[4];
        #pragma unroll
        for (int i = 0; i < 4; i++) {
            int kc = k0 + c0 + 4 * i;
            if (rv && kc <= HCDIM - 4)
                av[i] = *(const ushort4*)(aprow + kc);
            else
                av[i] = make_ushort4(0, 0, 0, 0);
            bv[i] = *(const ushort4*)(bprow + k0 + c0 + 4 * i);
        }
        __syncthreads();   // previous iteration's fragment reads complete
        #pragma unroll
        for (int i = 0; i < 4; i++) {
            *(ushort4*)&As[r * LDA + c0 + 4 * i] = av[i];
            *(ushort4*)&Bs[r * LDA + c0 + 4 * i] = bv[i];
        }
        __syncthreads();
        // ---- fragments + MFMA ----
        bf16x8_t af[4], bf[4];
        #pragma unroll
        for (int i = 0; i < 4; i++)
            af[i] = *(const bf16x8_t*)&As[(wr + i * 16 + m16) * LDA + q * 8];
        #pragma unroll
        for (int j = 0; j < 4; j++)
            bf[j] = *(const bf16x8_t*)&Bs[(wc + j * 16 + m16) * LDA + q * 8];
        #pragma unroll
        for (int i = 0; i < 4; i++)
            #pragma unroll
            for (int j = 0; j < 4; j++)
                acc[i][j] = __builtin_amdgcn_mfma_f32_16x16x32_bf16(af[i], bf[j], acc[i][j], 0, 0, 0);
    }

    __syncthreads();   // all frag reads done before Cs overwrites staging
    // ---- epilogue: bias + relu -> bf16 C tile in LDS ----
    // C/D layout: col = lane&15, row = quad*4 + reg
    #pragma unroll
    for (int i = 0; i < 4; i++) {
        #pragma unroll
        for (int j = 0; j < 4; j++) {
            int colc = wc + j * 16 + m16;
            int gcc = bn + colc;
            float bv = (gcc < HCDIM) ? bias[gcc] : 0.f;
            #pragma unroll
            for (int rr = 0; rr < 4; rr++) {
                int rowc = wr + i * 16 + q * 4 + rr;
                float v = acc[i][j][rr] + bv;
                v = v > 0.f ? v : 0.f;
                smem[rowc * LDC + colc] = f2bf(v);
            }
        }
    }
    __syncthreads();
    // ---- segmented max/sum over 128 sorted rows; 2 groups x 64 rows ----
    int colp = t & 127;
    int grp = t >> 7;
    int gc = bn + colp;
    if (gc < HCDIM) {
        int cur = -1; float mx = 0.f, sm = 0.f;
        int rbeg = grp * 64, rend = rbeg + 64;
        for (int rr = rbeg; rr < rend; rr++) {
            int b = bsh[rr];
            if (b < 0) break;
            float v = bf2f(smem[rr * LDC + colp]);
            if (b != cur) {
                if (cur >= 0) {
                    atomicMax((int*)(out + (size_t)cur * (2 * HCDIM) + gc), __float_as_int(mx));
                    atomicAdd(out + (size_t)cur * (2 * HCDIM) + HCDIM + gc, sm);
                }
                cur = b; mx = v; sm = v;
            } else { mx = fmaxf(mx, v); sm += v; }
        }
        if (cur >= 0) {
            atomicMax((int*)(out + (size_t)cur * (2 * HCDIM) + gc), __float_as_int(mx));
            atomicAdd(out + (size_t)cur * (2 * HCDIM) + HCDIM + gc, sm);
        }
    }
}

// divide the mean slots by counts
__global__ void finalize_kernel(float* __restrict__ out, const int* __restrict__ bst) {
    int i = blockIdx.x * blockDim.x + threadIdx.x;
    if (i >= NBATCH * HCDIM) return;
    int b = i / HCDIM, c = i - b * HCDIM;
    int cnt = bst[b + 1] - bst[b];
    out[(size_t)b * (2 * HCDIM) + HCDIM + c] /= (float)(cnt > 0 ? cnt : 1);
}

// ---------------------------------------------------------------------------
extern "C" void kernel_launch(void* const* d_in, const int* in_sizes, int n_in,
                              void* d_out, int out_size, void* d_ws, size_t ws_size,
                              hipStream_t stream) {
    const float* x       = (const float*)d_in[0];
    const int*   ei      = (const int*)d_in[1];
    const int*   batch   = (const int*)d_in[2];
    const float* W_l     = (const float*)d_in[3];
    const float* W_r     = (const float*)d_in[4];
    const float* att     = (const float*)d_in[5];
    const float* bias1   = (const float*)d_in[6];
    const float* W_gcn   = (const float*)d_in[7];
    const float* bias_gcn= (const float*)d_in[8];
    float* out = (float*)d_out;

    char* w = (char*)d_ws;
    const size_t BIGH = (size_t)NNODES * HCDIM * sizeof(unsigned short);  // 78,000,000
    unsigned short* xl  = (unsigned short*)(w);          // later reused as agg
    unsigned short* xr  = (unsigned short*)(w + BIGH);   // becomes h; later BT
    unsigned short* agg = xl;
    unsigned short* BT  = xr;                            // h dead after gcn_agg
    char* sm = w + 2 * BIGH;
    int*   deg  = (int*)(sm);                    sm += 50048 * 4;
    int*   rowp = (int*)(sm);                    sm += 50048 * 4;
    int*   curs = (int*)(sm);                    sm += 50048 * 4;
    int*   col  = (int*)(sm);                    sm += 450048 * 4;
    float* dinv = (float*)(sm);                  sm += 50048 * 4;
    int*   bst  = (int*)(sm);                    sm += 512 * 4;
    size_t needed = (size_t)(sm - (char*)d_ws);
    if (ws_size < needed) return;   // fail soft instead of OOB fault

    // --- zero-init (out for atomics; deg for CSR count) ---
    zero_f_kernel<<<(NBATCH * 2 * HCDIM + 255) / 256, 256, 0, stream>>>(out, NBATCH * 2 * HCDIM);
    zero_i_kernel<<<(NNODES + 255) / 256, 256, 0, stream>>>(deg, NNODES);

    // --- CSR build ---
    {
        int blocks = (ETOT + 255) / 256;
        count_kernel<<<blocks, 256, 0, stream>>>(ei, deg);
        scan_kernel<<<1, 1024, 0, stream>>>(deg, NNODES, rowp, curs);
        fill_kernel<<<blocks, 256, 0, stream>>>(ei, curs, col);
        dinv_kernel<<<(NNODES + 255) / 256, 256, 0, stream>>>(deg, dinv, NNODES);
        bstart_kernel<<<1, 512, 0, stream>>>(batch, NNODES, bst);
    }

    // --- xl = x @ W_l ; xr = x @ W_r (bf16 out) ---
    {
        dim3 grid((HCDIM + 63) / 64, (NNODES + 63) / 64);
        gemm1_kernel<<<grid, 256, 0, stream>>>(x, W_l, xl, NNODES, INDIM, HCDIM);
        gemm1_kernel<<<grid, 256, 0, stream>>>(x, W_r, xr, NNODES, INDIM, HCDIM);
    }

    // --- GATv2 + ELU (writes h over xr) ---
    {
        int pairs = NNODES * NHEADS;
        int blocks = (pairs + 3) / 4;
        gat_kernel<<<blocks, 256, 0, stream>>>(xl, xr, rowp, col, att, bias1, xr);
    }

    // --- GCN aggregate (h -> agg, overwrites xl space) ---
    gcn_agg_kernel<<<NNODES, 256, 0, stream>>>(xr, rowp, col, dinv, agg);

    // --- W_gcn^T -> bf16 padded (into xr region; h is dead) ---
    btprep_kernel<<<(NPAD * KPAD + 255) / 256, 256, 0, stream>>>(W_gcn, BT);

    // --- GEMM2 (MFMA) + bias + relu + fused segment max/mean pooling ---
    {
        dim3 grid(NPAD / BN, (NNODES + BM - 1) / BM);   // (7, 391)
        gemm2_pool_kernel<<<grid, 256, 0, stream>>>(agg, BT, bias_gcn, batch, out, NNODES);
    }

    // --- finalize means ---
    finalize_kernel<<<(NBATCH * HCDIM + 255) / 256, 256, 0, stream>>>(out, bst);
}

// Round 4
// 1134.645 us; speedup vs baseline: 1.7615x; 1.3040x over previous
//
#include <hip/hip_runtime.h>
#include <hip/hip_bf16.h>
#include <math.h>

#define NNODES   50000
#define INDIM    78
#define NHEADS   10
#define CDIM     78
#define HCDIM    780
#define NEDGES   400000
#define NBATCH   256
#define ETOT     (NEDGES + NNODES)   // 450000, with self-loops
#define NEG_SLOPE 0.2f

// GEMM2 MFMA tiling
#define BM 128
#define BN 128
#define BK 32
#define KPAD 800          // 25 * 32
#define NPAD 896          // 7 * 128
#define LDA 40            // LDS row stride (elems) for As/Bs: 80 B, 16B-aligned
#define LDC 132           // LDS row stride for bf16 C tile

typedef __attribute__((ext_vector_type(8))) short bf16x8_t;
typedef __attribute__((ext_vector_type(4))) float f32x4_t;

// bf16 <-> f32 helpers
__device__ __forceinline__ float bf2f(unsigned short u) {
    union { unsigned int i; float f; } v; v.i = ((unsigned int)u) << 16; return v.f;
}
__device__ __forceinline__ unsigned short f2bf(float f) {
    __hip_bfloat16 h = __float2bfloat16(f);
    return *reinterpret_cast<unsigned short*>(&h);
}

// ---------------------------------------------------------------------------
// zero-init
// ---------------------------------------------------------------------------
__global__ void zero_f_kernel(float* __restrict__ p, int n) {
    int i = blockIdx.x * blockDim.x + threadIdx.x;
    if (i < n) p[i] = 0.f;
}
__global__ void zero_i_kernel(int* __restrict__ p, int n) {
    int i = blockIdx.x * blockDim.x + threadIdx.x;
    if (i < n) p[i] = 0;
}

// ---------------------------------------------------------------------------
// CSR build
// ---------------------------------------------------------------------------
__global__ void count_kernel(const int* __restrict__ ei, int* __restrict__ deg) {
    int e = blockIdx.x * blockDim.x + threadIdx.x;
    if (e >= ETOT) return;
    int d = (e < NEDGES) ? ei[NEDGES + e] : (e - NEDGES);
    atomicAdd(&deg[d], 1);
}

__global__ void scan_kernel(const int* __restrict__ deg, int n,
                            int* __restrict__ row_ptr, int* __restrict__ cursor) {
    __shared__ int bufA[1024];
    __shared__ int bufB[1024];
    __shared__ int carry_s;
    int t = threadIdx.x;
    if (t == 0) carry_s = 0;
    __syncthreads();
    for (int base = 0; base < n; base += 1024) {
        int i = base + t;
        int v = (i < n) ? deg[i] : 0;
        bufA[t] = v;
        __syncthreads();
        int* src = bufA; int* dst = bufB;
        for (int off = 1; off < 1024; off <<= 1) {
            int val = src[t] + ((t >= off) ? src[t - off] : 0);
            dst[t] = val;
            __syncthreads();
            int* tp = src; src = dst; dst = tp;
        }
        int incl = src[t];
        int carry = carry_s;
        int excl = incl - v + carry;
        if (i < n) { row_ptr[i] = excl; cursor[i] = excl; }
        __syncthreads();
        if (t == 1023) carry_s = carry + src[1023];
        __syncthreads();
    }
    if (t == 0) row_ptr[n] = carry_s;
}

__global__ void fill_kernel(const int* __restrict__ ei,
                            int* __restrict__ cursor, int* __restrict__ col) {
    int e = blockIdx.x * blockDim.x + threadIdx.x;
    if (e >= ETOT) return;
    int s, d;
    if (e < NEDGES) { s = ei[e]; d = ei[NEDGES + e]; }
    else            { s = d = e - NEDGES; }
    int pos = atomicAdd(&cursor[d], 1);
    col[pos] = s;
}

__global__ void dinv_kernel(const int* __restrict__ deg, float* __restrict__ dinv, int n) {
    int i = blockIdx.x * blockDim.x + threadIdx.x;
    if (i < n) dinv[i] = rsqrtf((float)deg[i]);
}

__global__ void bstart_kernel(const int* __restrict__ batch, int n, int* __restrict__ start) {
    int b = threadIdx.x;
    if (b > NBATCH) return;
    int lo = 0, hi = n;
    while (lo < hi) { int mid = (lo + hi) >> 1; if (batch[mid] < b) lo = mid + 1; else hi = mid; }
    start[b] = lo;
}

// ---------------------------------------------------------------------------
// GEMM1: C_bf16[M,N] = A_f32[M,K] @ B_f32[K,N]   (64x64 tile, fp32 VALU)
// ---------------------------------------------------------------------------
__global__ __launch_bounds__(256) void gemm1_kernel(
        const float* __restrict__ A, const float* __restrict__ B,
        unsigned short* __restrict__ C, int M, int K, int N) {
    __shared__ float As[16][65];
    __shared__ float Bs[16][64];
    int tid = threadIdx.x;
    int bm = blockIdx.y * 64, bn = blockIdx.x * 64;
    int am = tid >> 2;
    int ak = (tid & 3) * 4;
    int bk = tid >> 4;
    int bnl = (tid & 15) * 4;
    int ty = tid >> 4, tx = tid & 15;
    float acc[4][4] = {};
    for (int k0 = 0; k0 < K; k0 += 16) {
        float a0 = 0.f, a1 = 0.f, a2 = 0.f, a3 = 0.f;
        int arow = bm + am;
        int kk = k0 + ak;
        if (arow < M) {
            const float* ap = A + (size_t)arow * K + kk;
            if (kk + 0 < K) a0 = ap[0];
            if (kk + 1 < K) a1 = ap[1];
            if (kk + 2 < K) a2 = ap[2];
            if (kk + 3 < K) a3 = ap[3];
        }
        float b0 = 0.f, b1 = 0.f, b2 = 0.f, b3 = 0.f;
        int brow = k0 + bk;
        if (brow < K) {
            int cc = bn + bnl;
            const float* bp = B + (size_t)brow * N + cc;
            if (cc + 3 < N) { float4 v = *(const float4*)bp; b0=v.x; b1=v.y; b2=v.z; b3=v.w; }
            else {
                if (cc + 0 < N) b0 = bp[0];
                if (cc + 1 < N) b1 = bp[1];
                if (cc + 2 < N) b2 = bp[2];
            }
        }
        __syncthreads();
        As[ak + 0][am] = a0; As[ak + 1][am] = a1;
        As[ak + 2][am] = a2; As[ak + 3][am] = a3;
        Bs[bk][bnl + 0] = b0; Bs[bk][bnl + 1] = b1;
        Bs[bk][bnl + 2] = b2; Bs[bk][bnl + 3] = b3;
        __syncthreads();
        #pragma unroll
        for (int k2 = 0; k2 < 16; k2++) {
            float ar[4], br[4];
            #pragma unroll
            for (int i = 0; i < 4; i++) { ar[i] = As[k2][ty * 4 + i]; br[i] = Bs[k2][tx * 4 + i]; }
            #pragma unroll
            for (int i = 0; i < 4; i++)
                #pragma unroll
                for (int j = 0; j < 4; j++)
                    acc[i][j] = fmaf(ar[i], br[j], acc[i][j]);
        }
    }
    #pragma unroll
    for (int i = 0; i < 4; i++) {
        int row = bm + ty * 4 + i;
        if (row >= M) continue;
        #pragma unroll
        for (int j = 0; j < 4; j++) {
            int cc = bn + tx * 4 + j;
            if (cc >= N) continue;
            C[(size_t)row * N + cc] = f2bf(acc[i][j]);
        }
    }
}

// ---------------------------------------------------------------------------
// GATv2 aggregation v2: one wave per (node, head-quad). 16-lane groups, one
// head per group (head = hq*4 + laneGroup), lane cl covers c = cl + 16k,
// k=0..4. 4-step butterfly within the group; plain exp (scores analytically
// bounded |s| < ~5 -> no max subtraction needed; softmax identical).
// h_out (bf16) aliases xr; each wave writes only its own (node, head) slice.
// ---------------------------------------------------------------------------
__global__ __launch_bounds__(256) void gat_kernel(
        const unsigned short* __restrict__ xl, const unsigned short* xr,
        const int* __restrict__ row_ptr, const int* __restrict__ col,
        const float* __restrict__ att, const float* __restrict__ bias1,
        unsigned short* h_out) {
    int wid = blockIdx.x * 4 + (threadIdx.x >> 6);
    int node = wid / 3;
    int hq = wid - node * 3;
    if (node >= NNODES) return;
    int lane = threadIdx.x & 63;
    int g = lane >> 4;            // group 0..3
    int cl = lane & 15;
    int head = hq * 4 + g;        // 0..11 (10,11 invalid)
    bool hv = head < NHEADS;
    int hoff = head * CDIM;
    size_t rbase = (size_t)node * HCDIM + hoff;

    float attv[5], xrv[5];
    #pragma unroll
    for (int k = 0; k < 5; k++) {
        int c = cl + 16 * k;
        bool cv = hv && (c < CDIM);
        attv[k] = cv ? att[hoff + c] : 0.f;
        xrv[k]  = cv ? bf2f(xr[rbase + c]) : 0.f;
    }

    float l = 0.f;
    float acc[5] = {0.f, 0.f, 0.f, 0.f, 0.f};
    int e0 = row_ptr[node], e1 = row_ptr[node + 1];
    for (int e = e0; e < e1; e++) {
        int j = __builtin_amdgcn_readfirstlane(col[e]);   // wave-uniform row
        const unsigned short* xp = xl + (size_t)j * HCDIM + hoff;
        float v[5], part = 0.f;
        #pragma unroll
        for (int k = 0; k < 5; k++) {
            v[k] = bf2f(xp[cl + 16 * k]);   // OOB-c lanes killed by attv=0
            float t = v[k] + xrv[k];
            t = fmaxf(t, 0.f) + NEG_SLOPE * fminf(t, 0.f);   // leaky relu
            part = fmaf(t, attv[k], part);
        }
        part += __shfl_xor(part, 1, 64);
        part += __shfl_xor(part, 2, 64);
        part += __shfl_xor(part, 4, 64);
        part += __shfl_xor(part, 8, 64);
        float p = __expf(part);
        l += p;
        #pragma unroll
        for (int k = 0; k < 5; k++) acc[k] = fmaf(p, v[k], acc[k]);
    }
    float inv = 1.f / l;          // l > 0 (self-loop)
    if (hv) {
        #pragma unroll
        for (int k = 0; k < 5; k++) {
            int c = cl + 16 * k;
            if (c < CDIM) {
                float r = acc[k] * inv + bias1[hoff + c];
                r = r > 0.f ? r : (__expf(r) - 1.f);   // ELU
                h_out[rbase + c] = f2bf(r);
            }
        }
    }
}

// ---------------------------------------------------------------------------
// GCN aggregation v2: agg[i] = dinv[i] * sum_j dinv[j] * h[j]  (bf16 in/out)
// one block per node; thread t<195 handles columns 4t..4t+3 (ushort4 loads)
// ---------------------------------------------------------------------------
__global__ __launch_bounds__(256) void gcn_agg_kernel(
        const unsigned short* __restrict__ h, const int* __restrict__ row_ptr,
        const int* __restrict__ col, const float* __restrict__ dinv,
        unsigned short* __restrict__ agg) {
    int i = blockIdx.x;
    int t = threadIdx.x;
    if (t >= HCDIM / 4) return;    // 195 active threads
    float a0 = 0.f, a1 = 0.f, a2 = 0.f, a3 = 0.f;
    int e0 = row_ptr[i], e1 = row_ptr[i + 1];
    for (int e = e0; e < e1; e++) {
        int j = col[e];            // block-uniform -> scalarized
        float s = dinv[j];
        ushort4 u = *(const ushort4*)(h + (size_t)j * HCDIM + 4 * t);
        a0 = fmaf(s, bf2f(u.x), a0);
        a1 = fmaf(s, bf2f(u.y), a1);
        a2 = fmaf(s, bf2f(u.z), a2);
        a3 = fmaf(s, bf2f(u.w), a3);
    }
    float di = dinv[i];
    ushort4 o;
    o.x = f2bf(a0 * di); o.y = f2bf(a1 * di);
    o.z = f2bf(a2 * di); o.w = f2bf(a3 * di);
    *(ushort4*)(agg + (size_t)i * HCDIM + 4 * t) = o;
}

// ---------------------------------------------------------------------------
// BT prep: BT[n][k] = bf16(W_gcn[k][n]), zero-padded to [NPAD][KPAD]
// ---------------------------------------------------------------------------
__global__ void btprep_kernel(const float* __restrict__ W, unsigned short* __restrict__ BT) {
    int idx = blockIdx.x * 256 + threadIdx.x;
    if (idx >= NPAD * KPAD) return;
    int n = idx / KPAD, k = idx - n * KPAD;
    float v = (n < HCDIM && k < HCDIM) ? W[(size_t)k * HCDIM + n] : 0.f;
    BT[idx] = f2bf(v);
}

// ---------------------------------------------------------------------------
// GEMM2 MFMA fused: h2 = relu(agg_bf16 @ W_gcn + bias); segment max/mean pool.
// ---------------------------------------------------------------------------
__global__ __launch_bounds__(256) void gemm2_pool_kernel(
        const unsigned short* __restrict__ A, const unsigned short* __restrict__ BT,
        const float* __restrict__ bias, const int* __restrict__ batch,
        float* __restrict__ out, int M) {
    __shared__ unsigned short smem[BM * LDC];          // 33,792 B (union)
    unsigned short* As = smem;                          // [BM][LDA]
    unsigned short* Bs = smem + BM * LDA;               // [BN][LDA]
    __shared__ int bsh[BM];

    int t = threadIdx.x;
    int bm = blockIdx.y * BM, bn = blockIdx.x * BN;

    if (t < BM) {
        int row = bm + t;
        bsh[t] = (row < M) ? batch[row] : -1;
    }

    int lane = t & 63, w = t >> 6;
    int wr = (w >> 1) * 64, wc = (w & 1) * 64;
    int m16 = lane & 15, q = lane >> 4;

    int r = t >> 1;
    int c0 = (t & 1) * 16;

    f32x4_t acc[4][4];
    #pragma unroll
    for (int i = 0; i < 4; i++)
        #pragma unroll
        for (int j = 0; j < 4; j++)
            acc[i][j] = (f32x4_t)(0.f);

    const int gr = bm + r;
    const bool rv = gr < M;
    const unsigned short* aprow = A + (size_t)gr * HCDIM;
    const unsigned short* bprow = BT + (size_t)(bn + r) * KPAD;

    for (int k0 = 0; k0 < KPAD; k0 += BK) {
        ushort4 av[4], bv[4];
        #pragma unroll
        for (int i = 0; i < 4; i++) {
            int kc = k0 + c0 + 4 * i;
            if (rv && kc <= HCDIM - 4)
                av[i] = *(const ushort4*)(aprow + kc);
            else
                av[i] = make_ushort4(0, 0, 0, 0);
            bv[i] = *(const ushort4*)(bprow + k0 + c0 + 4 * i);
        }
        __syncthreads();
        #pragma unroll
        for (int i = 0; i < 4; i++) {
            *(ushort4*)&As[r * LDA + c0 + 4 * i] = av[i];
            *(ushort4*)&Bs[r * LDA + c0 + 4 * i] = bv[i];
        }
        __syncthreads();
        bf16x8_t af[4], bf[4];
        #pragma unroll
        for (int i = 0; i < 4; i++)
            af[i] = *(const bf16x8_t*)&As[(wr + i * 16 + m16) * LDA + q * 8];
        #pragma unroll
        for (int j = 0; j < 4; j++)
            bf[j] = *(const bf16x8_t*)&Bs[(wc + j * 16 + m16) * LDA + q * 8];
        #pragma unroll
        for (int i = 0; i < 4; i++)
            #pragma unroll
            for (int j = 0; j < 4; j++)
                acc[i][j] = __builtin_amdgcn_mfma_f32_16x16x32_bf16(af[i], bf[j], acc[i][j], 0, 0, 0);
    }

    __syncthreads();
    #pragma unroll
    for (int i = 0; i < 4; i++) {
        #pragma unroll
        for (int j = 0; j < 4; j++) {
            int colc = wc + j * 16 + m16;
            int gcc = bn + colc;
            float bv = (gcc < HCDIM) ? bias[gcc] : 0.f;
            #pragma unroll
            for (int rr = 0; rr < 4; rr++) {
                int rowc = wr + i * 16 + q * 4 + rr;
                float v = acc[i][j][rr] + bv;
                v = v > 0.f ? v : 0.f;
                smem[rowc * LDC + colc] = f2bf(v);
            }
        }
    }
    __syncthreads();
    int colp = t & 127;
    int grp = t >> 7;
    int gc = bn + colp;
    if (gc < HCDIM) {
        int cur = -1; float mx = 0.f, sm = 0.f;
        int rbeg = grp * 64, rend = rbeg + 64;
        for (int rr = rbeg; rr < rend; rr++) {
            int b = bsh[rr];
            if (b < 0) break;
            float v = bf2f(smem[rr * LDC + colp]);
            if (b != cur) {
                if (cur >= 0) {
                    atomicMax((int*)(out + (size_t)cur * (2 * HCDIM) + gc), __float_as_int(mx));
                    atomicAdd(out + (size_t)cur * (2 * HCDIM) + HCDIM + gc, sm);
                }
                cur = b; mx = v; sm = v;
            } else { mx = fmaxf(mx, v); sm += v; }
        }
        if (cur >= 0) {
            atomicMax((int*)(out + (size_t)cur * (2 * HCDIM) + gc), __float_as_int(mx));
            atomicAdd(out + (size_t)cur * (2 * HCDIM) + HCDIM + gc, sm);
        }
    }
}

// divide the mean slots by counts
__global__ void finalize_kernel(float* __restrict__ out, const int* __restrict__ bst) {
    int i = blockIdx.x * blockDim.x + threadIdx.x;
    if (i >= NBATCH * HCDIM) return;
    int b = i / HCDIM, c = i - b * HCDIM;
    int cnt = bst[b + 1] - bst[b];
    out[(size_t)b * (2 * HCDIM) + HCDIM + c] /= (float)(cnt > 0 ? cnt : 1);
}

// ---------------------------------------------------------------------------
extern "C" void kernel_launch(void* const* d_in, const int* in_sizes, int n_in,
                              void* d_out, int out_size, void* d_ws, size_t ws_size,
                              hipStream_t stream) {
    const float* x       = (const float*)d_in[0];
    const int*   ei      = (const int*)d_in[1];
    const int*   batch   = (const int*)d_in[2];
    const float* W_l     = (const float*)d_in[3];
    const float* W_r     = (const float*)d_in[4];
    const float* att     = (const float*)d_in[5];
    const float* bias1   = (const float*)d_in[6];
    const float* W_gcn   = (const float*)d_in[7];
    const float* bias_gcn= (const float*)d_in[8];
    float* out = (float*)d_out;

    char* w = (char*)d_ws;
    const size_t BIGH = (size_t)NNODES * HCDIM * sizeof(unsigned short);  // 78,000,000
    unsigned short* xl  = (unsigned short*)(w);          // later reused as agg
    unsigned short* xr  = (unsigned short*)(w + BIGH);   // becomes h; later BT
    unsigned short* agg = xl;
    unsigned short* BT  = xr;                            // h dead after gcn_agg
    char* sm = w + 2 * BIGH;
    int*   deg  = (int*)(sm);                    sm += 50048 * 4;
    int*   rowp = (int*)(sm);                    sm += 50048 * 4;
    int*   curs = (int*)(sm);                    sm += 50048 * 4;
    int*   col  = (int*)(sm);                    sm += 450048 * 4;
    float* dinv = (float*)(sm);                  sm += 50048 * 4;
    int*   bst  = (int*)(sm);                    sm += 512 * 4;
    size_t needed = (size_t)(sm - (char*)d_ws);
    if (ws_size < needed) return;   // fail soft instead of OOB fault

    // --- zero-init (out for atomics; deg for CSR count) ---
    zero_f_kernel<<<(NBATCH * 2 * HCDIM + 255) / 256, 256, 0, stream>>>(out, NBATCH * 2 * HCDIM);
    zero_i_kernel<<<(NNODES + 255) / 256, 256, 0, stream>>>(deg, NNODES);

    // --- CSR build ---
    {
        int blocks = (ETOT + 255) / 256;
        count_kernel<<<blocks, 256, 0, stream>>>(ei, deg);
        scan_kernel<<<1, 1024, 0, stream>>>(deg, NNODES, rowp, curs);
        fill_kernel<<<blocks, 256, 0, stream>>>(ei, curs, col);
        dinv_kernel<<<(NNODES + 255) / 256, 256, 0, stream>>>(deg, dinv, NNODES);
        bstart_kernel<<<1, 512, 0, stream>>>(batch, NNODES, bst);
    }

    // --- xl = x @ W_l ; xr = x @ W_r (bf16 out) ---
    {
        dim3 grid((HCDIM + 63) / 64, (NNODES + 63) / 64);
        gemm1_kernel<<<grid, 256, 0, stream>>>(x, W_l, xl, NNODES, INDIM, HCDIM);
        gemm1_kernel<<<grid, 256, 0, stream>>>(x, W_r, xr, NNODES, INDIM, HCDIM);
    }

    // --- GATv2 + ELU (writes h over xr) ---
    {
        int jobs = NNODES * 3;                 // (node, head-quad)
        int blocks = (jobs + 3) / 4;           // 4 waves / block
        gat_kernel<<<blocks, 256, 0, stream>>>(xl, xr, rowp, col, att, bias1, xr);
    }

    // --- GCN aggregate (h -> agg, overwrites xl space) ---
    gcn_agg_kernel<<<NNODES, 256, 0, stream>>>(xr, rowp, col, dinv, agg);

    // --- W_gcn^T -> bf16 padded (into xr region; h is dead) ---
    btprep_kernel<<<(NPAD * KPAD + 255) / 256, 256, 0, stream>>>(W_gcn, BT);

    // --- GEMM2 (MFMA) + bias + relu + fused segment max/mean pooling ---
    {
        dim3 grid(NPAD / BN, (NNODES + BM - 1) / BM);   // (7, 391)
        gemm2_pool_kernel<<<grid, 256, 0, stream>>>(agg, BT, bias_gcn, batch, out, NNODES);
    }

    // --- finalize means ---
    finalize_kernel<<<(NBATCH * HCDIM + 255) / 256, 256, 0, stream>>>(out, bst);
}

// Round 5
// 972.794 us; speedup vs baseline: 2.0546x; 1.1664x over previous
//
#include <hip/hip_runtime.h>
#include <hip/hip_bf16.h>
#include <math.h>

#define NNODES   50000
#define INDIM    78
#define NHEADS   10
#define CDIM     78
#define HCDIM    780
#define NEDGES   400000
#define NBATCH   256
#define ETOT     (NEDGES + NNODES)   // 450000, with self-loops
#define NEG_SLOPE 0.2f

// GEMM2 MFMA tiling
#define BM 128
#define BN 128
#define BK 32
#define KPAD 800          // 25 * 32
#define NPAD 896          // 7 * 128
#define LDT 68            // transposed epilogue tile stride (ushorts)

typedef __attribute__((ext_vector_type(8))) short bf16x8_t;
typedef __attribute__((ext_vector_type(4))) float f32x4_t;

// bf16 <-> f32 helpers
__device__ __forceinline__ float bf2f(unsigned short u) {
    union { unsigned int i; float f; } v; v.i = ((unsigned int)u) << 16; return v.f;
}
__device__ __forceinline__ unsigned short f2bf(float f) {
    __hip_bfloat16 h = __float2bfloat16(f);
    return *reinterpret_cast<unsigned short*>(&h);
}

// async global->LDS, 16 B per lane; lptr must be wave-uniform (HW: base+lane*16)
__device__ __forceinline__ void async_ld16(const unsigned short* g, unsigned short* l) {
    __builtin_amdgcn_global_load_lds(
        (const __attribute__((address_space(1))) void*)g,
        (__attribute__((address_space(3))) void*)l, 16, 0, 0);
}

// ---------------------------------------------------------------------------
// zero-init
// ---------------------------------------------------------------------------
__global__ void zero_f_kernel(float* __restrict__ p, int n) {
    int i = blockIdx.x * blockDim.x + threadIdx.x;
    if (i < n) p[i] = 0.f;
}
__global__ void zero_i_kernel(int* __restrict__ p, int n) {
    int i = blockIdx.x * blockDim.x + threadIdx.x;
    if (i < n) p[i] = 0;
}

// ---------------------------------------------------------------------------
// CSR build
// ---------------------------------------------------------------------------
__global__ void count_kernel(const int* __restrict__ ei, int* __restrict__ deg) {
    int e = blockIdx.x * blockDim.x + threadIdx.x;
    if (e >= ETOT) return;
    int d = (e < NEDGES) ? ei[NEDGES + e] : (e - NEDGES);
    atomicAdd(&deg[d], 1);
}

__global__ void scan_kernel(const int* __restrict__ deg, int n,
                            int* __restrict__ row_ptr, int* __restrict__ cursor) {
    __shared__ int bufA[1024];
    __shared__ int bufB[1024];
    __shared__ int carry_s;
    int t = threadIdx.x;
    if (t == 0) carry_s = 0;
    __syncthreads();
    for (int base = 0; base < n; base += 1024) {
        int i = base + t;
        int v = (i < n) ? deg[i] : 0;
        bufA[t] = v;
        __syncthreads();
        int* src = bufA; int* dst = bufB;
        for (int off = 1; off < 1024; off <<= 1) {
            int val = src[t] + ((t >= off) ? src[t - off] : 0);
            dst[t] = val;
            __syncthreads();
            int* tp = src; src = dst; dst = tp;
        }
        int incl = src[t];
        int carry = carry_s;
        int excl = incl - v + carry;
        if (i < n) { row_ptr[i] = excl; cursor[i] = excl; }
        __syncthreads();
        if (t == 1023) carry_s = carry + src[1023];
        __syncthreads();
    }
    if (t == 0) row_ptr[n] = carry_s;
}

__global__ void fill_kernel(const int* __restrict__ ei,
                            int* __restrict__ cursor, int* __restrict__ col) {
    int e = blockIdx.x * blockDim.x + threadIdx.x;
    if (e >= ETOT) return;
    int s, d;
    if (e < NEDGES) { s = ei[e]; d = ei[NEDGES + e]; }
    else            { s = d = e - NEDGES; }
    int pos = atomicAdd(&cursor[d], 1);
    col[pos] = s;
}

__global__ void dinv_kernel(const int* __restrict__ deg, float* __restrict__ dinv, int n) {
    int i = blockIdx.x * blockDim.x + threadIdx.x;
    if (i < n) dinv[i] = rsqrtf((float)deg[i]);
}

__global__ void bstart_kernel(const int* __restrict__ batch, int n, int* __restrict__ start) {
    int b = threadIdx.x;
    if (b > NBATCH) return;
    int lo = 0, hi = n;
    while (lo < hi) { int mid = (lo + hi) >> 1; if (batch[mid] < b) lo = mid + 1; else hi = mid; }
    start[b] = lo;
}

// ---------------------------------------------------------------------------
// GEMM1: C_bf16[M,N] = A_f32[M,K] @ B_f32[K,N]   (64x64 tile, fp32 VALU)
// ---------------------------------------------------------------------------
__global__ __launch_bounds__(256) void gemm1_kernel(
        const float* __restrict__ A, const float* __restrict__ B,
        unsigned short* __restrict__ C, int M, int K, int N) {
    __shared__ float As[16][65];
    __shared__ float Bs[16][64];
    int tid = threadIdx.x;
    int bm = blockIdx.y * 64, bn = blockIdx.x * 64;
    int am = tid >> 2;
    int ak = (tid & 3) * 4;
    int bk = tid >> 4;
    int bnl = (tid & 15) * 4;
    int ty = tid >> 4, tx = tid & 15;
    float acc[4][4] = {};
    for (int k0 = 0; k0 < K; k0 += 16) {
        float a0 = 0.f, a1 = 0.f, a2 = 0.f, a3 = 0.f;
        int arow = bm + am;
        int kk = k0 + ak;
        if (arow < M) {
            const float* ap = A + (size_t)arow * K + kk;
            if (kk + 0 < K) a0 = ap[0];
            if (kk + 1 < K) a1 = ap[1];
            if (kk + 2 < K) a2 = ap[2];
            if (kk + 3 < K) a3 = ap[3];
        }
        float b0 = 0.f, b1 = 0.f, b2 = 0.f, b3 = 0.f;
        int brow = k0 + bk;
        if (brow < K) {
            int cc = bn + bnl;
            const float* bp = B + (size_t)brow * N + cc;
            if (cc + 3 < N) { float4 v = *(const float4*)bp; b0=v.x; b1=v.y; b2=v.z; b3=v.w; }
            else {
                if (cc + 0 < N) b0 = bp[0];
                if (cc + 1 < N) b1 = bp[1];
                if (cc + 2 < N) b2 = bp[2];
            }
        }
        __syncthreads();
        As[ak + 0][am] = a0; As[ak + 1][am] = a1;
        As[ak + 2][am] = a2; As[ak + 3][am] = a3;
        Bs[bk][bnl + 0] = b0; Bs[bk][bnl + 1] = b1;
        Bs[bk][bnl + 2] = b2; Bs[bk][bnl + 3] = b3;
        __syncthreads();
        #pragma unroll
        for (int k2 = 0; k2 < 16; k2++) {
            float ar[4], br[4];
            #pragma unroll
            for (int i = 0; i < 4; i++) { ar[i] = As[k2][ty * 4 + i]; br[i] = Bs[k2][tx * 4 + i]; }
            #pragma unroll
            for (int i = 0; i < 4; i++)
                #pragma unroll
                for (int j = 0; j < 4; j++)
                    acc[i][j] = fmaf(ar[i], br[j], acc[i][j]);
        }
    }
    #pragma unroll
    for (int i = 0; i < 4; i++) {
        int row = bm + ty * 4 + i;
        if (row >= M) continue;
        #pragma unroll
        for (int j = 0; j < 4; j++) {
            int cc = bn + tx * 4 + j;
            if (cc >= N) continue;
            C[(size_t)row * N + cc] = f2bf(acc[i][j]);
        }
    }
}

// ---------------------------------------------------------------------------
// GATv2 aggregation v2 (unchanged from round 4)
// ---------------------------------------------------------------------------
__global__ __launch_bounds__(256) void gat_kernel(
        const unsigned short* __restrict__ xl, const unsigned short* xr,
        const int* __restrict__ row_ptr, const int* __restrict__ col,
        const float* __restrict__ att, const float* __restrict__ bias1,
        unsigned short* h_out) {
    int wid = blockIdx.x * 4 + (threadIdx.x >> 6);
    int node = wid / 3;
    int hq = wid - node * 3;
    if (node >= NNODES) return;
    int lane = threadIdx.x & 63;
    int g = lane >> 4;
    int cl = lane & 15;
    int head = hq * 4 + g;
    bool hv = head < NHEADS;
    int hoff = head * CDIM;
    size_t rbase = (size_t)node * HCDIM + hoff;

    float attv[5], xrv[5];
    #pragma unroll
    for (int k = 0; k < 5; k++) {
        int c = cl + 16 * k;
        bool cv = hv && (c < CDIM);
        attv[k] = cv ? att[hoff + c] : 0.f;
        xrv[k]  = cv ? bf2f(xr[rbase + c]) : 0.f;
    }

    float l = 0.f;
    float acc[5] = {0.f, 0.f, 0.f, 0.f, 0.f};
    int e0 = row_ptr[node], e1 = row_ptr[node + 1];
    for (int e = e0; e < e1; e++) {
        int j = __builtin_amdgcn_readfirstlane(col[e]);
        const unsigned short* xp = xl + (size_t)j * HCDIM + hoff;
        float v[5], part = 0.f;
        #pragma unroll
        for (int k = 0; k < 5; k++) {
            v[k] = bf2f(xp[cl + 16 * k]);
            float t = v[k] + xrv[k];
            t = fmaxf(t, 0.f) + NEG_SLOPE * fminf(t, 0.f);
            part = fmaf(t, attv[k], part);
        }
        part += __shfl_xor(part, 1, 64);
        part += __shfl_xor(part, 2, 64);
        part += __shfl_xor(part, 4, 64);
        part += __shfl_xor(part, 8, 64);
        float p = __expf(part);
        l += p;
        #pragma unroll
        for (int k = 0; k < 5; k++) acc[k] = fmaf(p, v[k], acc[k]);
    }
    float inv = 1.f / l;
    if (hv) {
        #pragma unroll
        for (int k = 0; k < 5; k++) {
            int c = cl + 16 * k;
            if (c < CDIM) {
                float r = acc[k] * inv + bias1[hoff + c];
                r = r > 0.f ? r : (__expf(r) - 1.f);
                h_out[rbase + c] = f2bf(r);
            }
        }
    }
}

// ---------------------------------------------------------------------------
// GCN aggregation v2 (unchanged)
// ---------------------------------------------------------------------------
__global__ __launch_bounds__(256) void gcn_agg_kernel(
        const unsigned short* __restrict__ h, const int* __restrict__ row_ptr,
        const int* __restrict__ col, const float* __restrict__ dinv,
        unsigned short* __restrict__ agg) {
    int i = blockIdx.x;
    int t = threadIdx.x;
    if (t >= HCDIM / 4) return;
    float a0 = 0.f, a1 = 0.f, a2 = 0.f, a3 = 0.f;
    int e0 = row_ptr[i], e1 = row_ptr[i + 1];
    for (int e = e0; e < e1; e++) {
        int j = col[e];
        float s = dinv[j];
        ushort4 u = *(const ushort4*)(h + (size_t)j * HCDIM + 4 * t);
        a0 = fmaf(s, bf2f(u.x), a0);
        a1 = fmaf(s, bf2f(u.y), a1);
        a2 = fmaf(s, bf2f(u.z), a2);
        a3 = fmaf(s, bf2f(u.w), a3);
    }
    float di = dinv[i];
    ushort4 o;
    o.x = f2bf(a0 * di); o.y = f2bf(a1 * di);
    o.z = f2bf(a2 * di); o.w = f2bf(a3 * di);
    *(ushort4*)(agg + (size_t)i * HCDIM + 4 * t) = o;
}

// ---------------------------------------------------------------------------
// BT prep: BT[n][k] = bf16(W_gcn[k][n]), zero-padded to [NPAD][KPAD]
// ---------------------------------------------------------------------------
__global__ void btprep_kernel(const float* __restrict__ W, unsigned short* __restrict__ BT) {
    int idx = blockIdx.x * 256 + threadIdx.x;
    if (idx >= NPAD * KPAD) return;
    int n = idx / KPAD, k = idx - n * KPAD;
    float v = (n < HCDIM && k < HCDIM) ? W[(size_t)k * HCDIM + n] : 0.f;
    BT[idx] = f2bf(v);
}

// ---------------------------------------------------------------------------
// GEMM2 MFMA fused v2: h2 = relu(agg_bf16 @ W_gcn + bias); segment max/mean.
// global_load_lds(16B) staging into unpadded [128][32] bf16 tiles (XOR-swizzled
// chunks); epilogue via transposed [col][row] LDS tile in two 64-row phases.
// K-tail (780..799): A reads garbage-but-finite neighbors, BT zero -> no effect.
// M-tail rows: garbage C rows, skipped by pooling (bsh=-1).
// ---------------------------------------------------------------------------
__global__ __launch_bounds__(256) void gemm2_pool_kernel(
        const unsigned short* __restrict__ A, const unsigned short* __restrict__ BT,
        const float* __restrict__ bias, const int* __restrict__ batch,
        float* __restrict__ out, int M) {
    __shared__ unsigned short smem[128 * LDT];   // union: staging 8192 | Ct 8704
    unsigned short* As = smem;                    // [128][32]
    unsigned short* Bs = smem + 4096;             // [128][32]
    __shared__ int bsh[BM];

    int t = threadIdx.x;
    int lane = t & 63, w = t >> 6;
    int bm = blockIdx.y * BM, bn = blockIdx.x * BN;

    if (t < BM) {
        int row = bm + t;
        bsh[t] = (row < M) ? batch[row] : -1;
    }

    int m16 = lane & 15, q = lane >> 4;
    int wr = (w >> 1) * 64, wc = (w & 1) * 64;

    // staging: wave w covers rows [32w, 32w+32), 2 issues of 16 rows.
    // lane i -> local row (i>>2), LDS chunk (i&3); global chunk XOR-swizzled.
    int lrow = lane >> 2;
    int gchunk = (lane & 3) ^ (lrow & 3);          // 2-bit swizzle
    int rA0 = 32 * w + lrow;
    const unsigned short* ga0 = A  + (size_t)(bm + rA0)      * HCDIM + gchunk * 8;
    const unsigned short* ga1 = A  + (size_t)(bm + rA0 + 16) * HCDIM + gchunk * 8;
    const unsigned short* gb0 = BT + (size_t)(bn + rA0)      * KPAD  + gchunk * 8;
    const unsigned short* gb1 = BT + (size_t)(bn + rA0 + 16) * KPAD  + gchunk * 8;
    unsigned short* la0 = As + (32 * w) * 32;      // wave-uniform LDS bases
    unsigned short* la1 = As + (32 * w + 16) * 32;
    unsigned short* lb0 = Bs + (32 * w) * 32;
    unsigned short* lb1 = Bs + (32 * w + 16) * 32;

    f32x4_t acc[4][4];
    #pragma unroll
    for (int i = 0; i < 4; i++)
        #pragma unroll
        for (int j = 0; j < 4; j++)
            acc[i][j] = (f32x4_t)(0.f);

    for (int k0 = 0; k0 < KPAD; k0 += BK) {
        __syncthreads();                   // all waves done reading prev tile
        async_ld16(ga0 + k0, la0);
        async_ld16(ga1 + k0, la1);
        async_ld16(gb0 + k0, lb0);
        async_ld16(gb1 + k0, lb1);
        __syncthreads();                   // vmcnt(0) drained before barrier

        bf16x8_t af[4], bf[4];
        #pragma unroll
        for (int i = 0; i < 4; i++) {
            int row = wr + i * 16 + m16;
            af[i] = *(const bf16x8_t*)&As[row * 32 + (q ^ (row & 3)) * 8];
        }
        #pragma unroll
        for (int j = 0; j < 4; j++) {
            int row = wc + j * 16 + m16;
            bf[j] = *(const bf16x8_t*)&Bs[row * 32 + (q ^ (row & 3)) * 8];
        }
        #pragma unroll
        for (int i = 0; i < 4; i++)
            #pragma unroll
            for (int j = 0; j < 4; j++)
                acc[i][j] = __builtin_amdgcn_mfma_f32_16x16x32_bf16(af[i], bf[j], acc[i][j], 0, 0, 0);
    }

    // bias per owned column (colc = wc + j*16 + m16)
    float bvj[4];
    #pragma unroll
    for (int j = 0; j < 4; j++) {
        int gcc = bn + wc + j * 16 + m16;
        bvj[j] = (gcc < HCDIM) ? bias[gcc] : 0.f;
    }

    // two-phase epilogue: rows [64p, 64p+64) via transposed Ct[col][row]
    #pragma unroll
    for (int p = 0; p < 2; p++) {
        __syncthreads();   // staging reads / previous-phase pooling done
        if ((w >> 1) == p) {
            // C/D layout: col = m16, row(local in 64) = i*16 + q*4 + rr
            #pragma unroll
            for (int i = 0; i < 4; i++) {
                #pragma unroll
                for (int j = 0; j < 4; j++) {
                    int colc = wc + j * 16 + m16;
                    ushort4 o;
                    float v0 = acc[i][j][0] + bvj[j];
                    float v1 = acc[i][j][1] + bvj[j];
                    float v2 = acc[i][j][2] + bvj[j];
                    float v3 = acc[i][j][3] + bvj[j];
                    o.x = f2bf(v0 > 0.f ? v0 : 0.f);
                    o.y = f2bf(v1 > 0.f ? v1 : 0.f);
                    o.z = f2bf(v2 > 0.f ? v2 : 0.f);
                    o.w = f2bf(v3 > 0.f ? v3 : 0.f);
                    *(ushort4*)&smem[colc * LDT + i * 16 + q * 4] = o;
                }
            }
        }
        __syncthreads();
        // pooling: 128 cols x 2 row-groups of 32
        int colp = t & 127;
        int rb = (t >> 7) * 32;
        int gc = bn + colp;
        if (gc < HCDIM) {
            int cur = -1; float mx = 0.f, sm = 0.f;
            bool done = false;
            for (int rr = rb; rr < rb + 32 && !done; rr += 4) {
                ushort4 u = *(const ushort4*)&smem[colp * LDT + rr];
                unsigned short us[4] = {u.x, u.y, u.z, u.w};
                #pragma unroll
                for (int s2 = 0; s2 < 4; s2++) {
                    int b = bsh[64 * p + rr + s2];
                    if (b < 0) { done = true; break; }
                    float v = bf2f(us[s2]);
                    if (b != cur) {
                        if (cur >= 0) {
                            atomicMax((int*)(out + (size_t)cur * (2 * HCDIM) + gc), __float_as_int(mx));
                            atomicAdd(out + (size_t)cur * (2 * HCDIM) + HCDIM + gc, sm);
                        }
                        cur = b; mx = v; sm = v;
                    } else { mx = fmaxf(mx, v); sm += v; }
                }
            }
            if (cur >= 0) {
                atomicMax((int*)(out + (size_t)cur * (2 * HCDIM) + gc), __float_as_int(mx));
                atomicAdd(out + (size_t)cur * (2 * HCDIM) + HCDIM + gc, sm);
            }
        }
    }
}

// divide the mean slots by counts
__global__ void finalize_kernel(float* __restrict__ out, const int* __restrict__ bst) {
    int i = blockIdx.x * blockDim.x + threadIdx.x;
    if (i >= NBATCH * HCDIM) return;
    int b = i / HCDIM, c = i - b * HCDIM;
    int cnt = bst[b + 1] - bst[b];
    out[(size_t)b * (2 * HCDIM) + HCDIM + c] /= (float)(cnt > 0 ? cnt : 1);
}

// ---------------------------------------------------------------------------
extern "C" void kernel_launch(void* const* d_in, const int* in_sizes, int n_in,
                              void* d_out, int out_size, void* d_ws, size_t ws_size,
                              hipStream_t stream) {
    const float* x       = (const float*)d_in[0];
    const int*   ei      = (const int*)d_in[1];
    const int*   batch   = (const int*)d_in[2];
    const float* W_l     = (const float*)d_in[3];
    const float* W_r     = (const float*)d_in[4];
    const float* att     = (const float*)d_in[5];
    const float* bias1   = (const float*)d_in[6];
    const float* W_gcn   = (const float*)d_in[7];
    const float* bias_gcn= (const float*)d_in[8];
    float* out = (float*)d_out;

    char* w = (char*)d_ws;
    const size_t BIGH = (size_t)NNODES * HCDIM * sizeof(unsigned short);  // 78,000,000
    unsigned short* xl  = (unsigned short*)(w);          // later reused as agg
    unsigned short* xr  = (unsigned short*)(w + BIGH);   // becomes h; later BT
    unsigned short* agg = xl;
    unsigned short* BT  = xr;                            // h dead after gcn_agg
    char* sm = w + 2 * BIGH;
    int*   deg  = (int*)(sm);                    sm += 50048 * 4;
    int*   rowp = (int*)(sm);                    sm += 50048 * 4;
    int*   curs = (int*)(sm);                    sm += 50048 * 4;
    int*   col  = (int*)(sm);                    sm += 450048 * 4;
    float* dinv = (float*)(sm);                  sm += 50048 * 4;
    int*   bst  = (int*)(sm);                    sm += 512 * 4;
    size_t needed = (size_t)(sm - (char*)d_ws);
    if (ws_size < needed) return;   // fail soft instead of OOB fault

    // --- zero-init (out for atomics; deg for CSR count) ---
    zero_f_kernel<<<(NBATCH * 2 * HCDIM + 255) / 256, 256, 0, stream>>>(out, NBATCH * 2 * HCDIM);
    zero_i_kernel<<<(NNODES + 255) / 256, 256, 0, stream>>>(deg, NNODES);

    // --- CSR build ---
    {
        int blocks = (ETOT + 255) / 256;
        count_kernel<<<blocks, 256, 0, stream>>>(ei, deg);
        scan_kernel<<<1, 1024, 0, stream>>>(deg, NNODES, rowp, curs);
        fill_kernel<<<blocks, 256, 0, stream>>>(ei, curs, col);
        dinv_kernel<<<(NNODES + 255) / 256, 256, 0, stream>>>(deg, dinv, NNODES);
        bstart_kernel<<<1, 512, 0, stream>>>(batch, NNODES, bst);
    }

    // --- xl = x @ W_l ; xr = x @ W_r (bf16 out) ---
    {
        dim3 grid((HCDIM + 63) / 64, (NNODES + 63) / 64);
        gemm1_kernel<<<grid, 256, 0, stream>>>(x, W_l, xl, NNODES, INDIM, HCDIM);
        gemm1_kernel<<<grid, 256, 0, stream>>>(x, W_r, xr, NNODES, INDIM, HCDIM);
    }

    // --- GATv2 + ELU (writes h over xr) ---
    {
        int jobs = NNODES * 3;
        int blocks = (jobs + 3) / 4;
        gat_kernel<<<blocks, 256, 0, stream>>>(xl, xr, rowp, col, att, bias1, xr);
    }

    // --- GCN aggregate (h -> agg, overwrites xl space) ---
    gcn_agg_kernel<<<NNODES, 256, 0, stream>>>(xr, rowp, col, dinv, agg);

    // --- W_gcn^T -> bf16 padded (into xr region; h is dead) ---
    btprep_kernel<<<(NPAD * KPAD + 255) / 256, 256, 0, stream>>>(W_gcn, BT);

    // --- GEMM2 (MFMA, async staging) + bias + relu + fused pooling ---
    {
        dim3 grid(NPAD / BN, (NNODES + BM - 1) / BM);   // (7, 391)
        gemm2_pool_kernel<<<grid, 256, 0, stream>>>(agg, BT, bias_gcn, batch, out, NNODES);
    }

    // --- finalize means ---
    finalize_kernel<<<(NBATCH * HCDIM + 255) / 256, 256, 0, stream>>>(out, bst);
}

// Round 6
// 785.545 us; speedup vs baseline: 2.5444x; 1.2384x over previous
//
#include <hip/hip_runtime.h>
#include <hip/hip_bf16.h>
#include <math.h>

#define NNODES   50000
#define INDIM    78
#define NHEADS   10
#define CDIM     78
#define HCDIM    780
#define NEDGES   400000
#define NBATCH   256
#define ETOT     (NEDGES + NNODES)   // 450000, with self-loops
#define NEG_SLOPE 0.2f

// GEMM2 MFMA tiling
#define BM 128
#define BN 128
#define BK 32
#define KPAD 800          // 25 * 32
#define NPAD 896          // 7 * 128
#define LDT 68            // transposed epilogue tile stride (ushorts)

// GEMM1 (fused xl|xr) tiling
#define KP1 128           // 78 padded to 4*32
#define NP1 1664          // 13 * 128  (780 xl | 780 xr | pad)

typedef __attribute__((ext_vector_type(8))) short bf16x8_t;
typedef __attribute__((ext_vector_type(4))) float f32x4_t;

__device__ __forceinline__ float bf2f(unsigned short u) {
    union { unsigned int i; float f; } v; v.i = ((unsigned int)u) << 16; return v.f;
}
__device__ __forceinline__ unsigned short f2bf(float f) {
    __hip_bfloat16 h = __float2bfloat16(f);
    return *reinterpret_cast<unsigned short*>(&h);
}

// async global->LDS, 16 B per lane; LDS base wave-uniform (HW: base+lane*16)
__device__ __forceinline__ void async_ld16(const unsigned short* g, unsigned short* l) {
    __builtin_amdgcn_global_load_lds(
        (const __attribute__((address_space(1))) void*)g,
        (__attribute__((address_space(3))) void*)l, 16, 0, 0);
}

// ---------------------------------------------------------------------------
// zero-init
// ---------------------------------------------------------------------------
__global__ void zero_f_kernel(float* __restrict__ p, int n) {
    int i = blockIdx.x * blockDim.x + threadIdx.x;
    if (i < n) p[i] = 0.f;
}
__global__ void zero_i_kernel(int* __restrict__ p, int n) {
    int i = blockIdx.x * blockDim.x + threadIdx.x;
    if (i < n) p[i] = 0;
}

// ---------------------------------------------------------------------------
// CSR build
// ---------------------------------------------------------------------------
__global__ void count_kernel(const int* __restrict__ ei, int* __restrict__ deg) {
    int e = blockIdx.x * blockDim.x + threadIdx.x;
    if (e >= ETOT) return;
    int d = (e < NEDGES) ? ei[NEDGES + e] : (e - NEDGES);
    atomicAdd(&deg[d], 1);
}

// multi-block scan: phase 1 (per-block exclusive scan + block sums)
__global__ void scan1_kernel(const int* __restrict__ deg, int* __restrict__ rowp,
                             int* __restrict__ bsum) {
    __shared__ int s[256];
    int t = threadIdx.x, b = blockIdx.x;
    int i = b * 256 + t;
    int v = (i < NNODES) ? deg[i] : 0;
    s[t] = v;
    __syncthreads();
    #pragma unroll
    for (int off = 1; off < 256; off <<= 1) {
        int y = (t >= off) ? s[t - off] : 0;
        __syncthreads();
        s[t] += y;
        __syncthreads();
    }
    int incl = s[t];
    if (i < NNODES) rowp[i] = incl - v;
    if (t == 255) bsum[b] = incl;
}

// phase 2: scan 196 block sums (single block), write total to rowp[NNODES]
__global__ void scan2_kernel(int* __restrict__ bsum, int* __restrict__ rowp, int nblk) {
    __shared__ int s[256];
    int t = threadIdx.x;
    int v = (t < nblk) ? bsum[t] : 0;
    s[t] = v;
    __syncthreads();
    #pragma unroll
    for (int off = 1; off < 256; off <<= 1) {
        int y = (t >= off) ? s[t - off] : 0;
        __syncthreads();
        s[t] += y;
        __syncthreads();
    }
    int incl = s[t];
    if (t < nblk) bsum[t] = incl - v;   // exclusive
    if (t == 255) rowp[NNODES] = incl;  // grand total (tail vals are 0)
}

// phase 3: add block offsets, fill cursor
__global__ void scan3_kernel(int* __restrict__ rowp, const int* __restrict__ bsum,
                             int* __restrict__ curs) {
    int i = blockIdx.x * 256 + threadIdx.x;
    if (i >= NNODES) return;
    int r = rowp[i] + bsum[i >> 8];
    rowp[i] = r;
    curs[i] = r;
}

__global__ void fill_kernel(const int* __restrict__ ei,
                            int* __restrict__ cursor, int* __restrict__ col) {
    int e = blockIdx.x * blockDim.x + threadIdx.x;
    if (e >= ETOT) return;
    int s, d;
    if (e < NEDGES) { s = ei[e]; d = ei[NEDGES + e]; }
    else            { s = d = e - NEDGES; }
    int pos = atomicAdd(&cursor[d], 1);
    col[pos] = s;
}

__global__ void dinv_kernel(const int* __restrict__ deg, float* __restrict__ dinv, int n) {
    int i = blockIdx.x * blockDim.x + threadIdx.x;
    if (i < n) dinv[i] = rsqrtf((float)deg[i]);
}

__global__ void bstart_kernel(const int* __restrict__ batch, int n, int* __restrict__ start) {
    int b = threadIdx.x;
    if (b > NBATCH) return;
    int lo = 0, hi = n;
    while (lo < hi) { int mid = (lo + hi) >> 1; if (batch[mid] < b) lo = mid + 1; else hi = mid; }
    start[b] = lo;
}

// ---------------------------------------------------------------------------
// Wc prep: Wc[n][k] = bf16([W_l|W_r]^T), zero-padded to [NP1][KP1]
// ---------------------------------------------------------------------------
__global__ void wprep_kernel(const float* __restrict__ Wl, const float* __restrict__ Wr,
                             unsigned short* __restrict__ Wc) {
    int idx = blockIdx.x * 256 + threadIdx.x;
    if (idx >= NP1 * KP1) return;
    int n = idx >> 7, k = idx & 127;
    float v = 0.f;
    if (k < INDIM) {
        if (n < HCDIM)            v = Wl[(size_t)k * HCDIM + n];
        else if (n < 2 * HCDIM)   v = Wr[(size_t)k * HCDIM + (n - HCDIM)];
    }
    Wc[idx] = f2bf(v);
}

// ---------------------------------------------------------------------------
// GEMM1 fused MFMA: [xl|xr] = x @ [W_l|W_r]  (bf16 out)
// One block per 128 rows; A-tile staged ONCE (f32->bf16, swizzled), then
// 13 N-tiles of 128 with global_load_lds B staging (XOR-swizzled chunks).
// ---------------------------------------------------------------------------
__global__ __launch_bounds__(256) void gemm1_kernel(
        const float* __restrict__ x, const unsigned short* __restrict__ Wc,
        unsigned short* __restrict__ xl, unsigned short* __restrict__ xr, int M) {
    __shared__ unsigned short As[4 * 4096];   // [kc][row][32] swizzled, 32 KB
    __shared__ unsigned short Bs[4 * 4096];   // 32 KB
    int t = threadIdx.x;
    int lane = t & 63, w = t >> 6;
    int bm = blockIdx.x * 128;

    // ---- A staging (once): x f32 -> bf16 swizzled LDS ----
    for (int idx = t; idx < 128 * 128; idx += 256) {
        int row = idx >> 7, k = idx & 127;
        int kc = k >> 5, ch = (k >> 3) & 3, e = k & 7;
        int gr = bm + row;
        float v = (gr < M && k < INDIM) ? x[(size_t)gr * INDIM + k] : 0.f;
        As[kc * 4096 + row * 32 + ((ch ^ (row & 3)) * 8) + e] = f2bf(v);
    }

    int lrow = lane >> 2;
    int gch = (lane & 3) ^ (lrow & 3);
    int m16 = lane & 15, q = lane >> 4;
    int wr = (w >> 1) * 64, wcc = (w & 1) * 64;

    for (int nb = 0; nb < 13; nb++) {
        __syncthreads();   // prev frag reads done (and A staging visible)
        #pragma unroll
        for (int kc = 0; kc < 4; kc++) {
            const unsigned short* gb = Wc + ((size_t)(nb * 128 + 32 * w + lrow)) * KP1
                                          + kc * 32 + gch * 8;
            unsigned short* lb = Bs + kc * 4096 + (32 * w) * 32;
            async_ld16(gb, lb);
            async_ld16(gb + 16 * KP1, lb + 16 * 32);
        }
        __syncthreads();   // DMA drained

        f32x4_t acc[4][4];
        #pragma unroll
        for (int i = 0; i < 4; i++)
            #pragma unroll
            for (int j = 0; j < 4; j++)
                acc[i][j] = (f32x4_t)(0.f);

        #pragma unroll
        for (int kc = 0; kc < 4; kc++) {
            bf16x8_t af[4], bf[4];
            #pragma unroll
            for (int i = 0; i < 4; i++) {
                int row = wr + i * 16 + m16;
                af[i] = *(const bf16x8_t*)&As[kc * 4096 + row * 32 + ((q ^ (row & 3)) * 8)];
            }
            #pragma unroll
            for (int j = 0; j < 4; j++) {
                int row = wcc + j * 16 + m16;
                bf[j] = *(const bf16x8_t*)&Bs[kc * 4096 + row * 32 + ((q ^ (row & 3)) * 8)];
            }
            #pragma unroll
            for (int i = 0; i < 4; i++)
                #pragma unroll
                for (int j = 0; j < 4; j++)
                    acc[i][j] = __builtin_amdgcn_mfma_f32_16x16x32_bf16(af[i], bf[j], acc[i][j], 0, 0, 0);
        }

        // epilogue: direct bf16 stores into xl / xr
        #pragma unroll
        for (int j = 0; j < 4; j++) {
            int ng = nb * 128 + wcc + j * 16 + m16;
            if (ng >= 2 * HCDIM) continue;
            unsigned short* dst = (ng < HCDIM) ? (xl + ng) : (xr + (ng - HCDIM));
            #pragma unroll
            for (int i = 0; i < 4; i++) {
                #pragma unroll
                for (int rr = 0; rr < 4; rr++) {
                    int row = bm + wr + i * 16 + q * 4 + rr;
                    if (row < M) dst[(size_t)row * HCDIM] = f2bf(acc[i][j][rr]);
                }
            }
        }
    }
}

// ---------------------------------------------------------------------------
// GATv2 aggregation (unchanged from round 4/5)
// ---------------------------------------------------------------------------
__global__ __launch_bounds__(256) void gat_kernel(
        const unsigned short* __restrict__ xl, const unsigned short* xr,
        const int* __restrict__ row_ptr, const int* __restrict__ col,
        const float* __restrict__ att, const float* __restrict__ bias1,
        unsigned short* h_out) {
    int wid = blockIdx.x * 4 + (threadIdx.x >> 6);
    int node = wid / 3;
    int hq = wid - node * 3;
    if (node >= NNODES) return;
    int lane = threadIdx.x & 63;
    int g = lane >> 4;
    int cl = lane & 15;
    int head = hq * 4 + g;
    bool hv = head < NHEADS;
    int hoff = head * CDIM;
    size_t rbase = (size_t)node * HCDIM + hoff;

    float attv[5], xrv[5];
    #pragma unroll
    for (int k = 0; k < 5; k++) {
        int c = cl + 16 * k;
        bool cv = hv && (c < CDIM);
        attv[k] = cv ? att[hoff + c] : 0.f;
        xrv[k]  = cv ? bf2f(xr[rbase + c]) : 0.f;
    }

    float l = 0.f;
    float acc[5] = {0.f, 0.f, 0.f, 0.f, 0.f};
    int e0 = row_ptr[node], e1 = row_ptr[node + 1];
    for (int e = e0; e < e1; e++) {
        int j = __builtin_amdgcn_readfirstlane(col[e]);
        const unsigned short* xp = xl + (size_t)j * HCDIM + hoff;
        float v[5], part = 0.f;
        #pragma unroll
        for (int k = 0; k < 5; k++) {
            v[k] = bf2f(xp[cl + 16 * k]);
            float t = v[k] + xrv[k];
            t = fmaxf(t, 0.f) + NEG_SLOPE * fminf(t, 0.f);
            part = fmaf(t, attv[k], part);
        }
        part += __shfl_xor(part, 1, 64);
        part += __shfl_xor(part, 2, 64);
        part += __shfl_xor(part, 4, 64);
        part += __shfl_xor(part, 8, 64);
        float p = __expf(part);
        l += p;
        #pragma unroll
        for (int k = 0; k < 5; k++) acc[k] = fmaf(p, v[k], acc[k]);
    }
    float inv = 1.f / l;
    if (hv) {
        #pragma unroll
        for (int k = 0; k < 5; k++) {
            int c = cl + 16 * k;
            if (c < CDIM) {
                float r = acc[k] * inv + bias1[hoff + c];
                r = r > 0.f ? r : (__expf(r) - 1.f);
                h_out[rbase + c] = f2bf(r);
            }
        }
    }
}

// ---------------------------------------------------------------------------
// GCN aggregation v3: one wave per node; lane covers the whole 780-col row
// via bf16x8 (cols 0..511) + ushort4 (512..767) + masked ushort4 (768..779).
// ---------------------------------------------------------------------------
__global__ __launch_bounds__(256) void gcn_agg_kernel(
        const unsigned short* __restrict__ h, const int* __restrict__ row_ptr,
        const int* __restrict__ col, const float* __restrict__ dinv,
        unsigned short* __restrict__ agg) {
    int node = blockIdx.x * 4 + (threadIdx.x >> 6);
    if (node >= NNODES) return;
    int ln = threadIdx.x & 63;
    bool hasC = ln < 3;
    float accA[8] = {}, accB[4] = {}, accC[4] = {};
    int e0 = row_ptr[node], e1 = row_ptr[node + 1];
    int e = e0;
    int jn = (e < e1) ? col[e] : 0;
    for (; e < e1; ) {
        int j = __builtin_amdgcn_readfirstlane(jn);
        ++e;
        jn = (e < e1) ? col[e] : 0;          // prefetch next index
        float s = dinv[j];
        const unsigned short* hr = h + (size_t)j * HCDIM;
        bf16x8_t u = *(const bf16x8_t*)(hr + 8 * ln);
        ushort4 v4 = *(const ushort4*)(hr + 512 + 4 * ln);
        ushort4 w4 = hasC ? *(const ushort4*)(hr + 768 + 4 * ln) : make_ushort4(0, 0, 0, 0);
        #pragma unroll
        for (int k = 0; k < 8; k++) accA[k] = fmaf(s, bf2f((unsigned short)u[k]), accA[k]);
        accB[0] = fmaf(s, bf2f(v4.x), accB[0]);
        accB[1] = fmaf(s, bf2f(v4.y), accB[1]);
        accB[2] = fmaf(s, bf2f(v4.z), accB[2]);
        accB[3] = fmaf(s, bf2f(v4.w), accB[3]);
        accC[0] = fmaf(s, bf2f(w4.x), accC[0]);
        accC[1] = fmaf(s, bf2f(w4.y), accC[1]);
        accC[2] = fmaf(s, bf2f(w4.z), accC[2]);
        accC[3] = fmaf(s, bf2f(w4.w), accC[3]);
    }
    float di = dinv[node];
    unsigned short* ar = agg + (size_t)node * HCDIM;
    ushort4 o1, o2, ob;
    o1.x = f2bf(accA[0] * di); o1.y = f2bf(accA[1] * di);
    o1.z = f2bf(accA[2] * di); o1.w = f2bf(accA[3] * di);
    o2.x = f2bf(accA[4] * di); o2.y = f2bf(accA[5] * di);
    o2.z = f2bf(accA[6] * di); o2.w = f2bf(accA[7] * di);
    ob.x = f2bf(accB[0] * di); ob.y = f2bf(accB[1] * di);
    ob.z = f2bf(accB[2] * di); ob.w = f2bf(accB[3] * di);
    *(ushort4*)(ar + 8 * ln) = o1;
    *(ushort4*)(ar + 8 * ln + 4) = o2;
    *(ushort4*)(ar + 512 + 4 * ln) = ob;
    if (hasC) {
        ushort4 oc;
        oc.x = f2bf(accC[0] * di); oc.y = f2bf(accC[1] * di);
        oc.z = f2bf(accC[2] * di); oc.w = f2bf(accC[3] * di);
        *(ushort4*)(ar + 768 + 4 * ln) = oc;
    }
}

// ---------------------------------------------------------------------------
// BT prep: BT[n][k] = bf16(W_gcn[k][n]), zero-padded to [NPAD][KPAD]
// ---------------------------------------------------------------------------
__global__ void btprep_kernel(const float* __restrict__ W, unsigned short* __restrict__ BT) {
    int idx = blockIdx.x * 256 + threadIdx.x;
    if (idx >= NPAD * KPAD) return;
    int n = idx / KPAD, k = idx - n * KPAD;
    float v = (n < HCDIM && k < HCDIM) ? W[(size_t)k * HCDIM + n] : 0.f;
    BT[idx] = f2bf(v);
}

// ---------------------------------------------------------------------------
// GEMM2 MFMA fused (unchanged from round 5)
// ---------------------------------------------------------------------------
__global__ __launch_bounds__(256) void gemm2_pool_kernel(
        const unsigned short* __restrict__ A, const unsigned short* __restrict__ BT,
        const float* __restrict__ bias, const int* __restrict__ batch,
        float* __restrict__ out, int M) {
    __shared__ unsigned short smem[128 * LDT];   // union: staging 8192 | Ct 8704
    unsigned short* As = smem;                    // [128][32]
    unsigned short* Bs = smem + 4096;             // [128][32]
    __shared__ int bsh[BM];

    int t = threadIdx.x;
    int lane = t & 63, w = t >> 6;
    int bm = blockIdx.y * BM, bn = blockIdx.x * BN;

    if (t < BM) {
        int row = bm + t;
        bsh[t] = (row < M) ? batch[row] : -1;
    }

    int m16 = lane & 15, q = lane >> 4;
    int wr = (w >> 1) * 64, wc = (w & 1) * 64;

    int lrow = lane >> 2;
    int gchunk = (lane & 3) ^ (lrow & 3);
    int rA0 = 32 * w + lrow;
    const unsigned short* ga0 = A  + (size_t)(bm + rA0)      * HCDIM + gchunk * 8;
    const unsigned short* ga1 = A  + (size_t)(bm + rA0 + 16) * HCDIM + gchunk * 8;
    const unsigned short* gb0 = BT + (size_t)(bn + rA0)      * KPAD  + gchunk * 8;
    const unsigned short* gb1 = BT + (size_t)(bn + rA0 + 16) * KPAD  + gchunk * 8;
    unsigned short* la0 = As + (32 * w) * 32;
    unsigned short* la1 = As + (32 * w + 16) * 32;
    unsigned short* lb0 = Bs + (32 * w) * 32;
    unsigned short* lb1 = Bs + (32 * w + 16) * 32;

    f32x4_t acc[4][4];
    #pragma unroll
    for (int i = 0; i < 4; i++)
        #pragma unroll
        for (int j = 0; j < 4; j++)
            acc[i][j] = (f32x4_t)(0.f);

    for (int k0 = 0; k0 < KPAD; k0 += BK) {
        __syncthreads();
        async_ld16(ga0 + k0, la0);
        async_ld16(ga1 + k0, la1);
        async_ld16(gb0 + k0, lb0);
        async_ld16(gb1 + k0, lb1);
        __syncthreads();

        bf16x8_t af[4], bf[4];
        #pragma unroll
        for (int i = 0; i < 4; i++) {
            int row = wr + i * 16 + m16;
            af[i] = *(const bf16x8_t*)&As[row * 32 + (q ^ (row & 3)) * 8];
        }
        #pragma unroll
        for (int j = 0; j < 4; j++) {
            int row = wc + j * 16 + m16;
            bf[j] = *(const bf16x8_t*)&Bs[row * 32 + (q ^ (row & 3)) * 8];
        }
        #pragma unroll
        for (int i = 0; i < 4; i++)
            #pragma unroll
            for (int j = 0; j < 4; j++)
                acc[i][j] = __builtin_amdgcn_mfma_f32_16x16x32_bf16(af[i], bf[j], acc[i][j], 0, 0, 0);
    }

    float bvj[4];
    #pragma unroll
    for (int j = 0; j < 4; j++) {
        int gcc = bn + wc + j * 16 + m16;
        bvj[j] = (gcc < HCDIM) ? bias[gcc] : 0.f;
    }

    #pragma unroll
    for (int p = 0; p < 2; p++) {
        __syncthreads();
        if ((w >> 1) == p) {
            #pragma unroll
            for (int i = 0; i < 4; i++) {
                #pragma unroll
                for (int j = 0; j < 4; j++) {
                    int colc = wc + j * 16 + m16;
                    ushort4 o;
                    float v0 = acc[i][j][0] + bvj[j];
                    float v1 = acc[i][j][1] + bvj[j];
                    float v2 = acc[i][j][2] + bvj[j];
                    float v3 = acc[i][j][3] + bvj[j];
                    o.x = f2bf(v0 > 0.f ? v0 : 0.f);
                    o.y = f2bf(v1 > 0.f ? v1 : 0.f);
                    o.z = f2bf(v2 > 0.f ? v2 : 0.f);
                    o.w = f2bf(v3 > 0.f ? v3 : 0.f);
                    *(ushort4*)&smem[colc * LDT + i * 16 + q * 4] = o;
                }
            }
        }
        __syncthreads();
        int colp = t & 127;
        int rb = (t >> 7) * 32;
        int gc = bn + colp;
        if (gc < HCDIM) {
            int cur = -1; float mx = 0.f, sm = 0.f;
            bool done = false;
            for (int rr = rb; rr < rb + 32 && !done; rr += 4) {
                ushort4 u = *(const ushort4*)&smem[colp * LDT + rr];
                unsigned short us[4] = {u.x, u.y, u.z, u.w};
                #pragma unroll
                for (int s2 = 0; s2 < 4; s2++) {
                    int b = bsh[64 * p + rr + s2];
                    if (b < 0) { done = true; break; }
                    float v = bf2f(us[s2]);
                    if (b != cur) {
                        if (cur >= 0) {
                            atomicMax((int*)(out + (size_t)cur * (2 * HCDIM) + gc), __float_as_int(mx));
                            atomicAdd(out + (size_t)cur * (2 * HCDIM) + HCDIM + gc, sm);
                        }
                        cur = b; mx = v; sm = v;
                    } else { mx = fmaxf(mx, v); sm += v; }
                }
            }
            if (cur >= 0) {
                atomicMax((int*)(out + (size_t)cur * (2 * HCDIM) + gc), __float_as_int(mx));
                atomicAdd(out + (size_t)cur * (2 * HCDIM) + HCDIM + gc, sm);
            }
        }
    }
}

// divide the mean slots by counts
__global__ void finalize_kernel(float* __restrict__ out, const int* __restrict__ bst) {
    int i = blockIdx.x * blockDim.x + threadIdx.x;
    if (i >= NBATCH * HCDIM) return;
    int b = i / HCDIM, c = i - b * HCDIM;
    int cnt = bst[b + 1] - bst[b];
    out[(size_t)b * (2 * HCDIM) + HCDIM + c] /= (float)(cnt > 0 ? cnt : 1);
}

// ---------------------------------------------------------------------------
extern "C" void kernel_launch(void* const* d_in, const int* in_sizes, int n_in,
                              void* d_out, int out_size, void* d_ws, size_t ws_size,
                              hipStream_t stream) {
    const float* x       = (const float*)d_in[0];
    const int*   ei      = (const int*)d_in[1];
    const int*   batch   = (const int*)d_in[2];
    const float* W_l     = (const float*)d_in[3];
    const float* W_r     = (const float*)d_in[4];
    const float* att     = (const float*)d_in[5];
    const float* bias1   = (const float*)d_in[6];
    const float* W_gcn   = (const float*)d_in[7];
    const float* bias_gcn= (const float*)d_in[8];
    float* out = (float*)d_out;

    char* w = (char*)d_ws;
    const size_t BIGH = (size_t)NNODES * HCDIM * sizeof(unsigned short);  // 78,000,000
    unsigned short* xl  = (unsigned short*)(w);          // later reused as agg
    unsigned short* xr  = (unsigned short*)(w + BIGH);   // becomes h; later BT
    unsigned short* agg = xl;
    unsigned short* BT  = xr;                            // h dead after gcn_agg
    char* sm = w + 2 * BIGH;
    int*   rowp = (int*)(sm);                    sm += 50048 * 4;
    int*   col  = (int*)(sm);                    sm += 450048 * 4;
    float* dinv = (float*)(sm);                  sm += 50048 * 4;
    int*   bst  = (int*)(sm);                    sm += 512 * 4;
    int*   bsum = (int*)(sm);                    sm += 256 * 4;
    // scratch region S: deg+curs during CSR build, then Wc (1664*128*2 B)
    char* S = sm;                                sm += 426240;
    int*   deg  = (int*)(S);
    int*   curs = (int*)(S + 200192);
    unsigned short* Wc = (unsigned short*)(S);
    size_t needed = (size_t)(sm - (char*)d_ws);
    if (ws_size < needed) return;   // fail soft instead of OOB fault

    // --- zero-init (out for atomics; deg for CSR count) ---
    zero_f_kernel<<<(NBATCH * 2 * HCDIM + 255) / 256, 256, 0, stream>>>(out, NBATCH * 2 * HCDIM);
    zero_i_kernel<<<(NNODES + 255) / 256, 256, 0, stream>>>(deg, NNODES);

    // --- CSR build (multi-block scan) ---
    {
        int eblocks = (ETOT + 255) / 256;
        int nblocks = (NNODES + 255) / 256;     // 196
        count_kernel<<<eblocks, 256, 0, stream>>>(ei, deg);
        scan1_kernel<<<nblocks, 256, 0, stream>>>(deg, rowp, bsum);
        scan2_kernel<<<1, 256, 0, stream>>>(bsum, rowp, nblocks);
        scan3_kernel<<<nblocks, 256, 0, stream>>>(rowp, bsum, curs);
        fill_kernel<<<eblocks, 256, 0, stream>>>(ei, curs, col);
        dinv_kernel<<<nblocks, 256, 0, stream>>>(deg, dinv, NNODES);
        bstart_kernel<<<1, 512, 0, stream>>>(batch, NNODES, bst);
    }

    // --- Wc = [W_l|W_r]^T bf16 padded (overwrites deg/curs: CSR build done) ---
    wprep_kernel<<<(NP1 * KP1 + 255) / 256, 256, 0, stream>>>(W_l, W_r, Wc);

    // --- fused GEMM1 (MFMA): xl|xr = x @ [W_l|W_r] ---
    gemm1_kernel<<<(NNODES + 127) / 128, 256, 0, stream>>>(x, Wc, xl, xr, NNODES);

    // --- GATv2 + ELU (writes h over xr) ---
    {
        int jobs = NNODES * 3;
        int blocks = (jobs + 3) / 4;
        gat_kernel<<<blocks, 256, 0, stream>>>(xl, xr, rowp, col, att, bias1, xr);
    }

    // --- GCN aggregate (h -> agg, overwrites xl space) ---
    gcn_agg_kernel<<<(NNODES + 3) / 4, 256, 0, stream>>>(xr, rowp, col, dinv, agg);

    // --- W_gcn^T -> bf16 padded (into xr region; h is dead) ---
    btprep_kernel<<<(NPAD * KPAD + 255) / 256, 256, 0, stream>>>(W_gcn, BT);

    // --- GEMM2 (MFMA, async staging) + bias + relu + fused pooling ---
    {
        dim3 grid(NPAD / BN, (NNODES + BM - 1) / BM);   // (7, 391)
        gemm2_pool_kernel<<<grid, 256, 0, stream>>>(agg, BT, bias_gcn, batch, out, NNODES);
    }

    // --- finalize means ---
    finalize_kernel<<<(NBATCH * HCDIM + 255) / 256, 256, 0, stream>>>(out, bst);
}

// Round 7
// 716.374 us; speedup vs baseline: 2.7900x; 1.0966x over previous
//
#include <hip/hip_runtime.h>
#include <hip/hip_bf16.h>
#include <math.h>

#define NNODES   50000
#define INDIM    78
#define NHEADS   10
#define CDIM     78
#define HCDIM    780
#define NEDGES   400000
#define NBATCH   256
#define ETOT     (NEDGES + NNODES)   // 450000, with self-loops
#define NEG_SLOPE 0.2f

// GEMM2 MFMA tiling
#define BM 128
#define BN 128
#define BK 32
#define KPAD 800          // 25 * 32
#define NPAD 896          // 7 * 128
#define LDT 68            // transposed epilogue tile stride (ushorts)

// GEMM1 (fused xl|xr) tiling
#define KP1 128           // 78 padded to 4*32
#define NP1 1664          // 13 * 128  (780 xl | 780 xr | pad)

typedef __attribute__((ext_vector_type(8))) short bf16x8_t;
typedef __attribute__((ext_vector_type(4))) float f32x4_t;
typedef __attribute__((ext_vector_type(2))) float v2f;

__device__ __forceinline__ float bf2f(unsigned short u) {
    union { unsigned int i; float f; } v; v.i = ((unsigned int)u) << 16; return v.f;
}
__device__ __forceinline__ unsigned short f2bf(float f) {
    __hip_bfloat16 h = __float2bfloat16(f);
    return *reinterpret_cast<unsigned short*>(&h);
}
// packed pair of bf16 (even channel in low half) -> v2f
__device__ __forceinline__ v2f cvt2(unsigned int u) {
    union { unsigned int i; float f; } lo, hi;
    lo.i = u << 16;
    hi.i = u & 0xFFFF0000u;
    v2f r; r.x = lo.f; r.y = hi.f; return r;
}
__device__ __forceinline__ v2f vabs2(v2f t) {
    union { v2f f; unsigned long long u; } x; x.f = t;
    x.u &= 0x7FFFFFFF7FFFFFFFull; return x.f;
}
// sum over each 16-lane group via DPP (no LDS): xor1, xor2, half_mirror, mirror
__device__ __forceinline__ float dpp_red16(float x) {
    int y;
    y = __builtin_amdgcn_update_dpp(0, __float_as_int(x), 0xB1, 0xF, 0xF, true);   // quad_perm xor1
    x += __int_as_float(y);
    y = __builtin_amdgcn_update_dpp(0, __float_as_int(x), 0x4E, 0xF, 0xF, true);   // quad_perm xor2
    x += __int_as_float(y);
    y = __builtin_amdgcn_update_dpp(0, __float_as_int(x), 0x141, 0xF, 0xF, true);  // row_half_mirror
    x += __int_as_float(y);
    y = __builtin_amdgcn_update_dpp(0, __float_as_int(x), 0x140, 0xF, 0xF, true);  // row_mirror
    x += __int_as_float(y);
    return x;
}

// async global->LDS, 16 B per lane; LDS base wave-uniform (HW: base+lane*16)
__device__ __forceinline__ void async_ld16(const unsigned short* g, unsigned short* l) {
    __builtin_amdgcn_global_load_lds(
        (const __attribute__((address_space(1))) void*)g,
        (__attribute__((address_space(3))) void*)l, 16, 0, 0);
}

// ---------------------------------------------------------------------------
// zero-init (out for atomics + deg for CSR) in one launch
// ---------------------------------------------------------------------------
__global__ void zero_kernel(float* __restrict__ outp, int nf, int* __restrict__ deg, int ni) {
    int i = blockIdx.x * blockDim.x + threadIdx.x;
    if (i < nf) outp[i] = 0.f;
    if (i < ni) deg[i] = 0;
}

// ---------------------------------------------------------------------------
// CSR build
// ---------------------------------------------------------------------------
__global__ void count_kernel(const int* __restrict__ ei, int* __restrict__ deg) {
    int e = blockIdx.x * blockDim.x + threadIdx.x;
    if (e >= ETOT) return;
    int d = (e < NEDGES) ? ei[NEDGES + e] : (e - NEDGES);
    atomicAdd(&deg[d], 1);
}

// phase 1: per-block exclusive scan + block sums
__global__ void scan1_kernel(const int* __restrict__ deg, int* __restrict__ rowp,
                             int* __restrict__ bsum) {
    __shared__ int s[256];
    int t = threadIdx.x, b = blockIdx.x;
    int i = b * 256 + t;
    int v = (i < NNODES) ? deg[i] : 0;
    s[t] = v;
    __syncthreads();
    #pragma unroll
    for (int off = 1; off < 256; off <<= 1) {
        int y = (t >= off) ? s[t - off] : 0;
        __syncthreads();
        s[t] += y;
        __syncthreads();
    }
    int incl = s[t];
    if (i < NNODES) rowp[i] = incl - v;
    if (t == 255) bsum[b] = incl;
}

// phase 2: scan block sums (threads 0-255) + bstart binary searches (256-511)
__global__ void scan2_kernel(int* __restrict__ bsum, int* __restrict__ rowp, int nblk,
                             const int* __restrict__ batch, int* __restrict__ bst) {
    __shared__ int s[256];
    int t = threadIdx.x;
    int v = 0;
    if (t < 256) { v = (t < nblk) ? bsum[t] : 0; s[t] = v; }
    __syncthreads();
    #pragma unroll
    for (int off = 1; off < 256; off <<= 1) {
        int y = (t < 256 && t >= off) ? s[t - off] : 0;
        __syncthreads();
        if (t < 256) s[t] += y;
        __syncthreads();
    }
    if (t < 256) {
        int incl = s[t];
        if (t < nblk) bsum[t] = incl - v;   // exclusive
        if (t == 255) rowp[NNODES] = incl;
    } else {
        int b = t - 256;                     // 0..255
        int lo = 0, hi = NNODES;
        while (lo < hi) { int mid = (lo + hi) >> 1; if (batch[mid] < b) lo = mid + 1; else hi = mid; }
        bst[b] = lo;
        if (t == 511) bst[NBATCH] = NNODES;
    }
}

// phase 3: add block offsets, fill cursor, compute dinv
__global__ void scan3_kernel(int* __restrict__ rowp, const int* __restrict__ bsum,
                             int* __restrict__ curs, const int* __restrict__ deg,
                             float* __restrict__ dinv) {
    int i = blockIdx.x * 256 + threadIdx.x;
    if (i >= NNODES) return;
    int r = rowp[i] + bsum[i >> 8];
    rowp[i] = r;
    curs[i] = r;
    dinv[i] = rsqrtf((float)deg[i]);
}

__global__ void fill_kernel(const int* __restrict__ ei,
                            int* __restrict__ cursor, int* __restrict__ col) {
    int e = blockIdx.x * blockDim.x + threadIdx.x;
    if (e >= ETOT) return;
    int s, d;
    if (e < NEDGES) { s = ei[e]; d = ei[NEDGES + e]; }
    else            { s = d = e - NEDGES; }
    int pos = atomicAdd(&cursor[d], 1);
    col[pos] = s;
}

// ---------------------------------------------------------------------------
// Wc prep: Wc[n][k] = bf16([W_l|W_r]^T), zero-padded to [NP1][KP1]
// ---------------------------------------------------------------------------
__global__ void wprep_kernel(const float* __restrict__ Wl, const float* __restrict__ Wr,
                             unsigned short* __restrict__ Wc) {
    int idx = blockIdx.x * 256 + threadIdx.x;
    if (idx >= NP1 * KP1) return;
    int n = idx >> 7, k = idx & 127;
    float v = 0.f;
    if (k < INDIM) {
        if (n < HCDIM)            v = Wl[(size_t)k * HCDIM + n];
        else if (n < 2 * HCDIM)   v = Wr[(size_t)k * HCDIM + (n - HCDIM)];
    }
    Wc[idx] = f2bf(v);
}

// ---------------------------------------------------------------------------
// GEMM1 fused MFMA: [xl|xr] = x @ [W_l|W_r]  (bf16 out) — unchanged
// ---------------------------------------------------------------------------
__global__ __launch_bounds__(256) void gemm1_kernel(
        const float* __restrict__ x, const unsigned short* __restrict__ Wc,
        unsigned short* __restrict__ xl, unsigned short* __restrict__ xr, int M) {
    __shared__ unsigned short As[4 * 4096];
    __shared__ unsigned short Bs[4 * 4096];
    int t = threadIdx.x;
    int lane = t & 63, w = t >> 6;
    int bm = blockIdx.x * 128;

    for (int idx = t; idx < 128 * 128; idx += 256) {
        int row = idx >> 7, k = idx & 127;
        int kc = k >> 5, ch = (k >> 3) & 3, e = k & 7;
        int gr = bm + row;
        float v = (gr < M && k < INDIM) ? x[(size_t)gr * INDIM + k] : 0.f;
        As[kc * 4096 + row * 32 + ((ch ^ (row & 3)) * 8) + e] = f2bf(v);
    }

    int lrow = lane >> 2;
    int gch = (lane & 3) ^ (lrow & 3);
    int m16 = lane & 15, q = lane >> 4;
    int wr = (w >> 1) * 64, wcc = (w & 1) * 64;

    for (int nb = 0; nb < 13; nb++) {
        __syncthreads();
        #pragma unroll
        for (int kc = 0; kc < 4; kc++) {
            const unsigned short* gb = Wc + ((size_t)(nb * 128 + 32 * w + lrow)) * KP1
                                          + kc * 32 + gch * 8;
            unsigned short* lb = Bs + kc * 4096 + (32 * w) * 32;
            async_ld16(gb, lb);
            async_ld16(gb + 16 * KP1, lb + 16 * 32);
        }
        __syncthreads();

        f32x4_t acc[4][4];
        #pragma unroll
        for (int i = 0; i < 4; i++)
            #pragma unroll
            for (int j = 0; j < 4; j++)
                acc[i][j] = (f32x4_t)(0.f);

        #pragma unroll
        for (int kc = 0; kc < 4; kc++) {
            bf16x8_t af[4], bf[4];
            #pragma unroll
            for (int i = 0; i < 4; i++) {
                int row = wr + i * 16 + m16;
                af[i] = *(const bf16x8_t*)&As[kc * 4096 + row * 32 + ((q ^ (row & 3)) * 8)];
            }
            #pragma unroll
            for (int j = 0; j < 4; j++) {
                int row = wcc + j * 16 + m16;
                bf[j] = *(const bf16x8_t*)&Bs[kc * 4096 + row * 32 + ((q ^ (row & 3)) * 8)];
            }
            #pragma unroll
            for (int i = 0; i < 4; i++)
                #pragma unroll
                for (int j = 0; j < 4; j++)
                    acc[i][j] = __builtin_amdgcn_mfma_f32_16x16x32_bf16(af[i], bf[j], acc[i][j], 0, 0, 0);
        }

        #pragma unroll
        for (int j = 0; j < 4; j++) {
            int ng = nb * 128 + wcc + j * 16 + m16;
            if (ng >= 2 * HCDIM) continue;
            unsigned short* dst = (ng < HCDIM) ? (xl + ng) : (xr + (ng - HCDIM));
            #pragma unroll
            for (int i = 0; i < 4; i++) {
                #pragma unroll
                for (int rr = 0; rr < 4; rr++) {
                    int row = bm + wr + i * 16 + q * 4 + rr;
                    if (row < M) dst[(size_t)row * HCDIM] = f2bf(acc[i][j][rr]);
                }
            }
        }
    }
}

// ---------------------------------------------------------------------------
// GATv2 aggregation v4: wave per (node, head-quad); 16-lane groups; channel
// pairs as packed f32 (v_pk_*), ushort2 loads (3/edge), DPP group reduction,
// plain exp (scores analytically bounded), 2x edge unroll.
// ---------------------------------------------------------------------------
__device__ __forceinline__ void gat_edge(
        const unsigned int* __restrict__ xlu, int j, int hcl, int cl, bool lo7,
        v2f r0, v2f r1, v2f r2, v2f a0, v2f a1, v2f a2,
        float& l, v2f& acc0, v2f& acc1, v2f& acc2) {
    const unsigned int* xp = xlu + (size_t)j * (HCDIM / 2) + hcl;
    unsigned int u0 = xp[cl];
    unsigned int u1 = xp[cl + 16];
    unsigned int u2 = lo7 ? xp[cl + 32] : 0u;
    v2f v0 = cvt2(u0), v1 = cvt2(u1), v2v = cvt2(u2);
    v2f t0 = v0 + r0, t1 = v1 + r1, t2 = v2v + r2;
    // leaky relu: 0.6*t + 0.4*|t|  (== t if t>0 else 0.2t)
    v2f e0 = t0 * 0.6f + vabs2(t0) * 0.4f;
    v2f e1 = t1 * 0.6f + vabs2(t1) * 0.4f;
    v2f e2 = t2 * 0.6f + vabs2(t2) * 0.4f;
    v2f s2 = e0 * a0 + e1 * a1 + e2 * a2;
    float part = dpp_red16(s2.x + s2.y);
    float p = __expf(part);
    l += p;
    acc0 += p * v0; acc1 += p * v1; acc2 += p * v2v;
}

__global__ __launch_bounds__(256) void gat_kernel(
        const unsigned short* __restrict__ xl, const unsigned short* xr,
        const int* __restrict__ row_ptr, const int* __restrict__ col,
        const float* __restrict__ att, const float* __restrict__ bias1,
        unsigned short* h_out) {
    int wid = blockIdx.x * 4 + (threadIdx.x >> 6);
    int node = wid / 3;
    int hq = wid - node * 3;
    if (node >= NNODES) return;
    int lane = threadIdx.x & 63;
    int g = lane >> 4;
    int cl = lane & 15;
    bool lo7 = cl < 7;                 // pair-2 covers c=64..77
    int head = hq * 4 + g;             // 0..11 (10,11 dead)
    bool hv = head < NHEADS;
    int hC = hv ? head : (NHEADS - 1); // clamp dead heads onto valid data
    int hcl = hC * (CDIM / 2);         // uint offset of head base
    const unsigned int* xlu = (const unsigned int*)xl;
    const unsigned int* xru = (const unsigned int*)xr;

    // preload att (f32 pairs) and xr (bf16 pairs), masked
    const float2* ap = (const float2*)(att + hC * CDIM);
    v2f a0 = (v2f)(0.f), a1 = (v2f)(0.f), a2 = (v2f)(0.f);
    if (hv) {
        float2 f0 = ap[cl], f1 = ap[cl + 16];
        a0.x = f0.x; a0.y = f0.y; a1.x = f1.x; a1.y = f1.y;
        if (lo7) { float2 f2 = ap[cl + 32]; a2.x = f2.x; a2.y = f2.y; }
    }
    const unsigned int* xrp = xru + (size_t)node * (HCDIM / 2) + hcl;
    v2f r0 = cvt2(xrp[cl]);
    v2f r1 = cvt2(xrp[cl + 16]);
    v2f r2 = lo7 ? cvt2(xrp[cl + 32]) : (v2f)(0.f);

    float l = 0.f;
    v2f acc0 = (v2f)(0.f), acc1 = (v2f)(0.f), acc2 = (v2f)(0.f);
    int e0 = row_ptr[node], e1 = row_ptr[node + 1];
    int e = e0;
    for (; e + 2 <= e1; e += 2) {
        int ja = __builtin_amdgcn_readfirstlane(col[e]);
        int jb = __builtin_amdgcn_readfirstlane(col[e + 1]);
        gat_edge(xlu, ja, hcl, cl, lo7, r0, r1, r2, a0, a1, a2, l, acc0, acc1, acc2);
        gat_edge(xlu, jb, hcl, cl, lo7, r0, r1, r2, a0, a1, a2, l, acc0, acc1, acc2);
    }
    if (e < e1) {
        int j = __builtin_amdgcn_readfirstlane(col[e]);
        gat_edge(xlu, j, hcl, cl, lo7, r0, r1, r2, a0, a1, a2, l, acc0, acc1, acc2);
    }

    if (!hv) return;
    float inv = 1.f / l;               // l > 0 (self-loop)
    int hoff = head * CDIM;            // true offset for store/bias
    size_t rbase = (size_t)node * HCDIM + hoff;
    const float2* bp = (const float2*)(bias1 + hoff);
    unsigned int* op = (unsigned int*)(h_out + rbase);
    #pragma unroll
    for (int k = 0; k < 3; k++) {
        if (k == 2 && !lo7) break;
        v2f a = (k == 0) ? acc0 : (k == 1) ? acc1 : acc2;
        float2 bb = bp[cl + 16 * k];
        float x0 = a.x * inv + bb.x;
        float x1 = a.y * inv + bb.y;
        x0 = x0 > 0.f ? x0 : (__expf(x0) - 1.f);   // ELU
        x1 = x1 > 0.f ? x1 : (__expf(x1) - 1.f);
        unsigned int o = (unsigned int)f2bf(x0) | ((unsigned int)f2bf(x1) << 16);
        op[cl + 16 * k] = o;
    }
}

// ---------------------------------------------------------------------------
// GCN aggregation v3 (unchanged)
// ---------------------------------------------------------------------------
__global__ __launch_bounds__(256) void gcn_agg_kernel(
        const unsigned short* __restrict__ h, const int* __restrict__ row_ptr,
        const int* __restrict__ col, const float* __restrict__ dinv,
        unsigned short* __restrict__ agg) {
    int node = blockIdx.x * 4 + (threadIdx.x >> 6);
    if (node >= NNODES) return;
    int ln = threadIdx.x & 63;
    bool hasC = ln < 3;
    float accA[8] = {}, accB[4] = {}, accC[4] = {};
    int e0 = row_ptr[node], e1 = row_ptr[node + 1];
    int e = e0;
    int jn = (e < e1) ? col[e] : 0;
    for (; e < e1; ) {
        int j = __builtin_amdgcn_readfirstlane(jn);
        ++e;
        jn = (e < e1) ? col[e] : 0;
        float s = dinv[j];
        const unsigned short* hr = h + (size_t)j * HCDIM;
        bf16x8_t u = *(const bf16x8_t*)(hr + 8 * ln);
        ushort4 v4 = *(const ushort4*)(hr + 512 + 4 * ln);
        ushort4 w4 = hasC ? *(const ushort4*)(hr + 768 + 4 * ln) : make_ushort4(0, 0, 0, 0);
        #pragma unroll
        for (int k = 0; k < 8; k++) accA[k] = fmaf(s, bf2f((unsigned short)u[k]), accA[k]);
        accB[0] = fmaf(s, bf2f(v4.x), accB[0]);
        accB[1] = fmaf(s, bf2f(v4.y), accB[1]);
        accB[2] = fmaf(s, bf2f(v4.z), accB[2]);
        accB[3] = fmaf(s, bf2f(v4.w), accB[3]);
        accC[0] = fmaf(s, bf2f(w4.x), accC[0]);
        accC[1] = fmaf(s, bf2f(w4.y), accC[1]);
        accC[2] = fmaf(s, bf2f(w4.z), accC[2]);
        accC[3] = fmaf(s, bf2f(w4.w), accC[3]);
    }
    float di = dinv[node];
    unsigned short* ar = agg + (size_t)node * HCDIM;
    ushort4 o1, o2, ob;
    o1.x = f2bf(accA[0] * di); o1.y = f2bf(accA[1] * di);
    o1.z = f2bf(accA[2] * di); o1.w = f2bf(accA[3] * di);
    o2.x = f2bf(accA[4] * di); o2.y = f2bf(accA[5] * di);
    o2.z = f2bf(accA[6] * di); o2.w = f2bf(accA[7] * di);
    ob.x = f2bf(accB[0] * di); ob.y = f2bf(accB[1] * di);
    ob.z = f2bf(accB[2] * di); ob.w = f2bf(accB[3] * di);
    *(ushort4*)(ar + 8 * ln) = o1;
    *(ushort4*)(ar + 8 * ln + 4) = o2;
    *(ushort4*)(ar + 512 + 4 * ln) = ob;
    if (hasC) {
        ushort4 oc;
        oc.x = f2bf(accC[0] * di); oc.y = f2bf(accC[1] * di);
        oc.z = f2bf(accC[2] * di); oc.w = f2bf(accC[3] * di);
        *(ushort4*)(ar + 768 + 4 * ln) = oc;
    }
}

// ---------------------------------------------------------------------------
// BT prep: BT[n][k] = bf16(W_gcn[k][n]), zero-padded to [NPAD][KPAD]
// ---------------------------------------------------------------------------
__global__ void btprep_kernel(const float* __restrict__ W, unsigned short* __restrict__ BT) {
    int idx = blockIdx.x * 256 + threadIdx.x;
    if (idx >= NPAD * KPAD) return;
    int n = idx / KPAD, k = idx - n * KPAD;
    float v = (n < HCDIM && k < HCDIM) ? W[(size_t)k * HCDIM + n] : 0.f;
    BT[idx] = f2bf(v);
}

// ---------------------------------------------------------------------------
// GEMM2 MFMA fused (unchanged from round 5/6)
// ---------------------------------------------------------------------------
__global__ __launch_bounds__(256) void gemm2_pool_kernel(
        const unsigned short* __restrict__ A, const unsigned short* __restrict__ BT,
        const float* __restrict__ bias, const int* __restrict__ batch,
        float* __restrict__ out, int M) {
    __shared__ unsigned short smem[128 * LDT];
    unsigned short* As = smem;
    unsigned short* Bs = smem + 4096;
    __shared__ int bsh[BM];

    int t = threadIdx.x;
    int lane = t & 63, w = t >> 6;
    int bm = blockIdx.y * BM, bn = blockIdx.x * BN;

    if (t < BM) {
        int row = bm + t;
        bsh[t] = (row < M) ? batch[row] : -1;
    }

    int m16 = lane & 15, q = lane >> 4;
    int wr = (w >> 1) * 64, wc = (w & 1) * 64;

    int lrow = lane >> 2;
    int gchunk = (lane & 3) ^ (lrow & 3);
    int rA0 = 32 * w + lrow;
    const unsigned short* ga0 = A  + (size_t)(bm + rA0)      * HCDIM + gchunk * 8;
    const unsigned short* ga1 = A  + (size_t)(bm + rA0 + 16) * HCDIM + gchunk * 8;
    const unsigned short* gb0 = BT + (size_t)(bn + rA0)      * KPAD  + gchunk * 8;
    const unsigned short* gb1 = BT + (size_t)(bn + rA0 + 16) * KPAD  + gchunk * 8;
    unsigned short* la0 = As + (32 * w) * 32;
    unsigned short* la1 = As + (32 * w + 16) * 32;
    unsigned short* lb0 = Bs + (32 * w) * 32;
    unsigned short* lb1 = Bs + (32 * w + 16) * 32;

    f32x4_t acc[4][4];
    #pragma unroll
    for (int i = 0; i < 4; i++)
        #pragma unroll
        for (int j = 0; j < 4; j++)
            acc[i][j] = (f32x4_t)(0.f);

    for (int k0 = 0; k0 < KPAD; k0 += BK) {
        __syncthreads();
        async_ld16(ga0 + k0, la0);
        async_ld16(ga1 + k0, la1);
        async_ld16(gb0 + k0, lb0);
        async_ld16(gb1 + k0, lb1);
        __syncthreads();

        bf16x8_t af[4], bf[4];
        #pragma unroll
        for (int i = 0; i < 4; i++) {
            int row = wr + i * 16 + m16;
            af[i] = *(const bf16x8_t*)&As[row * 32 + (q ^ (row & 3)) * 8];
        }
        #pragma unroll
        for (int j = 0; j < 4; j++) {
            int row = wc + j * 16 + m16;
            bf[j] = *(const bf16x8_t*)&Bs[row * 32 + (q ^ (row & 3)) * 8];
        }
        #pragma unroll
        for (int i = 0; i < 4; i++)
            #pragma unroll
            for (int j = 0; j < 4; j++)
                acc[i][j] = __builtin_amdgcn_mfma_f32_16x16x32_bf16(af[i], bf[j], acc[i][j], 0, 0, 0);
    }

    float bvj[4];
    #pragma unroll
    for (int j = 0; j < 4; j++) {
        int gcc = bn + wc + j * 16 + m16;
        bvj[j] = (gcc < HCDIM) ? bias[gcc] : 0.f;
    }

    #pragma unroll
    for (int p = 0; p < 2; p++) {
        __syncthreads();
        if ((w >> 1) == p) {
            #pragma unroll
            for (int i = 0; i < 4; i++) {
                #pragma unroll
                for (int j = 0; j < 4; j++) {
                    int colc = wc + j * 16 + m16;
                    ushort4 o;
                    float v0 = acc[i][j][0] + bvj[j];
                    float v1 = acc[i][j][1] + bvj[j];
                    float v2 = acc[i][j][2] + bvj[j];
                    float v3 = acc[i][j][3] + bvj[j];
                    o.x = f2bf(v0 > 0.f ? v0 : 0.f);
                    o.y = f2bf(v1 > 0.f ? v1 : 0.f);
                    o.z = f2bf(v2 > 0.f ? v2 : 0.f);
                    o.w = f2bf(v3 > 0.f ? v3 : 0.f);
                    *(ushort4*)&smem[colc * LDT + i * 16 + q * 4] = o;
                }
            }
        }
        __syncthreads();
        int colp = t & 127;
        int rb = (t >> 7) * 32;
        int gc = bn + colp;
        if (gc < HCDIM) {
            int cur = -1; float mx = 0.f, sm = 0.f;
            bool done = false;
            for (int rr = rb; rr < rb + 32 && !done; rr += 4) {
                ushort4 u = *(const ushort4*)&smem[colp * LDT + rr];
                unsigned short us[4] = {u.x, u.y, u.z, u.w};
                #pragma unroll
                for (int s2 = 0; s2 < 4; s2++) {
                    int b = bsh[64 * p + rr + s2];
                    if (b < 0) { done = true; break; }
                    float v = bf2f(us[s2]);
                    if (b != cur) {
                        if (cur >= 0) {
                            atomicMax((int*)(out + (size_t)cur * (2 * HCDIM) + gc), __float_as_int(mx));
                            atomicAdd(out + (size_t)cur * (2 * HCDIM) + HCDIM + gc, sm);
                        }
                        cur = b; mx = v; sm = v;
                    } else { mx = fmaxf(mx, v); sm += v; }
                }
            }
            if (cur >= 0) {
                atomicMax((int*)(out + (size_t)cur * (2 * HCDIM) + gc), __float_as_int(mx));
                atomicAdd(out + (size_t)cur * (2 * HCDIM) + HCDIM + gc, sm);
            }
        }
    }
}

// divide the mean slots by counts
__global__ void finalize_kernel(float* __restrict__ out, const int* __restrict__ bst) {
    int i = blockIdx.x * blockDim.x + threadIdx.x;
    if (i >= NBATCH * HCDIM) return;
    int b = i / HCDIM, c = i - b * HCDIM;
    int cnt = bst[b + 1] - bst[b];
    out[(size_t)b * (2 * HCDIM) + HCDIM + c] /= (float)(cnt > 0 ? cnt : 1);
}

// ---------------------------------------------------------------------------
extern "C" void kernel_launch(void* const* d_in, const int* in_sizes, int n_in,
                              void* d_out, int out_size, void* d_ws, size_t ws_size,
                              hipStream_t stream) {
    const float* x       = (const float*)d_in[0];
    const int*   ei      = (const int*)d_in[1];
    const int*   batch   = (const int*)d_in[2];
    const float* W_l     = (const float*)d_in[3];
    const float* W_r     = (const float*)d_in[4];
    const float* att     = (const float*)d_in[5];
    const float* bias1   = (const float*)d_in[6];
    const float* W_gcn   = (const float*)d_in[7];
    const float* bias_gcn= (const float*)d_in[8];
    float* out = (float*)d_out;

    char* w = (char*)d_ws;
    const size_t BIGH = (size_t)NNODES * HCDIM * sizeof(unsigned short);  // 78,000,000
    unsigned short* xl  = (unsigned short*)(w);          // later reused as agg
    unsigned short* xr  = (unsigned short*)(w + BIGH);   // becomes h; later BT
    unsigned short* agg = xl;
    unsigned short* BT  = xr;                            // h dead after gcn_agg
    char* sm = w + 2 * BIGH;
    int*   rowp = (int*)(sm);                    sm += 50048 * 4;
    int*   col  = (int*)(sm);                    sm += 450048 * 4;
    float* dinv = (float*)(sm);                  sm += 50048 * 4;
    int*   bst  = (int*)(sm);                    sm += 512 * 4;
    int*   bsum = (int*)(sm);                    sm += 256 * 4;
    // scratch region S: deg+curs during CSR build, then Wc (1664*128*2 B)
    char* S = sm;                                sm += 426240;
    int*   deg  = (int*)(S);
    int*   curs = (int*)(S + 200192);
    unsigned short* Wc = (unsigned short*)(S);
    size_t needed = (size_t)(sm - (char*)d_ws);
    if (ws_size < needed) return;   // fail soft instead of OOB fault

    // --- zero-init (out for atomics + deg) ---
    zero_kernel<<<(NBATCH * 2 * HCDIM + 255) / 256, 256, 0, stream>>>(
        out, NBATCH * 2 * HCDIM, deg, NNODES);

    // --- CSR build (multi-block scan; bstart fused in scan2, dinv in scan3) ---
    {
        int eblocks = (ETOT + 255) / 256;
        int nblocks = (NNODES + 255) / 256;     // 196
        count_kernel<<<eblocks, 256, 0, stream>>>(ei, deg);
        scan1_kernel<<<nblocks, 256, 0, stream>>>(deg, rowp, bsum);
        scan2_kernel<<<1, 512, 0, stream>>>(bsum, rowp, nblocks, batch, bst);
        scan3_kernel<<<nblocks, 256, 0, stream>>>(rowp, bsum, curs, deg, dinv);
        fill_kernel<<<eblocks, 256, 0, stream>>>(ei, curs, col);
    }

    // --- Wc = [W_l|W_r]^T bf16 padded (overwrites deg/curs: CSR build done) ---
    wprep_kernel<<<(NP1 * KP1 + 255) / 256, 256, 0, stream>>>(W_l, W_r, Wc);

    // --- fused GEMM1 (MFMA): xl|xr = x @ [W_l|W_r] ---
    gemm1_kernel<<<(NNODES + 127) / 128, 256, 0, stream>>>(x, Wc, xl, xr, NNODES);

    // --- GATv2 + ELU (writes h over xr) ---
    {
        int jobs = NNODES * 3;
        int blocks = (jobs + 3) / 4;
        gat_kernel<<<blocks, 256, 0, stream>>>(xl, xr, rowp, col, att, bias1, xr);
    }

    // --- GCN aggregate (h -> agg, overwrites xl space) ---
    gcn_agg_kernel<<<(NNODES + 3) / 4, 256, 0, stream>>>(xr, rowp, col, dinv, agg);

    // --- W_gcn^T -> bf16 padded (into xr region; h is dead) ---
    btprep_kernel<<<(NPAD * KPAD + 255) / 256, 256, 0, stream>>>(W_gcn, BT);

    // --- GEMM2 (MFMA, async staging) + bias + relu + fused pooling ---
    {
        dim3 grid(NPAD / BN, (NNODES + BM - 1) / BM);   // (7, 391)
        gemm2_pool_kernel<<<grid, 256, 0, stream>>>(agg, BT, bias_gcn, batch, out, NNODES);
    }

    // --- finalize means ---
    finalize_kernel<<<(NBATCH * HCDIM + 255) / 256, 256, 0, stream>>>(out, bst);
}

// Round 8
// 666.267 us; speedup vs baseline: 2.9999x; 1.0752x over previous
//
#include <hip/hip_runtime.h>
#include <hip/hip_bf16.h>
#include <math.h>

#define NNODES   50000
#define INDIM    78
#define NHEADS   10
#define CDIM     78
#define HCDIM    780
#define NEDGES   400000
#define NBATCH   256
#define ETOT     (NEDGES + NNODES)   // 450000, with self-loops
#define NEG_SLOPE 0.2f

// GEMM2 MFMA tiling
#define BM 128
#define BN 128
#define BK 64             // K-tile (13 iters over KPAD)
#define KPAD 832          // 13 * 64
#define NPAD 896          // 7 * 128
#define LDT 68            // transposed epilogue tile stride (ushorts)

// GEMM1 (fused xl|xr) tiling
#define KP1 128           // 78 padded to 4*32
#define NP1 1664          // 13 * 128  (780 xl | 780 xr | pad)

typedef __attribute__((ext_vector_type(8))) short bf16x8_t;
typedef __attribute__((ext_vector_type(4))) float f32x4_t;
typedef __attribute__((ext_vector_type(2))) float v2f;

__device__ __forceinline__ float bf2f(unsigned short u) {
    union { unsigned int i; float f; } v; v.i = ((unsigned int)u) << 16; return v.f;
}
__device__ __forceinline__ unsigned short f2bf(float f) {
    __hip_bfloat16 h = __float2bfloat16(f);
    return *reinterpret_cast<unsigned short*>(&h);
}
// packed pair of bf16 (even channel in low half) -> v2f
__device__ __forceinline__ v2f cvt2(unsigned int u) {
    union { unsigned int i; float f; } lo, hi;
    lo.i = u << 16;
    hi.i = u & 0xFFFF0000u;
    v2f r; r.x = lo.f; r.y = hi.f; return r;
}
__device__ __forceinline__ v2f vabs2(v2f t) {
    union { v2f f; unsigned long long u; } x; x.f = t;
    x.u &= 0x7FFFFFFF7FFFFFFFull; return x.f;
}
// sum over each 16-lane group via DPP (no LDS)
__device__ __forceinline__ float dpp_red16(float x) {
    int y;
    y = __builtin_amdgcn_update_dpp(0, __float_as_int(x), 0xB1, 0xF, 0xF, true);
    x += __int_as_float(y);
    y = __builtin_amdgcn_update_dpp(0, __float_as_int(x), 0x4E, 0xF, 0xF, true);
    x += __int_as_float(y);
    y = __builtin_amdgcn_update_dpp(0, __float_as_int(x), 0x141, 0xF, 0xF, true);
    x += __int_as_float(y);
    y = __builtin_amdgcn_update_dpp(0, __float_as_int(x), 0x140, 0xF, 0xF, true);
    x += __int_as_float(y);
    return x;
}

// async global->LDS, 16 B per lane; LDS base wave-uniform (HW: base+lane*16)
__device__ __forceinline__ void async_ld16(const unsigned short* g, unsigned short* l) {
    __builtin_amdgcn_global_load_lds(
        (const __attribute__((address_space(1))) void*)g,
        (__attribute__((address_space(3))) void*)l, 16, 0, 0);
}

// ---------------------------------------------------------------------------
// zero-init (out for atomics + deg for CSR) in one launch
// ---------------------------------------------------------------------------
__global__ void zero_kernel(float* __restrict__ outp, int nf, int* __restrict__ deg, int ni) {
    int i = blockIdx.x * blockDim.x + threadIdx.x;
    if (i < nf) outp[i] = 0.f;
    if (i < ni) deg[i] = 0;
}

// ---------------------------------------------------------------------------
// CSR build
// ---------------------------------------------------------------------------
__global__ void count_kernel(const int* __restrict__ ei, int* __restrict__ deg) {
    int e = blockIdx.x * blockDim.x + threadIdx.x;
    if (e >= ETOT) return;
    int d = (e < NEDGES) ? ei[NEDGES + e] : (e - NEDGES);
    atomicAdd(&deg[d], 1);
}

__global__ void scan1_kernel(const int* __restrict__ deg, int* __restrict__ rowp,
                             int* __restrict__ bsum) {
    __shared__ int s[256];
    int t = threadIdx.x, b = blockIdx.x;
    int i = b * 256 + t;
    int v = (i < NNODES) ? deg[i] : 0;
    s[t] = v;
    __syncthreads();
    #pragma unroll
    for (int off = 1; off < 256; off <<= 1) {
        int y = (t >= off) ? s[t - off] : 0;
        __syncthreads();
        s[t] += y;
        __syncthreads();
    }
    int incl = s[t];
    if (i < NNODES) rowp[i] = incl - v;
    if (t == 255) bsum[b] = incl;
}

__global__ void scan2_kernel(int* __restrict__ bsum, int* __restrict__ rowp, int nblk,
                             const int* __restrict__ batch, int* __restrict__ bst) {
    __shared__ int s[256];
    int t = threadIdx.x;
    int v = 0;
    if (t < 256) { v = (t < nblk) ? bsum[t] : 0; s[t] = v; }
    __syncthreads();
    #pragma unroll
    for (int off = 1; off < 256; off <<= 1) {
        int y = (t < 256 && t >= off) ? s[t - off] : 0;
        __syncthreads();
        if (t < 256) s[t] += y;
        __syncthreads();
    }
    if (t < 256) {
        int incl = s[t];
        if (t < nblk) bsum[t] = incl - v;
        if (t == 255) rowp[NNODES] = incl;
    } else {
        int b = t - 256;
        int lo = 0, hi = NNODES;
        while (lo < hi) { int mid = (lo + hi) >> 1; if (batch[mid] < b) lo = mid + 1; else hi = mid; }
        bst[b] = lo;
        if (t == 511) bst[NBATCH] = NNODES;
    }
}

__global__ void scan3_kernel(int* __restrict__ rowp, const int* __restrict__ bsum,
                             int* __restrict__ curs, const int* __restrict__ deg,
                             float* __restrict__ dinv) {
    int i = blockIdx.x * 256 + threadIdx.x;
    if (i >= NNODES) return;
    int r = rowp[i] + bsum[i >> 8];
    rowp[i] = r;
    curs[i] = r;
    dinv[i] = rsqrtf((float)deg[i]);
}

__global__ void fill_kernel(const int* __restrict__ ei,
                            int* __restrict__ cursor, int* __restrict__ col) {
    int e = blockIdx.x * blockDim.x + threadIdx.x;
    if (e >= ETOT) return;
    int s, d;
    if (e < NEDGES) { s = ei[e]; d = ei[NEDGES + e]; }
    else            { s = d = e - NEDGES; }
    int pos = atomicAdd(&cursor[d], 1);
    col[pos] = s;
}

// ---------------------------------------------------------------------------
// Wc prep: Wc[n][k] = bf16([W_l|W_r]^T), zero-padded to [NP1][KP1]
// ---------------------------------------------------------------------------
__global__ void wprep_kernel(const float* __restrict__ Wl, const float* __restrict__ Wr,
                             unsigned short* __restrict__ Wc) {
    int idx = blockIdx.x * 256 + threadIdx.x;
    if (idx >= NP1 * KP1) return;
    int n = idx >> 7, k = idx & 127;
    float v = 0.f;
    if (k < INDIM) {
        if (n < HCDIM)            v = Wl[(size_t)k * HCDIM + n];
        else if (n < 2 * HCDIM)   v = Wr[(size_t)k * HCDIM + (n - HCDIM)];
    }
    Wc[idx] = f2bf(v);
}

// ---------------------------------------------------------------------------
// GEMM1 fused MFMA: [xl|xr] = x @ [W_l|W_r]  (bf16 out)
// Rotation swizzle: LDS pos p of row r holds global chunk (p - (r>>1)) & 3
// -> 8 consecutive lanes of a fragment read hit 8 distinct bank groups.
// ---------------------------------------------------------------------------
__global__ __launch_bounds__(256) void gemm1_kernel(
        const float* __restrict__ x, const unsigned short* __restrict__ Wc,
        unsigned short* __restrict__ xl, unsigned short* __restrict__ xr, int M) {
    __shared__ unsigned short As[4 * 4096];
    __shared__ unsigned short Bs[4 * 4096];
    int t = threadIdx.x;
    int lane = t & 63, w = t >> 6;
    int bm = blockIdx.x * 128;

    for (int idx = t; idx < 128 * 128; idx += 256) {
        int row = idx >> 7, k = idx & 127;
        int kc = k >> 5, ch = (k >> 3) & 3, e = k & 7;
        int gr = bm + row;
        float v = (gr < M && k < INDIM) ? x[(size_t)gr * INDIM + k] : 0.f;
        As[kc * 4096 + row * 32 + (((ch + (row >> 1)) & 3) * 8) + e] = f2bf(v);
    }

    int lrow = lane >> 2;
    int gch = ((lane & 3) - (lane >> 3)) & 3;   // global chunk staged at pos lane&3
    int m16 = lane & 15, q = lane >> 4;
    int wr = (w >> 1) * 64, wcc = (w & 1) * 64;

    for (int nb = 0; nb < 13; nb++) {
        __syncthreads();
        #pragma unroll
        for (int kc = 0; kc < 4; kc++) {
            const unsigned short* gb = Wc + ((size_t)(nb * 128 + 32 * w + lrow)) * KP1
                                          + kc * 32 + gch * 8;
            unsigned short* lb = Bs + kc * 4096 + (32 * w) * 32;
            async_ld16(gb, lb);
            async_ld16(gb + 16 * KP1, lb + 16 * 32);
        }
        __syncthreads();

        f32x4_t acc[4][4];
        #pragma unroll
        for (int i = 0; i < 4; i++)
            #pragma unroll
            for (int j = 0; j < 4; j++)
                acc[i][j] = (f32x4_t)(0.f);

        #pragma unroll
        for (int kc = 0; kc < 4; kc++) {
            bf16x8_t af[4], bf[4];
            #pragma unroll
            for (int i = 0; i < 4; i++) {
                int row = wr + i * 16 + m16;
                af[i] = *(const bf16x8_t*)&As[kc * 4096 + row * 32 + (((q + (row >> 1)) & 3) * 8)];
            }
            #pragma unroll
            for (int j = 0; j < 4; j++) {
                int row = wcc + j * 16 + m16;
                bf[j] = *(const bf16x8_t*)&Bs[kc * 4096 + row * 32 + (((q + (row >> 1)) & 3) * 8)];
            }
            #pragma unroll
            for (int i = 0; i < 4; i++)
                #pragma unroll
                for (int j = 0; j < 4; j++)
                    acc[i][j] = __builtin_amdgcn_mfma_f32_16x16x32_bf16(af[i], bf[j], acc[i][j], 0, 0, 0);
        }

        #pragma unroll
        for (int j = 0; j < 4; j++) {
            int ng = nb * 128 + wcc + j * 16 + m16;
            if (ng >= 2 * HCDIM) continue;
            unsigned short* dst = (ng < HCDIM) ? (xl + ng) : (xr + (ng - HCDIM));
            #pragma unroll
            for (int i = 0; i < 4; i++) {
                #pragma unroll
                for (int rr = 0; rr < 4; rr++) {
                    int row = bm + wr + i * 16 + q * 4 + rr;
                    if (row < M) dst[(size_t)row * HCDIM] = f2bf(acc[i][j][rr]);
                }
            }
        }
    }
}

// ---------------------------------------------------------------------------
// GATv2 aggregation v4 (unchanged from round 7)
// ---------------------------------------------------------------------------
__device__ __forceinline__ void gat_edge(
        const unsigned int* __restrict__ xlu, int j, int hcl, int cl, bool lo7,
        v2f r0, v2f r1, v2f r2, v2f a0, v2f a1, v2f a2,
        float& l, v2f& acc0, v2f& acc1, v2f& acc2) {
    const unsigned int* xp = xlu + (size_t)j * (HCDIM / 2) + hcl;
    unsigned int u0 = xp[cl];
    unsigned int u1 = xp[cl + 16];
    unsigned int u2 = lo7 ? xp[cl + 32] : 0u;
    v2f v0 = cvt2(u0), v1 = cvt2(u1), v2v = cvt2(u2);
    v2f t0 = v0 + r0, t1 = v1 + r1, t2 = v2v + r2;
    v2f e0 = t0 * 0.6f + vabs2(t0) * 0.4f;
    v2f e1 = t1 * 0.6f + vabs2(t1) * 0.4f;
    v2f e2 = t2 * 0.6f + vabs2(t2) * 0.4f;
    v2f s2 = e0 * a0 + e1 * a1 + e2 * a2;
    float part = dpp_red16(s2.x + s2.y);
    float p = __expf(part);
    l += p;
    acc0 += p * v0; acc1 += p * v1; acc2 += p * v2v;
}

__global__ __launch_bounds__(256) void gat_kernel(
        const unsigned short* __restrict__ xl, const unsigned short* xr,
        const int* __restrict__ row_ptr, const int* __restrict__ col,
        const float* __restrict__ att, const float* __restrict__ bias1,
        unsigned short* h_out) {
    int wid = blockIdx.x * 4 + (threadIdx.x >> 6);
    int node = wid / 3;
    int hq = wid - node * 3;
    if (node >= NNODES) return;
    int lane = threadIdx.x & 63;
    int g = lane >> 4;
    int cl = lane & 15;
    bool lo7 = cl < 7;
    int head = hq * 4 + g;
    bool hv = head < NHEADS;
    int hC = hv ? head : (NHEADS - 1);
    int hcl = hC * (CDIM / 2);
    const unsigned int* xlu = (const unsigned int*)xl;
    const unsigned int* xru = (const unsigned int*)xr;

    const float2* ap = (const float2*)(att + hC * CDIM);
    v2f a0 = (v2f)(0.f), a1 = (v2f)(0.f), a2 = (v2f)(0.f);
    if (hv) {
        float2 f0 = ap[cl], f1 = ap[cl + 16];
        a0.x = f0.x; a0.y = f0.y; a1.x = f1.x; a1.y = f1.y;
        if (lo7) { float2 f2 = ap[cl + 32]; a2.x = f2.x; a2.y = f2.y; }
    }
    const unsigned int* xrp = xru + (size_t)node * (HCDIM / 2) + hcl;
    v2f r0 = cvt2(xrp[cl]);
    v2f r1 = cvt2(xrp[cl + 16]);
    v2f r2 = lo7 ? cvt2(xrp[cl + 32]) : (v2f)(0.f);

    float l = 0.f;
    v2f acc0 = (v2f)(0.f), acc1 = (v2f)(0.f), acc2 = (v2f)(0.f);
    int e0 = row_ptr[node], e1 = row_ptr[node + 1];
    int e = e0;
    for (; e + 2 <= e1; e += 2) {
        int ja = __builtin_amdgcn_readfirstlane(col[e]);
        int jb = __builtin_amdgcn_readfirstlane(col[e + 1]);
        gat_edge(xlu, ja, hcl, cl, lo7, r0, r1, r2, a0, a1, a2, l, acc0, acc1, acc2);
        gat_edge(xlu, jb, hcl, cl, lo7, r0, r1, r2, a0, a1, a2, l, acc0, acc1, acc2);
    }
    if (e < e1) {
        int j = __builtin_amdgcn_readfirstlane(col[e]);
        gat_edge(xlu, j, hcl, cl, lo7, r0, r1, r2, a0, a1, a2, l, acc0, acc1, acc2);
    }

    if (!hv) return;
    float inv = 1.f / l;
    int hoff = head * CDIM;
    size_t rbase = (size_t)node * HCDIM + hoff;
    const float2* bp = (const float2*)(bias1 + hoff);
    unsigned int* op = (unsigned int*)(h_out + rbase);
    #pragma unroll
    for (int k = 0; k < 3; k++) {
        if (k == 2 && !lo7) break;
        v2f a = (k == 0) ? acc0 : (k == 1) ? acc1 : acc2;
        float2 bb = bp[cl + 16 * k];
        float x0 = a.x * inv + bb.x;
        float x1 = a.y * inv + bb.y;
        x0 = x0 > 0.f ? x0 : (__expf(x0) - 1.f);
        x1 = x1 > 0.f ? x1 : (__expf(x1) - 1.f);
        unsigned int o = (unsigned int)f2bf(x0) | ((unsigned int)f2bf(x1) << 16);
        op[cl + 16 * k] = o;
    }
}

// ---------------------------------------------------------------------------
// GCN aggregation v3 (unchanged)
// ---------------------------------------------------------------------------
__global__ __launch_bounds__(256) void gcn_agg_kernel(
        const unsigned short* __restrict__ h, const int* __restrict__ row_ptr,
        const int* __restrict__ col, const float* __restrict__ dinv,
        unsigned short* __restrict__ agg) {
    int node = blockIdx.x * 4 + (threadIdx.x >> 6);
    if (node >= NNODES) return;
    int ln = threadIdx.x & 63;
    bool hasC = ln < 3;
    float accA[8] = {}, accB[4] = {}, accC[4] = {};
    int e0 = row_ptr[node], e1 = row_ptr[node + 1];
    int e = e0;
    int jn = (e < e1) ? col[e] : 0;
    for (; e < e1; ) {
        int j = __builtin_amdgcn_readfirstlane(jn);
        ++e;
        jn = (e < e1) ? col[e] : 0;
        float s = dinv[j];
        const unsigned short* hr = h + (size_t)j * HCDIM;
        bf16x8_t u = *(const bf16x8_t*)(hr + 8 * ln);
        ushort4 v4 = *(const ushort4*)(hr + 512 + 4 * ln);
        ushort4 w4 = hasC ? *(const ushort4*)(hr + 768 + 4 * ln) : make_ushort4(0, 0, 0, 0);
        #pragma unroll
        for (int k = 0; k < 8; k++) accA[k] = fmaf(s, bf2f((unsigned short)u[k]), accA[k]);
        accB[0] = fmaf(s, bf2f(v4.x), accB[0]);
        accB[1] = fmaf(s, bf2f(v4.y), accB[1]);
        accB[2] = fmaf(s, bf2f(v4.z), accB[2]);
        accB[3] = fmaf(s, bf2f(v4.w), accB[3]);
        accC[0] = fmaf(s, bf2f(w4.x), accC[0]);
        accC[1] = fmaf(s, bf2f(w4.y), accC[1]);
        accC[2] = fmaf(s, bf2f(w4.z), accC[2]);
        accC[3] = fmaf(s, bf2f(w4.w), accC[3]);
    }
    float di = dinv[node];
    unsigned short* ar = agg + (size_t)node * HCDIM;
    ushort4 o1, o2, ob;
    o1.x = f2bf(accA[0] * di); o1.y = f2bf(accA[1] * di);
    o1.z = f2bf(accA[2] * di); o1.w = f2bf(accA[3] * di);
    o2.x = f2bf(accA[4] * di); o2.y = f2bf(accA[5] * di);
    o2.z = f2bf(accA[6] * di); o2.w = f2bf(accA[7] * di);
    ob.x = f2bf(accB[0] * di); ob.y = f2bf(accB[1] * di);
    ob.z = f2bf(accB[2] * di); ob.w = f2bf(accB[3] * di);
    *(ushort4*)(ar + 8 * ln) = o1;
    *(ushort4*)(ar + 8 * ln + 4) = o2;
    *(ushort4*)(ar + 512 + 4 * ln) = ob;
    if (hasC) {
        ushort4 oc;
        oc.x = f2bf(accC[0] * di); oc.y = f2bf(accC[1] * di);
        oc.z = f2bf(accC[2] * di); oc.w = f2bf(accC[3] * di);
        *(ushort4*)(ar + 768 + 4 * ln) = oc;
    }
}

// ---------------------------------------------------------------------------
// BT prep: BT[n][k] = bf16(W_gcn[k][n]), zero-padded to [NPAD][KPAD]
// ---------------------------------------------------------------------------
__global__ void btprep_kernel(const float* __restrict__ W, unsigned short* __restrict__ BT) {
    int idx = blockIdx.x * 256 + threadIdx.x;
    if (idx >= NPAD * KPAD) return;
    int n = idx / KPAD, k = idx - n * KPAD;
    float v = (n < HCDIM && k < HCDIM) ? W[(size_t)k * HCDIM + n] : 0.f;
    BT[idx] = f2bf(v);
}

// ---------------------------------------------------------------------------
// GEMM2 MFMA fused v3: BK=64, conflict-free rotation swizzle.
// LDS tile [128 rows][64 cols]: row stride 128 B = exactly 32 banks, so the
// chunk position alone decides the bank group. LDS pos p of row r holds global
// chunk (p - r) & 7; fragment read uses pos = (4*half + q + row) & 7 -> within
// any 8 consecutive lanes all 8 bank groups distinct (0 conflicts).
// ---------------------------------------------------------------------------
__global__ __launch_bounds__(256) void gemm2_pool_kernel(
        const unsigned short* __restrict__ A, const unsigned short* __restrict__ BT,
        const float* __restrict__ bias, const int* __restrict__ batch,
        float* __restrict__ out, int M) {
    __shared__ unsigned short smem[2 * 128 * 64];   // As|Bs 32 KB; epilogue reuses
    unsigned short* As = smem;                       // [128][64]
    unsigned short* Bs = smem + 128 * 64;            // [128][64]
    __shared__ int bsh[BM];

    int t = threadIdx.x;
    int lane = t & 63, w = t >> 6;
    int bm = blockIdx.y * BM, bn = blockIdx.x * BN;

    if (t < BM) {
        int row = bm + t;
        bsh[t] = (row < M) ? batch[row] : -1;
    }

    int m16 = lane & 15, q = lane >> 4;
    int wr = (w >> 1) * 64, wc = (w & 1) * 64;

    // staging: wave w covers rows [32w, 32w+32); 4 issues of 8 rows per matrix.
    // lane -> (local row lrow8 = lane>>3, LDS chunk pos c8 = lane&7);
    // global chunk staged at pos c8 of row r is (c8 - r) & 7.
    int lrow8 = lane >> 3;
    int c8 = lane & 7;
    int gch = (c8 - lrow8) & 7;        // row base multiple of 8 -> uniform
    const unsigned short* gA = A  + (size_t)(bm + 32 * w + lrow8) * HCDIM + gch * 8;
    const unsigned short* gB = BT + (size_t)(bn + 32 * w + lrow8) * KPAD  + gch * 8;
    unsigned short* lA = As + (32 * w) * 64;
    unsigned short* lB = Bs + (32 * w) * 64;

    f32x4_t acc[4][4];
    #pragma unroll
    for (int i = 0; i < 4; i++)
        #pragma unroll
        for (int j = 0; j < 4; j++)
            acc[i][j] = (f32x4_t)(0.f);

    for (int k0 = 0; k0 < KPAD; k0 += BK) {
        __syncthreads();                   // all waves done reading prev tile
        #pragma unroll
        for (int ib = 0; ib < 4; ib++) {
            async_ld16(gA + (size_t)(8 * ib) * HCDIM + k0, lA + (8 * ib) * 64);
            async_ld16(gB + (size_t)(8 * ib) * KPAD  + k0, lB + (8 * ib) * 64);
        }
        __syncthreads();                   // DMA drained

        #pragma unroll
        for (int half = 0; half < 2; half++) {
            bf16x8_t af[4], bf[4];
            #pragma unroll
            for (int i = 0; i < 4; i++) {
                int row = wr + i * 16 + m16;
                af[i] = *(const bf16x8_t*)&As[row * 64 + ((4 * half + q + row) & 7) * 8];
            }
            #pragma unroll
            for (int j = 0; j < 4; j++) {
                int row = wc + j * 16 + m16;
                bf[j] = *(const bf16x8_t*)&Bs[row * 64 + ((4 * half + q + row) & 7) * 8];
            }
            #pragma unroll
            for (int i = 0; i < 4; i++)
                #pragma unroll
                for (int j = 0; j < 4; j++)
                    acc[i][j] = __builtin_amdgcn_mfma_f32_16x16x32_bf16(af[i], bf[j], acc[i][j], 0, 0, 0);
        }
    }

    float bvj[4];
    #pragma unroll
    for (int j = 0; j < 4; j++) {
        int gcc = bn + wc + j * 16 + m16;
        bvj[j] = (gcc < HCDIM) ? bias[gcc] : 0.f;
    }

    // two-phase epilogue: rows [64p, 64p+64) via transposed Ct[col][row]
    #pragma unroll
    for (int p = 0; p < 2; p++) {
        __syncthreads();   // staging reads / previous-phase pooling done
        if ((w >> 1) == p) {
            #pragma unroll
            for (int i = 0; i < 4; i++) {
                #pragma unroll
                for (int j = 0; j < 4; j++) {
                    int colc = wc + j * 16 + m16;
                    ushort4 o;
                    float v0 = acc[i][j][0] + bvj[j];
                    float v1 = acc[i][j][1] + bvj[j];
                    float v2 = acc[i][j][2] + bvj[j];
                    float v3 = acc[i][j][3] + bvj[j];
                    o.x = f2bf(v0 > 0.f ? v0 : 0.f);
                    o.y = f2bf(v1 > 0.f ? v1 : 0.f);
                    o.z = f2bf(v2 > 0.f ? v2 : 0.f);
                    o.w = f2bf(v3 > 0.f ? v3 : 0.f);
                    *(ushort4*)&smem[colc * LDT + i * 16 + q * 4] = o;
                }
            }
        }
        __syncthreads();
        int colp = t & 127;
        int rb = (t >> 7) * 32;
        int gc = bn + colp;
        if (gc < HCDIM) {
            int cur = -1; float mx = 0.f, sm = 0.f;
            bool done = false;
            for (int rr = rb; rr < rb + 32 && !done; rr += 4) {
                ushort4 u = *(const ushort4*)&smem[colp * LDT + rr];
                unsigned short us[4] = {u.x, u.y, u.z, u.w};
                #pragma unroll
                for (int s2 = 0; s2 < 4; s2++) {
                    int b = bsh[64 * p + rr + s2];
                    if (b < 0) { done = true; break; }
                    float v = bf2f(us[s2]);
                    if (b != cur) {
                        if (cur >= 0) {
                            atomicMax((int*)(out + (size_t)cur * (2 * HCDIM) + gc), __float_as_int(mx));
                            atomicAdd(out + (size_t)cur * (2 * HCDIM) + HCDIM + gc, sm);
                        }
                        cur = b; mx = v; sm = v;
                    } else { mx = fmaxf(mx, v); sm += v; }
                }
            }
            if (cur >= 0) {
                atomicMax((int*)(out + (size_t)cur * (2 * HCDIM) + gc), __float_as_int(mx));
                atomicAdd(out + (size_t)cur * (2 * HCDIM) + HCDIM + gc, sm);
            }
        }
    }
}

// divide the mean slots by counts
__global__ void finalize_kernel(float* __restrict__ out, const int* __restrict__ bst) {
    int i = blockIdx.x * blockDim.x + threadIdx.x;
    if (i >= NBATCH * HCDIM) return;
    int b = i / HCDIM, c = i - b * HCDIM;
    int cnt = bst[b + 1] - bst[b];
    out[(size_t)b * (2 * HCDIM) + HCDIM + c] /= (float)(cnt > 0 ? cnt : 1);
}

// ---------------------------------------------------------------------------
extern "C" void kernel_launch(void* const* d_in, const int* in_sizes, int n_in,
                              void* d_out, int out_size, void* d_ws, size_t ws_size,
                              hipStream_t stream) {
    const float* x       = (const float*)d_in[0];
    const int*   ei      = (const int*)d_in[1];
    const int*   batch   = (const int*)d_in[2];
    const float* W_l     = (const float*)d_in[3];
    const float* W_r     = (const float*)d_in[4];
    const float* att     = (const float*)d_in[5];
    const float* bias1   = (const float*)d_in[6];
    const float* W_gcn   = (const float*)d_in[7];
    const float* bias_gcn= (const float*)d_in[8];
    float* out = (float*)d_out;

    char* w = (char*)d_ws;
    const size_t BIGH = (size_t)NNODES * HCDIM * sizeof(unsigned short);  // 78,000,000
    unsigned short* xl  = (unsigned short*)(w);          // later reused as agg
    unsigned short* xr  = (unsigned short*)(w + BIGH);   // becomes h; later BT
    unsigned short* agg = xl;
    unsigned short* BT  = xr;                            // h dead after gcn_agg
    char* sm = w + 2 * BIGH;
    int*   rowp = (int*)(sm);                    sm += 50048 * 4;
    int*   col  = (int*)(sm);                    sm += 450048 * 4;
    float* dinv = (float*)(sm);                  sm += 50048 * 4;
    int*   bst  = (int*)(sm);                    sm += 512 * 4;
    int*   bsum = (int*)(sm);                    sm += 256 * 4;
    char* S = sm;                                sm += 426240;
    int*   deg  = (int*)(S);
    int*   curs = (int*)(S + 200192);
    unsigned short* Wc = (unsigned short*)(S);
    size_t needed = (size_t)(sm - (char*)d_ws);
    if (ws_size < needed) return;   // fail soft instead of OOB fault

    // --- zero-init (out for atomics + deg) ---
    zero_kernel<<<(NBATCH * 2 * HCDIM + 255) / 256, 256, 0, stream>>>(
        out, NBATCH * 2 * HCDIM, deg, NNODES);

    // --- CSR build ---
    {
        int eblocks = (ETOT + 255) / 256;
        int nblocks = (NNODES + 255) / 256;     // 196
        count_kernel<<<eblocks, 256, 0, stream>>>(ei, deg);
        scan1_kernel<<<nblocks, 256, 0, stream>>>(deg, rowp, bsum);
        scan2_kernel<<<1, 512, 0, stream>>>(bsum, rowp, nblocks, batch, bst);
        scan3_kernel<<<nblocks, 256, 0, stream>>>(rowp, bsum, curs, deg, dinv);
        fill_kernel<<<eblocks, 256, 0, stream>>>(ei, curs, col);
    }

    // --- Wc = [W_l|W_r]^T bf16 padded (overwrites deg/curs) ---
    wprep_kernel<<<(NP1 * KP1 + 255) / 256, 256, 0, stream>>>(W_l, W_r, Wc);

    // --- fused GEMM1 (MFMA): xl|xr = x @ [W_l|W_r] ---
    gemm1_kernel<<<(NNODES + 127) / 128, 256, 0, stream>>>(x, Wc, xl, xr, NNODES);

    // --- GATv2 + ELU (writes h over xr) ---
    {
        int jobs = NNODES * 3;
        int blocks = (jobs + 3) / 4;
        gat_kernel<<<blocks, 256, 0, stream>>>(xl, xr, rowp, col, att, bias1, xr);
    }

    // --- GCN aggregate (h -> agg, overwrites xl space) ---
    gcn_agg_kernel<<<(NNODES + 3) / 4, 256, 0, stream>>>(xr, rowp, col, dinv, agg);

    // --- W_gcn^T -> bf16 padded (into xr region; h is dead) ---
    btprep_kernel<<<(NPAD * KPAD + 255) / 256, 256, 0, stream>>>(W_gcn, BT);

    // --- GEMM2 (MFMA, BK=64, swizzled) + bias + relu + fused pooling ---
    {
        dim3 grid(NPAD / BN, (NNODES + BM - 1) / BM);   // (7, 391)
        gemm2_pool_kernel<<<grid, 256, 0, stream>>>(agg, BT, bias_gcn, batch, out, NNODES);
    }

    // --- finalize means ---
    finalize_kernel<<<(NBATCH * HCDIM + 255) / 256, 256, 0, stream>>>(out, bst);
}

// Round 9
// 642.386 us; speedup vs baseline: 3.1114x; 1.0372x over previous
//
#include <hip/hip_runtime.h>
#include <hip/hip_bf16.h>
#include <math.h>

#define NNODES   50000
#define INDIM    78
#define NHEADS   10
#define CDIM     78
#define HCDIM    780
#define NEDGES   400000
#define NBATCH   256
#define ETOT     (NEDGES + NNODES)   // 450000, with self-loops
#define NEG_SLOPE 0.2f

// GEMM2 MFMA tiling
#define BM 128
#define BN 128
#define BK 64             // K-tile (13 iters over KPAD)
#define KPAD 832          // 13 * 64
#define NPAD 896          // 7 * 128
#define LDT 68            // transposed epilogue tile stride (ushorts)

// GEMM1 (fused xl|xr) tiling
#define KP1 128           // 78 padded to 4*32
#define NP1 1664          // 13 * 128  (780 xl | 780 xr | pad)

typedef __attribute__((ext_vector_type(8))) short bf16x8_t;
typedef __attribute__((ext_vector_type(4))) float f32x4_t;
typedef __attribute__((ext_vector_type(2))) float v2f;

__device__ __forceinline__ float bf2f(unsigned short u) {
    union { unsigned int i; float f; } v; v.i = ((unsigned int)u) << 16; return v.f;
}
__device__ __forceinline__ unsigned short f2bf(float f) {
    __hip_bfloat16 h = __float2bfloat16(f);
    return *reinterpret_cast<unsigned short*>(&h);
}
// packed pair of bf16 (even channel in low half) -> v2f
__device__ __forceinline__ v2f cvt2(unsigned int u) {
    union { unsigned int i; float f; } lo, hi;
    lo.i = u << 16;
    hi.i = u & 0xFFFF0000u;
    v2f r; r.x = lo.f; r.y = hi.f; return r;
}
__device__ __forceinline__ v2f vabs2(v2f t) {
    union { v2f f; unsigned long long u; } x; x.f = t;
    x.u &= 0x7FFFFFFF7FFFFFFFull; return x.f;
}
// sum over each 16-lane group via DPP (no LDS)
__device__ __forceinline__ float dpp_red16(float x) {
    int y;
    y = __builtin_amdgcn_update_dpp(0, __float_as_int(x), 0xB1, 0xF, 0xF, true);
    x += __int_as_float(y);
    y = __builtin_amdgcn_update_dpp(0, __float_as_int(x), 0x4E, 0xF, 0xF, true);
    x += __int_as_float(y);
    y = __builtin_amdgcn_update_dpp(0, __float_as_int(x), 0x141, 0xF, 0xF, true);
    x += __int_as_float(y);
    y = __builtin_amdgcn_update_dpp(0, __float_as_int(x), 0x140, 0xF, 0xF, true);
    x += __int_as_float(y);
    return x;
}

// async global->LDS, 16 B per lane; LDS base wave-uniform (HW: base+lane*16)
__device__ __forceinline__ void async_ld16(const unsigned short* g, unsigned short* l) {
    __builtin_amdgcn_global_load_lds(
        (const __attribute__((address_space(1))) void*)g,
        (__attribute__((address_space(3))) void*)l, 16, 0, 0);
}

// ---------------------------------------------------------------------------
// zero-init (out for atomics + deg for CSR) in one launch
// ---------------------------------------------------------------------------
__global__ void zero_kernel(float* __restrict__ outp, int nf, int* __restrict__ deg, int ni) {
    int i = blockIdx.x * blockDim.x + threadIdx.x;
    if (i < nf) outp[i] = 0.f;
    if (i < ni) deg[i] = 0;
}

// ---------------------------------------------------------------------------
// CSR build
// ---------------------------------------------------------------------------
__global__ void count_kernel(const int* __restrict__ ei, int* __restrict__ deg) {
    int e = blockIdx.x * blockDim.x + threadIdx.x;
    if (e >= ETOT) return;
    int d = (e < NEDGES) ? ei[NEDGES + e] : (e - NEDGES);
    atomicAdd(&deg[d], 1);
}

__global__ void scan1_kernel(const int* __restrict__ deg, int* __restrict__ rowp,
                             int* __restrict__ bsum) {
    __shared__ int s[256];
    int t = threadIdx.x, b = blockIdx.x;
    int i = b * 256 + t;
    int v = (i < NNODES) ? deg[i] : 0;
    s[t] = v;
    __syncthreads();
    #pragma unroll
    for (int off = 1; off < 256; off <<= 1) {
        int y = (t >= off) ? s[t - off] : 0;
        __syncthreads();
        s[t] += y;
        __syncthreads();
    }
    int incl = s[t];
    if (i < NNODES) rowp[i] = incl - v;
    if (t == 255) bsum[b] = incl;
}

__global__ void scan2_kernel(int* __restrict__ bsum, int* __restrict__ rowp, int nblk,
                             const int* __restrict__ batch, int* __restrict__ bst) {
    __shared__ int s[256];
    int t = threadIdx.x;
    int v = 0;
    if (t < 256) { v = (t < nblk) ? bsum[t] : 0; s[t] = v; }
    __syncthreads();
    #pragma unroll
    for (int off = 1; off < 256; off <<= 1) {
        int y = (t < 256 && t >= off) ? s[t - off] : 0;
        __syncthreads();
        if (t < 256) s[t] += y;
        __syncthreads();
    }
    if (t < 256) {
        int incl = s[t];
        if (t < nblk) bsum[t] = incl - v;
        if (t == 255) rowp[NNODES] = incl;
    } else {
        int b = t - 256;
        int lo = 0, hi = NNODES;
        while (lo < hi) { int mid = (lo + hi) >> 1; if (batch[mid] < b) lo = mid + 1; else hi = mid; }
        bst[b] = lo;
        if (t == 511) bst[NBATCH] = NNODES;
    }
}

__global__ void scan3_kernel(int* __restrict__ rowp, const int* __restrict__ bsum,
                             int* __restrict__ curs, const int* __restrict__ deg,
                             float* __restrict__ dinv) {
    int i = blockIdx.x * 256 + threadIdx.x;
    if (i >= NNODES) return;
    int r = rowp[i] + bsum[i >> 8];
    rowp[i] = r;
    curs[i] = r;
    dinv[i] = rsqrtf((float)deg[i]);
}

__global__ void fill_kernel(const int* __restrict__ ei,
                            int* __restrict__ cursor, int* __restrict__ col) {
    int e = blockIdx.x * blockDim.x + threadIdx.x;
    if (e >= ETOT) return;
    int s, d;
    if (e < NEDGES) { s = ei[e]; d = ei[NEDGES + e]; }
    else            { s = d = e - NEDGES; }
    int pos = atomicAdd(&cursor[d], 1);
    col[pos] = s;
}

// ---------------------------------------------------------------------------
// Wc prep: Wc[n][k] = bf16([W_l|W_r]^T), zero-padded to [NP1][KP1]
// ---------------------------------------------------------------------------
__global__ void wprep_kernel(const float* __restrict__ Wl, const float* __restrict__ Wr,
                             unsigned short* __restrict__ Wc) {
    int idx = blockIdx.x * 256 + threadIdx.x;
    if (idx >= NP1 * KP1) return;
    int n = idx >> 7, k = idx & 127;
    float v = 0.f;
    if (k < INDIM) {
        if (n < HCDIM)            v = Wl[(size_t)k * HCDIM + n];
        else if (n < 2 * HCDIM)   v = Wr[(size_t)k * HCDIM + (n - HCDIM)];
    }
    Wc[idx] = f2bf(v);
}

// ---------------------------------------------------------------------------
// GEMM1 fused MFMA: [xl|xr] = x @ [W_l|W_r]  (bf16 out) — unchanged (rot swizzle)
// ---------------------------------------------------------------------------
__global__ __launch_bounds__(256) void gemm1_kernel(
        const float* __restrict__ x, const unsigned short* __restrict__ Wc,
        unsigned short* __restrict__ xl, unsigned short* __restrict__ xr, int M) {
    __shared__ unsigned short As[4 * 4096];
    __shared__ unsigned short Bs[4 * 4096];
    int t = threadIdx.x;
    int lane = t & 63, w = t >> 6;
    int bm = blockIdx.x * 128;

    for (int idx = t; idx < 128 * 128; idx += 256) {
        int row = idx >> 7, k = idx & 127;
        int kc = k >> 5, ch = (k >> 3) & 3, e = k & 7;
        int gr = bm + row;
        float v = (gr < M && k < INDIM) ? x[(size_t)gr * INDIM + k] : 0.f;
        As[kc * 4096 + row * 32 + (((ch + (row >> 1)) & 3) * 8) + e] = f2bf(v);
    }

    int lrow = lane >> 2;
    int gch = ((lane & 3) - (lane >> 3)) & 3;
    int m16 = lane & 15, q = lane >> 4;
    int wr = (w >> 1) * 64, wcc = (w & 1) * 64;

    for (int nb = 0; nb < 13; nb++) {
        __syncthreads();
        #pragma unroll
        for (int kc = 0; kc < 4; kc++) {
            const unsigned short* gb = Wc + ((size_t)(nb * 128 + 32 * w + lrow)) * KP1
                                          + kc * 32 + gch * 8;
            unsigned short* lb = Bs + kc * 4096 + (32 * w) * 32;
            async_ld16(gb, lb);
            async_ld16(gb + 16 * KP1, lb + 16 * 32);
        }
        __syncthreads();

        f32x4_t acc[4][4];
        #pragma unroll
        for (int i = 0; i < 4; i++)
            #pragma unroll
            for (int j = 0; j < 4; j++)
                acc[i][j] = (f32x4_t)(0.f);

        #pragma unroll
        for (int kc = 0; kc < 4; kc++) {
            bf16x8_t af[4], bf[4];
            #pragma unroll
            for (int i = 0; i < 4; i++) {
                int row = wr + i * 16 + m16;
                af[i] = *(const bf16x8_t*)&As[kc * 4096 + row * 32 + (((q + (row >> 1)) & 3) * 8)];
            }
            #pragma unroll
            for (int j = 0; j < 4; j++) {
                int row = wcc + j * 16 + m16;
                bf[j] = *(const bf16x8_t*)&Bs[kc * 4096 + row * 32 + (((q + (row >> 1)) & 3) * 8)];
            }
            #pragma unroll
            for (int i = 0; i < 4; i++)
                #pragma unroll
                for (int j = 0; j < 4; j++)
                    acc[i][j] = __builtin_amdgcn_mfma_f32_16x16x32_bf16(af[i], bf[j], acc[i][j], 0, 0, 0);
        }

        #pragma unroll
        for (int j = 0; j < 4; j++) {
            int ng = nb * 128 + wcc + j * 16 + m16;
            if (ng >= 2 * HCDIM) continue;
            unsigned short* dst = (ng < HCDIM) ? (xl + ng) : (xr + (ng - HCDIM));
            #pragma unroll
            for (int i = 0; i < 4; i++) {
                #pragma unroll
                for (int rr = 0; rr < 4; rr++) {
                    int row = bm + wr + i * 16 + q * 4 + rr;
                    if (row < M) dst[(size_t)row * HCDIM] = f2bf(acc[i][j][rr]);
                }
            }
        }
    }
}

// ---------------------------------------------------------------------------
// GATv2 aggregation v5: 5 waves per 2 nodes (zero dead lanes).
//  slots 0,1: node A heads 0-3 / 4-7; slots 2,3: node B; slot 4 (straddle):
//  groups 0,1 -> A heads 8,9; groups 2,3 -> B heads 8,9.
// att pre-scaled by 0.6*log2e / 0.4*log2e: score*log2e = sum t*a6 + |t|*a4,
// p = exp2(part) (softmax invariant under the rescale).
// ---------------------------------------------------------------------------
__device__ __forceinline__ void gat_body(
        const unsigned int* __restrict__ xp, int cl, bool lo7, bool live,
        v2f r0, v2f r1, v2f r2,
        v2f a60, v2f a61, v2f a62, v2f a40, v2f a41, v2f a42,
        float& l, v2f& acc0, v2f& acc1, v2f& acc2) {
    unsigned int u0 = xp[cl];
    unsigned int u1 = xp[cl + 16];
    unsigned int u2 = lo7 ? xp[cl + 32] : 0u;
    v2f v0 = cvt2(u0), v1 = cvt2(u1), v2v = cvt2(u2);
    v2f t0 = v0 + r0, t1 = v1 + r1, t2 = v2v + r2;
    v2f s2 = t0 * a60 + vabs2(t0) * a40;
    s2 += t1 * a61 + vabs2(t1) * a41;
    s2 += t2 * a62 + vabs2(t2) * a42;
    float part = dpp_red16(s2.x + s2.y);
    float p = __builtin_amdgcn_exp2f(part);
    p = live ? p : 0.f;
    l += p;
    acc0 += p * v0; acc1 += p * v1; acc2 += p * v2v;
}

__global__ __launch_bounds__(256) void gat_kernel(
        const unsigned short* __restrict__ xl, const unsigned short* xr,
        const int* __restrict__ row_ptr, const int* __restrict__ col,
        const float* __restrict__ att, const float* __restrict__ bias1,
        unsigned short* h_out) {
    int wid = blockIdx.x * 4 + (threadIdx.x >> 6);
    int pair = wid / 5;
    int slot = wid - 5 * pair;
    if (pair >= NNODES / 2) return;
    int lane = threadIdx.x & 63;
    int g = lane >> 4, cl = lane & 15;
    bool lo7 = cl < 7;
    bool strad = (slot == 4);
    int node, head;
    if (!strad) { node = 2 * pair + (slot >> 1); head = ((slot & 1) << 2) + g; }
    else        { node = 2 * pair + (g >> 1);    head = 8 + (g & 1); }
    int hcl = head * (CDIM / 2);
    const unsigned int* xlu = (const unsigned int*)xl;
    const unsigned int* xru = (const unsigned int*)xr;

    const float L6 = 0.6f * 1.4426950408889634f;
    const float L4 = 0.4f * 1.4426950408889634f;
    const float2* ap = (const float2*)(att + head * CDIM);
    float2 f0 = ap[cl], f1 = ap[cl + 16];
    float2 f2 = lo7 ? ap[cl + 32] : make_float2(0.f, 0.f);
    v2f a60, a61, a62, a40, a41, a42;
    a60.x = f0.x * L6; a60.y = f0.y * L6;
    a61.x = f1.x * L6; a61.y = f1.y * L6;
    a62.x = f2.x * L6; a62.y = f2.y * L6;
    a40.x = f0.x * L4; a40.y = f0.y * L4;
    a41.x = f1.x * L4; a41.y = f1.y * L4;
    a42.x = f2.x * L4; a42.y = f2.y * L4;

    const unsigned int* xrp = xru + (size_t)node * (HCDIM / 2) + hcl;
    v2f r0 = cvt2(xrp[cl]);
    v2f r1 = cvt2(xrp[cl + 16]);
    v2f r2 = lo7 ? cvt2(xrp[cl + 32]) : (v2f)(0.f);

    float l = 0.f;
    v2f acc0 = (v2f)(0.f), acc1 = (v2f)(0.f), acc2 = (v2f)(0.f);

    if (!strad) {
        int e0 = row_ptr[node], e1 = row_ptr[node + 1];
        int e = e0;
        for (; e + 2 <= e1; e += 2) {
            int ja = __builtin_amdgcn_readfirstlane(col[e]);
            int jb = __builtin_amdgcn_readfirstlane(col[e + 1]);
            gat_body(xlu + (size_t)ja * (HCDIM / 2) + hcl, cl, lo7, true,
                     r0, r1, r2, a60, a61, a62, a40, a41, a42, l, acc0, acc1, acc2);
            gat_body(xlu + (size_t)jb * (HCDIM / 2) + hcl, cl, lo7, true,
                     r0, r1, r2, a60, a61, a62, a40, a41, a42, l, acc0, acc1, acc2);
        }
        if (e < e1) {
            int j = __builtin_amdgcn_readfirstlane(col[e]);
            gat_body(xlu + (size_t)j * (HCDIM / 2) + hcl, cl, lo7, true,
                     r0, r1, r2, a60, a61, a62, a40, a41, a42, l, acc0, acc1, acc2);
        }
    } else {
        // straddle: halves own different nodes; joint loop over max degree
        int re0 = row_ptr[node], re1 = row_ptr[node + 1];
        int deg = re1 - re0;
        int dA = __builtin_amdgcn_readlane(deg, 0);
        int dB = __builtin_amdgcn_readlane(deg, 32);
        int iters = dA > dB ? dA : dB;
        for (int i = 0; i < iters; i++) {
            bool live = i < deg;
            int ec = re0 + (live ? i : deg - 1);   // clamped: loads stay in-bounds
            int j = col[ec];                        // same addr within half -> broadcast
            gat_body(xlu + (size_t)j * (HCDIM / 2) + hcl, cl, lo7, live,
                     r0, r1, r2, a60, a61, a62, a40, a41, a42, l, acc0, acc1, acc2);
        }
    }

    float inv = 1.f / l;                   // l > 0 (self-loop)
    size_t rbase = (size_t)node * HCDIM + head * CDIM;
    const float2* bp = (const float2*)(bias1 + head * CDIM);
    unsigned int* op = (unsigned int*)(h_out + rbase);
    #pragma unroll
    for (int k = 0; k < 3; k++) {
        if (k == 2 && !lo7) break;
        v2f a = (k == 0) ? acc0 : (k == 1) ? acc1 : acc2;
        float2 bb = bp[cl + 16 * k];
        float x0 = a.x * inv + bb.x;
        float x1 = a.y * inv + bb.y;
        x0 = x0 > 0.f ? x0 : (__expf(x0) - 1.f);   // ELU
        x1 = x1 > 0.f ? x1 : (__expf(x1) - 1.f);
        unsigned int o = (unsigned int)f2bf(x0) | ((unsigned int)f2bf(x1) << 16);
        op[cl + 16 * k] = o;
    }
}

// ---------------------------------------------------------------------------
// GCN aggregation v3 (unchanged)
// ---------------------------------------------------------------------------
__global__ __launch_bounds__(256) void gcn_agg_kernel(
        const unsigned short* __restrict__ h, const int* __restrict__ row_ptr,
        const int* __restrict__ col, const float* __restrict__ dinv,
        unsigned short* __restrict__ agg) {
    int node = blockIdx.x * 4 + (threadIdx.x >> 6);
    if (node >= NNODES) return;
    int ln = threadIdx.x & 63;
    bool hasC = ln < 3;
    float accA[8] = {}, accB[4] = {}, accC[4] = {};
    int e0 = row_ptr[node], e1 = row_ptr[node + 1];
    int e = e0;
    int jn = (e < e1) ? col[e] : 0;
    for (; e < e1; ) {
        int j = __builtin_amdgcn_readfirstlane(jn);
        ++e;
        jn = (e < e1) ? col[e] : 0;
        float s = dinv[j];
        const unsigned short* hr = h + (size_t)j * HCDIM;
        bf16x8_t u = *(const bf16x8_t*)(hr + 8 * ln);
        ushort4 v4 = *(const ushort4*)(hr + 512 + 4 * ln);
        ushort4 w4 = hasC ? *(const ushort4*)(hr + 768 + 4 * ln) : make_ushort4(0, 0, 0, 0);
        #pragma unroll
        for (int k = 0; k < 8; k++) accA[k] = fmaf(s, bf2f((unsigned short)u[k]), accA[k]);
        accB[0] = fmaf(s, bf2f(v4.x), accB[0]);
        accB[1] = fmaf(s, bf2f(v4.y), accB[1]);
        accB[2] = fmaf(s, bf2f(v4.z), accB[2]);
        accB[3] = fmaf(s, bf2f(v4.w), accB[3]);
        accC[0] = fmaf(s, bf2f(w4.x), accC[0]);
        accC[1] = fmaf(s, bf2f(w4.y), accC[1]);
        accC[2] = fmaf(s, bf2f(w4.z), accC[2]);
        accC[3] = fmaf(s, bf2f(w4.w), accC[3]);
    }
    float di = dinv[node];
    unsigned short* ar = agg + (size_t)node * HCDIM;
    ushort4 o1, o2, ob;
    o1.x = f2bf(accA[0] * di); o1.y = f2bf(accA[1] * di);
    o1.z = f2bf(accA[2] * di); o1.w = f2bf(accA[3] * di);
    o2.x = f2bf(accA[4] * di); o2.y = f2bf(accA[5] * di);
    o2.z = f2bf(accA[6] * di); o2.w = f2bf(accA[7] * di);
    ob.x = f2bf(accB[0] * di); ob.y = f2bf(accB[1] * di);
    ob.z = f2bf(accB[2] * di); ob.w = f2bf(accB[3] * di);
    *(ushort4*)(ar + 8 * ln) = o1;
    *(ushort4*)(ar + 8 * ln + 4) = o2;
    *(ushort4*)(ar + 512 + 4 * ln) = ob;
    if (hasC) {
        ushort4 oc;
        oc.x = f2bf(accC[0] * di); oc.y = f2bf(accC[1] * di);
        oc.z = f2bf(accC[2] * di); oc.w = f2bf(accC[3] * di);
        *(ushort4*)(ar + 768 + 4 * ln) = oc;
    }
}

// ---------------------------------------------------------------------------
// BT prep: BT[n][k] = bf16(W_gcn[k][n]), zero-padded to [NPAD][KPAD]
// ---------------------------------------------------------------------------
__global__ void btprep_kernel(const float* __restrict__ W, unsigned short* __restrict__ BT) {
    int idx = blockIdx.x * 256 + threadIdx.x;
    if (idx >= NPAD * KPAD) return;
    int n = idx / KPAD, k = idx - n * KPAD;
    float v = (n < HCDIM && k < HCDIM) ? W[(size_t)k * HCDIM + n] : 0.f;
    BT[idx] = f2bf(v);
}

// ---------------------------------------------------------------------------
// GEMM2 MFMA fused v4: BK=64, rotation swizzle, XCD-aware band mapping.
// Flat 1-D grid; decode so all 7 column-tiles of one A-row-band land on the
// same XCD (f & 7 selects band%8) -> A band fetched into one L2, reused 7x.
// ---------------------------------------------------------------------------
__global__ __launch_bounds__(256) void gemm2_pool_kernel(
        const unsigned short* __restrict__ A, const unsigned short* __restrict__ BT,
        const float* __restrict__ bias, const int* __restrict__ batch,
        float* __restrict__ out, int M) {
    int f = blockIdx.x;
    int xcd = f & 7, inner = f >> 3;
    int bq = inner / 7, colt = inner - 7 * bq;
    int band = 8 * bq + xcd;
    if (band >= (M + BM - 1) / BM) return;   // block-uniform
    int bm = band * BM, bn = colt * BN;

    __shared__ unsigned short smem[2 * 128 * 64];   // As|Bs 32 KB; epilogue reuses
    unsigned short* As = smem;                       // [128][64]
    unsigned short* Bs = smem + 128 * 64;            // [128][64]
    __shared__ int bsh[BM];

    int t = threadIdx.x;
    int lane = t & 63, w = t >> 6;

    if (t < BM) {
        int row = bm + t;
        bsh[t] = (row < M) ? batch[row] : -1;
    }

    int m16 = lane & 15, q = lane >> 4;
    int wr = (w >> 1) * 64, wc = (w & 1) * 64;

    int lrow8 = lane >> 3;
    int c8 = lane & 7;
    int gch = (c8 - lrow8) & 7;
    const unsigned short* gA = A  + (size_t)(bm + 32 * w + lrow8) * HCDIM + gch * 8;
    const unsigned short* gB = BT + (size_t)(bn + 32 * w + lrow8) * KPAD  + gch * 8;
    unsigned short* lA = As + (32 * w) * 64;
    unsigned short* lB = Bs + (32 * w) * 64;

    f32x4_t acc[4][4];
    #pragma unroll
    for (int i = 0; i < 4; i++)
        #pragma unroll
        for (int j = 0; j < 4; j++)
            acc[i][j] = (f32x4_t)(0.f);

    for (int k0 = 0; k0 < KPAD; k0 += BK) {
        __syncthreads();
        #pragma unroll
        for (int ib = 0; ib < 4; ib++) {
            async_ld16(gA + (size_t)(8 * ib) * HCDIM + k0, lA + (8 * ib) * 64);
            async_ld16(gB + (size_t)(8 * ib) * KPAD  + k0, lB + (8 * ib) * 64);
        }
        __syncthreads();

        #pragma unroll
        for (int half = 0; half < 2; half++) {
            bf16x8_t af[4], bf[4];
            #pragma unroll
            for (int i = 0; i < 4; i++) {
                int row = wr + i * 16 + m16;
                af[i] = *(const bf16x8_t*)&As[row * 64 + ((4 * half + q + row) & 7) * 8];
            }
            #pragma unroll
            for (int j = 0; j < 4; j++) {
                int row = wc + j * 16 + m16;
                bf[j] = *(const bf16x8_t*)&Bs[row * 64 + ((4 * half + q + row) & 7) * 8];
            }
            #pragma unroll
            for (int i = 0; i < 4; i++)
                #pragma unroll
                for (int j = 0; j < 4; j++)
                    acc[i][j] = __builtin_amdgcn_mfma_f32_16x16x32_bf16(af[i], bf[j], acc[i][j], 0, 0, 0);
        }
    }

    float bvj[4];
    #pragma unroll
    for (int j = 0; j < 4; j++) {
        int gcc = bn + wc + j * 16 + m16;
        bvj[j] = (gcc < HCDIM) ? bias[gcc] : 0.f;
    }

    #pragma unroll
    for (int p = 0; p < 2; p++) {
        __syncthreads();
        if ((w >> 1) == p) {
            #pragma unroll
            for (int i = 0; i < 4; i++) {
                #pragma unroll
                for (int j = 0; j < 4; j++) {
                    int colc = wc + j * 16 + m16;
                    ushort4 o;
                    float v0 = acc[i][j][0] + bvj[j];
                    float v1 = acc[i][j][1] + bvj[j];
                    float v2 = acc[i][j][2] + bvj[j];
                    float v3 = acc[i][j][3] + bvj[j];
                    o.x = f2bf(v0 > 0.f ? v0 : 0.f);
                    o.y = f2bf(v1 > 0.f ? v1 : 0.f);
                    o.z = f2bf(v2 > 0.f ? v2 : 0.f);
                    o.w = f2bf(v3 > 0.f ? v3 : 0.f);
                    *(ushort4*)&smem[colc * LDT + i * 16 + q * 4] = o;
                }
            }
        }
        __syncthreads();
        int colp = t & 127;
        int rb = (t >> 7) * 32;
        int gc = bn + colp;
        if (gc < HCDIM) {
            int cur = -1; float mx = 0.f, sm = 0.f;
            bool done = false;
            for (int rr = rb; rr < rb + 32 && !done; rr += 4) {
                ushort4 u = *(const ushort4*)&smem[colp * LDT + rr];
                unsigned short us[4] = {u.x, u.y, u.z, u.w};
                #pragma unroll
                for (int s2 = 0; s2 < 4; s2++) {
                    int b = bsh[64 * p + rr + s2];
                    if (b < 0) { done = true; break; }
                    float v = bf2f(us[s2]);
                    if (b != cur) {
                        if (cur >= 0) {
                            atomicMax((int*)(out + (size_t)cur * (2 * HCDIM) + gc), __float_as_int(mx));
                            atomicAdd(out + (size_t)cur * (2 * HCDIM) + HCDIM + gc, sm);
                        }
                        cur = b; mx = v; sm = v;
                    } else { mx = fmaxf(mx, v); sm += v; }
                }
            }
            if (cur >= 0) {
                atomicMax((int*)(out + (size_t)cur * (2 * HCDIM) + gc), __float_as_int(mx));
                atomicAdd(out + (size_t)cur * (2 * HCDIM) + HCDIM + gc, sm);
            }
        }
    }
}

// divide the mean slots by counts
__global__ void finalize_kernel(float* __restrict__ out, const int* __restrict__ bst) {
    int i = blockIdx.x * blockDim.x + threadIdx.x;
    if (i >= NBATCH * HCDIM) return;
    int b = i / HCDIM, c = i - b * HCDIM;
    int cnt = bst[b + 1] - bst[b];
    out[(size_t)b * (2 * HCDIM) + HCDIM + c] /= (float)(cnt > 0 ? cnt : 1);
}

// ---------------------------------------------------------------------------
extern "C" void kernel_launch(void* const* d_in, const int* in_sizes, int n_in,
                              void* d_out, int out_size, void* d_ws, size_t ws_size,
                              hipStream_t stream) {
    const float* x       = (const float*)d_in[0];
    const int*   ei      = (const int*)d_in[1];
    const int*   batch   = (const int*)d_in[2];
    const float* W_l     = (const float*)d_in[3];
    const float* W_r     = (const float*)d_in[4];
    const float* att     = (const float*)d_in[5];
    const float* bias1   = (const float*)d_in[6];
    const float* W_gcn   = (const float*)d_in[7];
    const float* bias_gcn= (const float*)d_in[8];
    float* out = (float*)d_out;

    char* w = (char*)d_ws;
    const size_t BIGH = (size_t)NNODES * HCDIM * sizeof(unsigned short);  // 78,000,000
    unsigned short* xl  = (unsigned short*)(w);          // later reused as agg
    unsigned short* xr  = (unsigned short*)(w + BIGH);   // becomes h; later BT
    unsigned short* agg = xl;
    unsigned short* BT  = xr;                            // h dead after gcn_agg
    char* sm = w + 2 * BIGH;
    int*   rowp = (int*)(sm);                    sm += 50048 * 4;
    int*   col  = (int*)(sm);                    sm += 450048 * 4;
    float* dinv = (float*)(sm);                  sm += 50048 * 4;
    int*   bst  = (int*)(sm);                    sm += 512 * 4;
    int*   bsum = (int*)(sm);                    sm += 256 * 4;
    char* S = sm;                                sm += 426240;
    int*   deg  = (int*)(S);
    int*   curs = (int*)(S + 200192);
    unsigned short* Wc = (unsigned short*)(S);
    size_t needed = (size_t)(sm - (char*)d_ws);
    if (ws_size < needed) return;   // fail soft instead of OOB fault

    // --- zero-init (out for atomics + deg) ---
    zero_kernel<<<(NBATCH * 2 * HCDIM + 255) / 256, 256, 0, stream>>>(
        out, NBATCH * 2 * HCDIM, deg, NNODES);

    // --- CSR build ---
    {
        int eblocks = (ETOT + 255) / 256;
        int nblocks = (NNODES + 255) / 256;     // 196
        count_kernel<<<eblocks, 256, 0, stream>>>(ei, deg);
        scan1_kernel<<<nblocks, 256, 0, stream>>>(deg, rowp, bsum);
        scan2_kernel<<<1, 512, 0, stream>>>(bsum, rowp, nblocks, batch, bst);
        scan3_kernel<<<nblocks, 256, 0, stream>>>(rowp, bsum, curs, deg, dinv);
        fill_kernel<<<eblocks, 256, 0, stream>>>(ei, curs, col);
    }

    // --- Wc = [W_l|W_r]^T bf16 padded (overwrites deg/curs) ---
    wprep_kernel<<<(NP1 * KP1 + 255) / 256, 256, 0, stream>>>(W_l, W_r, Wc);

    // --- fused GEMM1 (MFMA): xl|xr = x @ [W_l|W_r] ---
    gemm1_kernel<<<(NNODES + 127) / 128, 256, 0, stream>>>(x, Wc, xl, xr, NNODES);

    // --- GATv2 + ELU (writes h over xr); 5 waves per 2 nodes ---
    {
        int waves = (NNODES / 2) * 5;          // 125000
        int blocks = (waves + 3) / 4;          // 31250
        gat_kernel<<<blocks, 256, 0, stream>>>(xl, xr, rowp, col, att, bias1, xr);
    }

    // --- GCN aggregate (h -> agg, overwrites xl space) ---
    gcn_agg_kernel<<<(NNODES + 3) / 4, 256, 0, stream>>>(xr, rowp, col, dinv, agg);

    // --- W_gcn^T -> bf16 padded (into xr region; h is dead) ---
    btprep_kernel<<<(NPAD * KPAD + 255) / 256, 256, 0, stream>>>(W_gcn, BT);

    // --- GEMM2 (MFMA, XCD-swizzled flat grid) + bias + relu + fused pooling ---
    {
        int nb = (NNODES + BM - 1) / BM;       // 391
        int gx = 8 * ((nb + 7) / 8) * 7;       // 2744
        gemm2_pool_kernel<<<gx, 256, 0, stream>>>(agg, BT, bias_gcn, batch, out, NNODES);
    }

    // --- finalize means ---
    finalize_kernel<<<(NBATCH * HCDIM + 255) / 256, 256, 0, stream>>>(out, bst);
}